// Round 12
// baseline (531.453 us; speedup 1.0000x reference)
//
#include <hip/hip_runtime.h>

#define NAG 3
#define BATCH 32768
#define HD 128
#define SD 18
#define TB 32
#define ROWS 48
#define NBLK 683
#define PADB (NBLK * ROWS)     // 32784
#define EPSV 1e-5f
#define SCALE 0.08838834764831845f

typedef __attribute__((ext_vector_type(8))) short short8;
typedef __attribute__((ext_vector_type(4))) float f32x4;

// ---------------- ws byte layout ----------------
#define WSB_STATS 0
#define WSB_ACCUM 512
#define WSB_F     1024
#define WSB_W     197632
#define OFF_FT0 0
#define OFF_FT1 32768
#define OFF_MT  65536
#define OFF_AV0 98304
#define OFF_AV1 131072
#define OFF_CV  163840
#define OFF_MG(n) (196608 + (n)*98304)
#define OFF_C1(n) (491520 + (n)*65536)
#define OFF_C2(n) (688128 + (n)*4096)
#define OFF_SW(n) (700416 + (n)*57344)
#define WSB_SA  2097152
#define SA_BYTES_P ((size_t)NAG * PADB * HD * 2)

__device__ __forceinline__ float lrelu(float x){ return x >= 0.0f ? x : 0.01f * x; }
__device__ __forceinline__ f32x4 lrelu4(f32x4 v){
  f32x4 r; r[0]=lrelu(v[0]); r[1]=lrelu(v[1]); r[2]=lrelu(v[2]); r[3]=lrelu(v[3]); return r;
}
__device__ __forceinline__ f32x4 binit(float b){ f32x4 c; c[0]=b;c[1]=b;c[2]=b;c[3]=b; return c; }
__device__ __forceinline__ unsigned short f2bf(float f){
  unsigned int u = __float_as_uint(f);
  unsigned int r = (u + 0x7FFFu + ((u >> 16) & 1u)) >> 16;
  return (unsigned short)r;
}
__device__ __forceinline__ float bf2f(unsigned short h){
  return __uint_as_float(((unsigned int)h) << 16);
}

// ---------------- prep: batch stats ----------------
__global__ void stats_partial_kernel(const float* __restrict__ s,
                                     const float* __restrict__ a,
                                     float* __restrict__ accum){
  const int n = blockIdx.x >> 4;
  const int chunk = blockIdx.x & 15;
  const int t = threadIdx.x;
  const int rows = BATCH / 16;
  const int b0 = chunk * rows;
  float sum[20], sq[20];
  #pragma unroll
  for (int c = 0; c < 20; ++c){ sum[c] = 0.f; sq[c] = 0.f; }
  for (int b = b0 + t; b < b0 + rows; b += 256){
    const float* row = s + ((size_t)n * BATCH + b) * SD;
    #pragma unroll
    for (int c = 0; c < SD; ++c){ float v = row[c]; sum[c] += v; sq[c] += v * v; }
    const float* ra = a + ((size_t)n * BATCH + b) * 2;
    #pragma unroll
    for (int c = 0; c < 2; ++c){ float v = ra[c]; sum[SD + c] += v; sq[SD + c] += v * v; }
  }
  __shared__ float red[256];
  for (int c = 0; c < 20; ++c){
    red[t] = sum[c]; __syncthreads();
    for (int off = 128; off > 0; off >>= 1){ if (t < off) red[t] += red[t + off]; __syncthreads(); }
    if (t == 0) atomicAdd(&accum[(n * 20 + c) * 2 + 0], red[0]);
    __syncthreads();
    red[t] = sq[c]; __syncthreads();
    for (int off = 128; off > 0; off >>= 1){ if (t < off) red[t] += red[t + off]; __syncthreads(); }
    if (t == 0) atomicAdd(&accum[(n * 20 + c) * 2 + 1], red[0]);
    __syncthreads();
  }
}

// ---------------- prep: F_m = sel @ key^T + stats finalize ----------------
__global__ void fuse_mats_kernel(const float* __restrict__ asel, const float* __restrict__ akey,
                                 const float* __restrict__ csel, const float* __restrict__ ckey,
                                 float* __restrict__ F, const float* __restrict__ accum,
                                 float* __restrict__ stats){
  const int m  = blockIdx.y;
  if (m == 3){
    if (blockIdx.x == 0){
      int i = threadIdx.x;
      if (i < 60){
        float S = accum[i * 2 + 0], SQ = accum[i * 2 + 1];
        float mean = S / (float)BATCH;
        float var = SQ / (float)BATCH - mean * mean;
        stats[i * 2 + 0] = mean;
        stats[i * 2 + 1] = 1.0f / sqrtf(var + EPSV);
      }
    }
    return;
  }
  const int h1 = blockIdx.x;
  const int h2 = threadIdx.x;
  const float* A; const float* Bm;
  if (m == 0){ A = asel;            Bm = akey; }
  else if (m == 1){ A = asel + HD*HD; Bm = akey + HD*HD; }
  else { A = csel; Bm = ckey; }
  const float* arow = A + h1 * HD;
  const float* brow = Bm + h2 * HD;
  float acc = 0.f;
  #pragma unroll 4
  for (int d = 0; d < HD; ++d) acc = fmaf(arow[d], brow[d], acc);
  F[m * HD * HD + h1 * HD + h2] = acc;
}

// ---------------- prep: all weight splits + smallpack ----------------
__global__ void prep_split_kernel(const float* __restrict__ F, const float* __restrict__ aval_W,
                                  const float* __restrict__ cval_W, const float* __restrict__ merge_W,
                                  const float* __restrict__ cW1, const float* __restrict__ cW2,
                                  const float* __restrict__ en_W, const float* __restrict__ oa_W,
                                  const float* __restrict__ goal_W, const float* __restrict__ senc_W,
                                  unsigned short* __restrict__ wsu){
  const int job = blockIdx.y;
  const int idx = blockIdx.x * 256 + threadIdx.x;
  if (job == 15){
    if (idx >= 3 * 896 * 32) return;
    int k = idx & 31; int c = (idx >> 5) % 896; int n = idx / (896 * 32);
    int tt = c >> 7, cc = c & 127;
    float v = 0.f;
    if (tt == 0){
      if (k < 4) v = en_W[(size_t)(n*6 + k)*128 + cc];
      else if (k == 18 || k == 19) v = en_W[(size_t)(n*6 + 4 + (k-18))*128 + cc];
    } else if (tt <= 2){
      int j = tt - 1; int kk = k - (4 + 4*j);
      if (kk >= 0 && kk < 4) v = oa_W[(size_t)(n*4 + kk)*128 + cc];
    } else if (tt <= 5){
      int j = tt - 3; int kk = k - (12 + 2*j);
      if (kk >= 0 && kk < 2) v = goal_W[(size_t)(n*2 + kk)*128 + cc];
    } else {
      if (k < 18) v = senc_W[(size_t)(n*18 + k)*128 + cc];
    }
    unsigned short hi = f2bf(v); float lo = v - bf2f(hi);
    unsigned short* dh = wsu + OFF_SW(n);
    dh[c * 32 + k] = hi;
    dh[28672 + c * 32 + k] = f2bf(lo);
    return;
  }
  const float* src; unsigned short* dh; int K = 128, Csrc = 128, Cdst = 128, loff = 16384;
  switch (job){
    case 0: src = F;              dh = wsu + OFF_FT0; break;
    case 1: src = F + 16384;      dh = wsu + OFF_FT1; break;
    case 2: src = F + 32768;      dh = wsu + OFF_MT;  break;
    case 3: src = aval_W;         dh = wsu + OFF_AV0; break;
    case 4: src = aval_W + 16384; dh = wsu + OFF_AV1; break;
    case 5: src = cval_W;         dh = wsu + OFF_CV;  break;
    case 6: case 7: case 8: {
      int n = job - 6; src = merge_W + (size_t)n * 49152; dh = wsu + OFF_MG(n);
      K = 384; loff = 49152; } break;
    case 9: case 10: case 11: {
      int n = job - 9; src = cW1 + (size_t)n * 32768; dh = wsu + OFF_C1(n);
      K = 256; loff = 32768; } break;
    default: {
      int n = job - 12; src = cW2 + (size_t)n * 256; dh = wsu + OFF_C2(n);
      Csrc = 2; Cdst = 16; loff = 2048; } break;
  }
  if (idx >= K * Cdst) return;
  int k = idx / Cdst, c = idx - k * Cdst;
  float v = (c < Csrc) ? src[(size_t)k * Csrc + c] : 0.f;
  unsigned short hi = f2bf(v);
  dh[(size_t)c * K + k] = hi;
  dh[loff + (size_t)c * K + k] = f2bf(v - bf2f(hi));
}

// ---------------- MFMA helpers (shared) ----------------
__device__ __forceinline__ short8 ldAh(const unsigned char* sm, int base, int mi, int ks, int lane){
  int row = mi * 16 + (lane & 15);
  int bc  = ks * 64 + ((lane >> 4) << 4);
  return *(const short8*)(sm + base + row * 256 + (bc ^ ((row & 7) << 4)));
}
__device__ __forceinline__ void ldA(const unsigned char* sm, int base, int mi, int ks, int lane,
                                    short8& h, short8& l){
  int row = mi * 16 + (lane & 15);
  int bc  = ks * 64 + ((lane >> 4) << 4);
  int off = base + row * 256 + (bc ^ ((row & 7) << 4));
  h = *(const short8*)(sm + off);
  l = *(const short8*)(sm + off + 8192);
}
__device__ __forceinline__ void ldA32(const unsigned char* sm, int base, int mi, int lane,
                                      short8& h, short8& l){
  int row = mi * 16 + (lane & 15);
  int bc  = (lane >> 4) << 4;
  int off = base + row * 64 + (bc ^ ((row & 3) << 4));
  h = *(const short8*)(sm + off);
  l = *(const short8*)(sm + off + 2048);
}
__device__ __forceinline__ void ldA32_48(const unsigned char* sm, int base, int mi, int lane,
                                         short8& h, short8& l){
  int row = mi * 16 + (lane & 15);
  int bc  = (lane >> 4) << 4;
  int off = base + row * 64 + (bc ^ ((row & 3) << 4));
  h = *(const short8*)(sm + off);
  l = *(const short8*)(sm + off + 3072);
}

#define MM3(acc, ah, al, bh, bl) \
  acc = __builtin_amdgcn_mfma_f32_16x16x32_bf16(ah, bh, acc, 0, 0, 0); \
  acc = __builtin_amdgcn_mfma_f32_16x16x32_bf16(ah, bl, acc, 0, 0, 0); \
  acc = __builtin_amdgcn_mfma_f32_16x16x32_bf16(al, bh, acc, 0, 0, 0);
#define MM2(acc, ah, bh, bl) \
  acc = __builtin_amdgcn_mfma_f32_16x16x32_bf16(ah, bh, acc, 0, 0, 0); \
  acc = __builtin_amdgcn_mfma_f32_16x16x32_bf16(ah, bl, acc, 0, 0, 0);
#define MM1(acc, ah, bh) \
  acc = __builtin_amdgcn_mfma_f32_16x16x32_bf16(ah, bh, acc, 0, 0, 0);

// ---------------- 12-wave (mt, col-group) helpers: 1 mt, 2 colfrags ----------------
// K=32 small encoder: 2 LDS reads, 6 MFMA
__device__ __forceinline__ void gS(f32x4& ca, f32x4& cb, const unsigned char* sm, int abase,
                                   const unsigned short* wh, const unsigned short* wl,
                                   int bcol, int mt, int lane){
  const size_t b0 = (size_t)bcol * 32 + ((lane >> 4) << 3);
  const size_t b1 = b0 + 16 * 32;
  short8 ah, al;
  ldA32_48(sm, abase, mt, lane, ah, al);
  const short8 bh0 = *(const short8*)(wh + b0);
  const short8 bl0 = *(const short8*)(wl + b0);
  const short8 bh1 = *(const short8*)(wh + b1);
  const short8 bl1 = *(const short8*)(wl + b1);
  MM3(ca, ah, al, bh0, bl0);
  MM3(cb, ah, al, bh1, bl1);
}
// 2 hi-B mats x 2 cf: 4 LDS reads, 16 MFMA (selk)
__device__ __forceinline__ void gFT(f32x4& ka, f32x4& kb, f32x4& ma, f32x4& mb,
                                    const unsigned char* sm, int abase,
                                    const unsigned short* w0, const unsigned short* w1,
                                    int bcol, int mt, int lane){
  const size_t b0 = (size_t)bcol * 128 + ((lane >> 4) << 3);
  const size_t b1 = b0 + 16 * 128;
  #pragma unroll
  for (int ks = 0; ks < 4; ++ks){
    short8 A = ldAh(sm, abase, mt, ks, lane);
    MM1(ka, A, *(const short8*)(w0 + b0 + ks*32));
    MM1(kb, A, *(const short8*)(w0 + b1 + ks*32));
    MM1(ma, A, *(const short8*)(w1 + b0 + ks*32));
    MM1(mb, A, *(const short8*)(w1 + b1 + ks*32));
  }
}
// 2 slices x 2 cf (hi-A, hi-B): 8 reads, 16 MFMA
__device__ __forceinline__ void gV2(f32x4& s0a, f32x4& s0b, f32x4& s1a, f32x4& s1b,
                                    const unsigned char* sm, int t0, int t1,
                                    const unsigned short* wh, int bcol, int mt, int lane){
  const size_t b0 = (size_t)bcol * 128 + ((lane >> 4) << 3);
  const size_t b1 = b0 + 16 * 128;
  #pragma unroll
  for (int ks = 0; ks < 4; ++ks){
    const short8 B0 = *(const short8*)(wh + b0 + ks*32);
    const short8 B1 = *(const short8*)(wh + b1 + ks*32);
    short8 A0 = ldAh(sm, t0, mt, ks, lane);
    MM1(s0a, A0, B0); MM1(s0b, A0, B1);
    short8 A1 = ldAh(sm, t1, mt, ks, lane);
    MM1(s1a, A1, B0); MM1(s1b, A1, B1);
  }
}
// 3 slices x 2 cf: 12 reads, 24 MFMA
__device__ __forceinline__ void gV3(f32x4& s0a, f32x4& s0b, f32x4& s1a, f32x4& s1b,
                                    f32x4& s2a, f32x4& s2b,
                                    const unsigned char* sm, int t0, int t1, int t2,
                                    const unsigned short* wh, int bcol, int mt, int lane){
  const size_t b0 = (size_t)bcol * 128 + ((lane >> 4) << 3);
  const size_t b1 = b0 + 16 * 128;
  #pragma unroll
  for (int ks = 0; ks < 4; ++ks){
    const short8 B0 = *(const short8*)(wh + b0 + ks*32);
    const short8 B1 = *(const short8*)(wh + b1 + ks*32);
    short8 A0 = ldAh(sm, t0, mt, ks, lane);
    MM1(s0a, A0, B0); MM1(s0b, A0, B1);
    short8 A1 = ldAh(sm, t1, mt, ks, lane);
    MM1(s1a, A1, B0); MM1(s1b, A1, B1);
    short8 A2 = ldAh(sm, t2, mt, ks, lane);
    MM1(s2a, A2, B0); MM1(s2b, A2, B1);
  }
}
// split-B x 2 cf (merge/cW1 segment): 4 reads, 16 MFMA
__device__ __forceinline__ void gM(f32x4& ca, f32x4& cb, const unsigned char* sm, int abase,
                                   const unsigned short* wh, const unsigned short* wl,
                                   int K, int bcol, int kBase, int mt, int lane){
  const size_t b0 = (size_t)bcol * K + kBase + ((lane >> 4) << 3);
  const size_t b1 = b0 + (size_t)16 * K;
  #pragma unroll
  for (int ks = 0; ks < 4; ++ks){
    short8 A = ldAh(sm, abase, mt, ks, lane);
    MM2(ca, A, *(const short8*)(wh + b0 + ks*32), *(const short8*)(wl + b0 + ks*32));
    MM2(cb, A, *(const short8*)(wh + b1 + ks*32), *(const short8*)(wl + b1 + ks*32));
  }
}
// hi-B single mat x 2 cf (MT): 4 reads, 8 MFMA
__device__ __forceinline__ void gHB(f32x4& ca, f32x4& cb, const unsigned char* sm, int abase,
                                    const unsigned short* wh, int bcol, int mt, int lane){
  const size_t b0 = (size_t)bcol * 128 + ((lane >> 4) << 3);
  const size_t b1 = b0 + 16 * 128;
  #pragma unroll
  for (int ks = 0; ks < 4; ++ks){
    short8 A = ldAh(sm, abase, mt, ks, lane);
    MM1(ca, A, *(const short8*)(wh + b0 + ks*32));
    MM1(cb, A, *(const short8*)(wh + b1 + ks*32));
  }
}

// stores
__device__ __forceinline__ void stTile(unsigned char* sm, int base, int mi, int lane, int col, f32x4 v){
  #pragma unroll
  for (int r = 0; r < 4; ++r){
    int row = mi * 16 + ((lane >> 4) << 2) + r;
    int off = base + row * 256 + ((col * 2) ^ ((row & 7) << 4));
    unsigned short hi = f2bf(v[r]);
    *(unsigned short*)(sm + off) = hi;
    *(unsigned short*)(sm + off + 8192) = f2bf(v[r] - bf2f(hi));
  }
}
__device__ __forceinline__ void stTileC(unsigned char* sm, int base, int mi, int lane, int col, f32x4 v){
  #pragma unroll
  for (int r = 0; r < 4; ++r){
    int row = mi * 16 + ((lane >> 4) << 2) + r;
    int off = base + row * 256 + ((col * 2) ^ ((row & 7) << 4));
    unsigned short hi = f2bf(v[r]);
    *(unsigned short*)(sm + off) = hi;
    *(unsigned short*)(sm + off + 12288) = f2bf(v[r] - bf2f(hi));
  }
}
__device__ __forceinline__ void stH(unsigned char* sm, int base, int mi, int lane, int col, f32x4 v){
  #pragma unroll
  for (int r = 0; r < 4; ++r){
    int row = mi * 16 + ((lane >> 4) << 2) + r;
    int off = base + row * 256 + ((col * 2) ^ ((row & 7) << 4));
    *(unsigned short*)(sm + off) = f2bf(v[r]);
  }
}
__device__ __forceinline__ void stSK(unsigned char* sm, int base, int mi, int lane, int col, f32x4 v){
  #pragma unroll
  for (int r = 0; r < 4; ++r){
    int row = mi * 16 + ((lane >> 4) << 2) + r;
    int off = base + row * 256 + ((col * 2) ^ ((row & 7) << 5));
    *(unsigned short*)(sm + off) = f2bf(v[r]);
  }
}
__device__ __forceinline__ float dot8(short8 x, short8 y){
  float acc = 0.f;
  #pragma unroll
  for (int e = 0; e < 8; ++e)
    acc = fmaf(bf2f((unsigned short)x[e]), bf2f((unsigned short)y[e]), acc);
  return acc;
}
#define RED16(p) { p += __shfl_xor(p, 1, 16); p += __shfl_xor(p, 2, 16); \
                   p += __shfl_xor(p, 4, 16); p += __shfl_xor(p, 8, 16); }

// ======================================================================
// PATH A: actor kernel — grid (NBLK, NAG), 768 threads (12 waves), 78.75KB LDS
// ======================================================================
__global__ __launch_bounds__(768, 4) void actor_kernel(
    const float* __restrict__ s, const float* __restrict__ a,
    const float* __restrict__ en_b, const float* __restrict__ oa_b,
    const float* __restrict__ goal_b, const float* __restrict__ aval_b,
    const float* __restrict__ merge_b, const unsigned char* __restrict__ wsc,
    unsigned short* __restrict__ sa_g)
{
  __shared__ __align__(16) unsigned char SM[80640];
  const int AXN = 0, AEN = 6144, AOV = 18432, ASK = 30720;
  const int SLB0 = 43008, SLB1 = 55296, SLB2 = 67584, AEP = 79872;
  const int t = threadIdx.x, lane = t & 63, wave = t >> 6;
  const int mt = wave >> 2;                         // 0..2
  const int col0 = (wave & 3) * 32 + (lane & 15);   // first colfrag; second at +16
  const int n = blockIdx.y;
  const int gb0 = blockIdx.x * ROWS;
  const float* stats = (const float*)(wsc + WSB_STATS);
  const unsigned short* wsu = (const unsigned short*)(wsc + WSB_W);
  const unsigned short* swh = wsu + OFF_SW(n);
  const unsigned short* swl = swh + 28672;
  float* eP0 = (float*)(SM + AEP);
  float* eP1 = eP0 + 48;
  float* eP2 = eP0 + 96;
  float* esm = eP0 + 144;
  const f32x4 Z = binit(0.f);
  const int drow = t >> 4;            // 0..47 (768 threads / 16 lanes)
  const int dcb  = (t & 15) * 16;     // 16B chunk per lane
  const int r0base = (lane >> 4) << 2;
  const int mrow = mt * 16 + r0base;  // accumulator row base

  // init: stage normalized XN (split, K=32), clamped reads
  if (t < ROWS){
    int row = t;
    size_t gb = (size_t)gb0 + row;
    if (gb >= BATCH) gb = BATCH - 1;
    const float* st = stats + n * 40;
    const float* srow = s + ((size_t)n * BATCH + gb) * SD;
    const float* arow = a + ((size_t)n * BATCH + gb) * 2;
    #pragma unroll
    for (int c = 0; c < 32; ++c){
      float v = 0.f;
      if (c < 18) v = (srow[c] - st[c*2]) * st[c*2+1];
      else if (c < 20) v = (arow[c-18] - st[c*2]) * st[c*2+1];
      unsigned short hi = f2bf(v);
      int off = AXN + row * 64 + ((c * 2) ^ ((row & 3) << 4));
      *(unsigned short*)(SM + off) = hi;
      *(unsigned short*)(SM + off + 3072) = f2bf(v - bf2f(hi));
    }
  }
  __syncthreads();
  // R0: en_enc -> AEN ; oa slices -> SLB0, SLB1
  {
    f32x4 ca = binit(en_b[n*HD + col0]), cb = binit(en_b[n*HD + col0 + 16]);
    gS(ca, cb, SM, AXN, swh, swl, col0, mt, lane);
    stH(SM, AEN, mt, lane, col0, lrelu4(ca));
    stH(SM, AEN, mt, lane, col0 + 16, lrelu4(cb));
    float b0 = oa_b[n*HD + col0], b1 = oa_b[n*HD + col0 + 16];
    ca = binit(b0); cb = binit(b1);
    gS(ca, cb, SM, AXN, swh, swl, 128 + col0, mt, lane);
    stH(SM, SLB0, mt, lane, col0, lrelu4(ca));
    stH(SM, SLB0, mt, lane, col0 + 16, lrelu4(cb));
    ca = binit(b0); cb = binit(b1);
    gS(ca, cb, SM, AXN, swh, swl, 256 + col0, mt, lane);
    stH(SM, SLB1, mt, lane, col0, lrelu4(ca));
    stH(SM, SLB1, mt, lane, col0 + 16, lrelu4(cb));
  }
  __syncthreads();
  // R1: selk0 -> AOV, selk1 -> ASK (hi-B)
  {
    f32x4 ka = Z, kb = Z, ma = Z, mb = Z;
    gFT(ka, kb, ma, mb, SM, AEN, wsu + OFF_FT0, wsu + OFF_FT1, col0, mt, lane);
    stSK(SM, AOV, mt, lane, col0, ka); stSK(SM, AOV, mt, lane, col0 + 16, kb);
    stSK(SM, ASK, mt, lane, col0, ma); stSK(SM, ASK, mt, lane, col0 + 16, mb);
  }
  __syncthreads();
  // R2: oa vals (2 slices x 2 cf, shared hi-B) + logit dots + exp
  f32x4 v0a, v0b, v1a, v1b;
  {
    v0a = binit(aval_b[col0]); v0b = binit(aval_b[col0 + 16]);
    v1a = v0a; v1b = v0b;
    gV2(v0a, v0b, v1a, v1b, SM, SLB0, SLB1, wsu + OFF_AV0, col0, mt, lane);
    int sw5 = (drow & 7) << 5, sw4 = (drow & 7) << 4;
    short8 kf = *(const short8*)(SM + AOV + drow * 256 + (dcb ^ sw5));
    short8 e0 = *(const short8*)(SM + SLB0 + drow * 256 + (dcb ^ sw4));
    short8 e1 = *(const short8*)(SM + SLB1 + drow * 256 + (dcb ^ sw4));
    float p0 = dot8(kf, e0), p1 = dot8(kf, e1);
    RED16(p0) RED16(p1)
    if ((t & 15) == 0){
      float q0 = __expf(p0 * SCALE), q1 = __expf(p1 * SCALE);
      eP0[drow] = q0; eP1[drow] = q1; esm[drow] = q0 + q1;
    }
  }
  __syncthreads();
  // R3: ov0 -> AOV ; goal slices g0,g1,g2 -> SLB0,1,2
  {
    f32x4 oa, ob;
    #pragma unroll
    for (int r = 0; r < 4; ++r){
      int mr = mrow + r;
      float inv = 1.f / esm[mr];
      oa[r] = (eP0[mr] * lrelu(v0a[r]) + eP1[mr] * lrelu(v1a[r])) * inv;
      ob[r] = (eP0[mr] * lrelu(v0b[r]) + eP1[mr] * lrelu(v1b[r])) * inv;
    }
    stH(SM, AOV, mt, lane, col0, oa);
    stH(SM, AOV, mt, lane, col0 + 16, ob);
    float b0 = goal_b[n*HD + col0], b1 = goal_b[n*HD + col0 + 16];
    f32x4 ca = binit(b0), cb = binit(b1);
    gS(ca, cb, SM, AXN, swh, swl, 384 + col0, mt, lane);
    stH(SM, SLB0, mt, lane, col0, lrelu4(ca));
    stH(SM, SLB0, mt, lane, col0 + 16, lrelu4(cb));
    ca = binit(b0); cb = binit(b1);
    gS(ca, cb, SM, AXN, swh, swl, 512 + col0, mt, lane);
    stH(SM, SLB1, mt, lane, col0, lrelu4(ca));
    stH(SM, SLB1, mt, lane, col0 + 16, lrelu4(cb));
    ca = binit(b0); cb = binit(b1);
    gS(ca, cb, SM, AXN, swh, swl, 640 + col0, mt, lane);
    stH(SM, SLB2, mt, lane, col0, lrelu4(ca));
    stH(SM, SLB2, mt, lane, col0 + 16, lrelu4(cb));
  }
  __syncthreads();
  // R4: goal vals (3 slices x 2 cf, shared hi-B) + 3 dots + exps
  f32x4 g0a, g0b, g1a, g1b, g2a, g2b;
  {
    g0a = binit(aval_b[HD + col0]); g0b = binit(aval_b[HD + col0 + 16]);
    g1a = g0a; g1b = g0b; g2a = g0a; g2b = g0b;
    gV3(g0a, g0b, g1a, g1b, g2a, g2b, SM, SLB0, SLB1, SLB2,
        wsu + OFF_AV1, col0, mt, lane);
    int sw5 = (drow & 7) << 5, sw4 = (drow & 7) << 4;
    short8 kf = *(const short8*)(SM + ASK + drow * 256 + (dcb ^ sw5));
    short8 e0 = *(const short8*)(SM + SLB0 + drow * 256 + (dcb ^ sw4));
    short8 e1 = *(const short8*)(SM + SLB1 + drow * 256 + (dcb ^ sw4));
    short8 e2 = *(const short8*)(SM + SLB2 + drow * 256 + (dcb ^ sw4));
    float p0 = dot8(kf, e0), p1 = dot8(kf, e1), p2 = dot8(kf, e2);
    RED16(p0) RED16(p1) RED16(p2)
    if ((t & 15) == 0){
      float q0 = __expf(p0 * SCALE), q1 = __expf(p1 * SCALE), q2 = __expf(p2 * SCALE);
      eP0[drow] = q0; eP1[drow] = q1; eP2[drow] = q2;
      esm[drow] = (q0 + q1) + q2;
    }
  }
  __syncthreads();
  // R5: ov1 -> SLB0
  {
    f32x4 oa, ob;
    #pragma unroll
    for (int r = 0; r < 4; ++r){
      int mr = mrow + r;
      float inv = 1.f / esm[mr];
      oa[r] = ((eP0[mr] * lrelu(g0a[r]) + eP1[mr] * lrelu(g1a[r]))
               + eP2[mr] * lrelu(g2a[r])) * inv;
      ob[r] = ((eP0[mr] * lrelu(g0b[r]) + eP1[mr] * lrelu(g1b[r]))
               + eP2[mr] * lrelu(g2b[r])) * inv;
    }
    stH(SM, SLB0, mt, lane, col0, oa);
    stH(SM, SLB0, mt, lane, col0 + 16, ob);
  }
  __syncthreads();
  // R6: merge (split-B) -> SLB1
  {
    const unsigned short* mh = wsu + OFF_MG(n);
    const unsigned short* ml = mh + 49152;
    f32x4 ca = binit(merge_b[n*HD + col0]), cb = binit(merge_b[n*HD + col0 + 16]);
    gM(ca, cb, SM, AEN,  mh, ml, 384, col0, 0,   mt, lane);
    gM(ca, cb, SM, AOV,  mh, ml, 384, col0, 128, mt, lane);
    gM(ca, cb, SM, SLB0, mh, ml, 384, col0, 256, mt, lane);
    stH(SM, SLB1, mt, lane, col0, lrelu4(ca));
    stH(SM, SLB1, mt, lane, col0 + 16, lrelu4(cb));
  }
  __syncthreads();
  // R7: coalesced copy SLB1 -> sa_g (padded): 768 entries = 768 threads
  {
    int row = t >> 4, ch = t & 15;
    short8 u = *(const short8*)(SM + SLB1 + row * 256 + ((ch * 16) ^ ((row & 7) << 4)));
    *(short8*)(sa_g + ((size_t)n * PADB + gb0 + row) * HD + ch * 8) = u;
  }
}

// ======================================================================
// PATH A: critic kernel — grid (NBLK, NAG=i), 768 threads, 66.4KB LDS
// ======================================================================
__global__ __launch_bounds__(768, 4) void critic_kernel(
    const float* __restrict__ s, const float* __restrict__ a,
    const float* __restrict__ senc_b, const float* __restrict__ cval_b,
    const float* __restrict__ cb1, const float* __restrict__ cW2,
    const float* __restrict__ cb2, const unsigned char* __restrict__ wsc,
    const unsigned short* __restrict__ sa_g, float* __restrict__ out)
{
  __shared__ __align__(16) unsigned char SM[67968];
  const int CXN = 0, CEN = 6144, CSMo = 18432, CSA = 30720, COV = 55296, CH = 30720, CLW = 67584;
  const int t = threadIdx.x, lane = t & 63, wave = t >> 6;
  const int mt = wave >> 2;
  const int col0 = (wave & 3) * 32 + (lane & 15);
  const int i = blockIdx.y;
  const int gb0 = blockIdx.x * ROWS;
  const int j0 = (i == 0) ? 1 : 0;
  const int j1 = (i == 2) ? 1 : 2;
  const float* stats = (const float*)(wsc + WSB_STATS);
  const unsigned short* wsu = (const unsigned short*)(wsc + WSB_W);
  const unsigned short* swh = wsu + OFF_SW(i);
  const unsigned short* swl = swh + 28672;
  const f32x4 Z = binit(0.f);
  const int drow = t >> 4;
  const int dcb  = (t & 15) * 16;
  const int r0base = (lane >> 4) << 2;
  const int mrow = mt * 16 + r0base;

  // R0: stage XN_i (split, clamped) + copy sa_j0/j1 -> LDS (hi, swz)
  if (t < ROWS){
    int row = t;
    size_t gb = (size_t)gb0 + row;
    if (gb >= BATCH) gb = BATCH - 1;
    const float* st = stats + i * 40;
    const float* srow = s + ((size_t)i * BATCH + gb) * SD;
    const float* arow = a + ((size_t)i * BATCH + gb) * 2;
    #pragma unroll
    for (int c = 0; c < 32; ++c){
      float v = 0.f;
      if (c < 18) v = (srow[c] - st[c*2]) * st[c*2+1];
      else if (c < 20) v = (arow[c-18] - st[c*2]) * st[c*2+1];
      unsigned short hi = f2bf(v);
      int off = CXN + row * 64 + ((c * 2) ^ ((row & 3) << 4));
      *(unsigned short*)(SM + off) = hi;
      *(unsigned short*)(SM + off + 3072) = f2bf(v - bf2f(hi));
    }
  }
  for (int idx = t; idx < 2 * ROWS * 16; idx += 768){
    int tile = idx >= ROWS * 16;
    int k = idx - tile * ROWS * 16;
    int row = k >> 4, ch = k & 15;
    int j = tile ? j1 : j0;
    short8 u = *(const short8*)(sa_g + ((size_t)j * PADB + gb0 + row) * HD + ch * 8);
    *(short8*)(SM + CSA + tile * 12288 + row * 256 + ((ch * 16) ^ ((row & 7) << 4))) = u;
  }
  __syncthreads();
  // R1: s_enc -> CEN (hi)
  {
    f32x4 ca = binit(senc_b[i*HD + col0]), cb = binit(senc_b[i*HD + col0 + 16]);
    gS(ca, cb, SM, CXN, swh, swl, 768 + col0, mt, lane);
    stH(SM, CEN, mt, lane, col0, lrelu4(ca));
    stH(SM, CEN, mt, lane, col0 + 16, lrelu4(cb));
  }
  __syncthreads();
  // R2: selsM = s_enc @ M (hi-B) -> CSM (32B-swz)
  {
    f32x4 ka = Z, kb = Z;
    gHB(ka, kb, SM, CEN, wsu + OFF_MT, col0, mt, lane);
    stSK(SM, CSMo, mt, lane, col0, ka);
    stSK(SM, CSMo, mt, lane, col0 + 16, kb);
  }
  __syncthreads();
  // R3: vals GEMMs (2 sa-tiles x 2 cf, shared hi-B) + dots + 2-way softmax
  f32x4 v0a, v0b, v1a, v1b;
  {
    v0a = binit(cval_b[col0]); v0b = binit(cval_b[col0 + 16]);
    v1a = v0a; v1b = v0b;
    gV2(v0a, v0b, v1a, v1b, SM, CSA, CSA + 12288, wsu + OFF_CV, col0, mt, lane);
    int sw5 = (drow & 7) << 5, sw4 = (drow & 7) << 4;
    short8 mf = *(const short8*)(SM + CSMo + drow * 256 + (dcb ^ sw5));
    short8 a0 = *(const short8*)(SM + CSA + drow * 256 + (dcb ^ sw4));
    short8 b0 = *(const short8*)(SM + CSA + 12288 + drow * 256 + (dcb ^ sw4));
    float p0 = dot8(mf, a0);
    float p1 = dot8(mf, b0);
    RED16(p0) RED16(p1)
    if ((t & 15) == 0){
      float q0 = __expf(p0 * SCALE), q1 = __expf(p1 * SCALE);
      float inv = 1.f / (q0 + q1);
      ((float*)(SM + CLW))[drow]      = q0 * inv;
      ((float*)(SM + CLW))[48 + drow] = q1 * inv;
    }
  }
  __syncthreads();
  // R4: ov -> COV (hi)
  {
    const float* w0 = (const float*)(SM + CLW);
    const float* w1 = w0 + 48;
    f32x4 oa, ob;
    #pragma unroll
    for (int r = 0; r < 4; ++r){
      int mr = mrow + r;
      oa[r] = w0[mr] * lrelu(v0a[r]) + w1[mr] * lrelu(v1a[r]);
      ob[r] = w0[mr] * lrelu(v0b[r]) + w1[mr] * lrelu(v1b[r]);
    }
    stH(SM, COV, mt, lane, col0, oa);
    stH(SM, COV, mt, lane, col0 + 16, ob);
  }
  __syncthreads();
  // R5: h = lrelu([s_enc|ov] @ cW1 + b) -> CH (split; overwrites CSA)
  {
    const unsigned short* c1h = wsu + OFF_C1(i);
    const unsigned short* c1l = c1h + 32768;
    f32x4 ha = binit(cb1[i*HD + col0]), hb = binit(cb1[i*HD + col0 + 16]);
    gM(ha, hb, SM, CEN, c1h, c1l, 256, col0, 0,   mt, lane);
    gM(ha, hb, SM, COV, c1h, c1l, 256, col0, 128, mt, lane);
    stTileC(SM, CH, mt, lane, col0, lrelu4(ha));
    stTileC(SM, CH, mt, lane, col0 + 16, lrelu4(hb));
  }
  __syncthreads();
  // R6: q = h @ cW2 + cb2 (per-row dot, split h), guarded store
  if (gb0 + drow < BATCH){
    int sw4 = (drow & 7) << 4;
    const unsigned char* hb = SM + CH + drow * 256;
    short8 hh = *(const short8*)(hb + (dcb ^ sw4));
    short8 ll = *(const short8*)(hb + 12288 + (dcb ^ sw4));
    float q0 = 0.f, q1 = 0.f;
    #pragma unroll
    for (int e = 0; e < 8; ++e){
      int d = (t & 15) * 8 + e;
      float hv = bf2f((unsigned short)hh[e]) + bf2f((unsigned short)ll[e]);
      q0 = fmaf(hv, cW2[(i * HD + d) * 2 + 0], q0);
      q1 = fmaf(hv, cW2[(i * HD + d) * 2 + 1], q1);
    }
    RED16(q0) RED16(q1)
    if ((t & 15) == 0){
      out[((size_t)i * BATCH + gb0 + drow) * 2 + 0] = q0 + cb2[i * 2 + 0];
      out[((size_t)i * BATCH + gb0 + drow) * 2 + 1] = q1 + cb2[i * 2 + 1];
    }
  }
}

// ======================================================================
// PATH B fallback: TB=32 helpers + round-2 fused kernel (proven)
// ======================================================================
__device__ __forceinline__ void gemmA(f32x4& c0, f32x4& c1, const unsigned char* sm, int abase,
                                      const unsigned short* wh, const unsigned short* wl,
                                      int K, int bcol, int kBaseB, int lane){
  const size_t bb = (size_t)bcol * K + kBaseB + ((lane >> 4) << 3);
  #pragma unroll
  for (int ks = 0; ks < 4; ++ks){
    short8 ah0, al0, ah1, al1;
    ldA(sm, abase, 0, ks, lane, ah0, al0);
    ldA(sm, abase, 1, ks, lane, ah1, al1);
    const short8 bh = *(const short8*)(wh + bb + ks * 32);
    const short8 bl = *(const short8*)(wl + bb + ks * 32);
    MM3(c0, ah0, al0, bh, bl);
    MM3(c1, ah1, al1, bh, bl);
  }
}
__device__ __forceinline__ void gemmS(f32x4& c0, f32x4& c1, const unsigned char* sm, int abase,
                                      const unsigned short* wh, const unsigned short* wl,
                                      int bcol, int lane){
  const size_t bb = (size_t)bcol * 32 + ((lane >> 4) << 3);
  short8 ah0, al0, ah1, al1;
  ldA32(sm, abase, 0, lane, ah0, al0);
  ldA32(sm, abase, 1, lane, ah1, al1);
  const short8 bh = *(const short8*)(wh + bb);
  const short8 bl = *(const short8*)(wl + bb);
  MM3(c0, ah0, al0, bh, bl);
  MM3(c1, ah1, al1, bh, bl);
}
__device__ __forceinline__ void dotTile(unsigned char* sm, int tbase, const f32x4 d0, const f32x4 d1,
                                        int lane, int wave, int col, int part_o){
  float* part = (float*)(sm + part_o);
  #pragma unroll
  for (int mi = 0; mi < 2; ++mi){
    #pragma unroll
    for (int r = 0; r < 4; ++r){
      int row = mi * 16 + ((lane >> 4) << 2) + r;
      int off = tbase + row * 256 + ((col * 2) ^ ((row & 7) << 4));
      float v = bf2f(*(const unsigned short*)(sm + off)) +
                bf2f(*(const unsigned short*)(sm + off + 8192));
      float p = (mi ? d1[r] : d0[r]) * v;
      RED16(p)
      if ((lane & 15) == 0) part[wave * 32 + row] = p;
    }
  }
}

#define XN_O    0
#define EN_O    12288
#define SLICE_O 28672
#define OV0_O   45056
#define SA_O    61440
#define PART_O  110592
#define EP_O    111616
#define ESUM_O  111744
#define LW_O    111872
#define SM_TOTAL 113024

__global__ __launch_bounds__(512, 2) void fused_kernel(
    const float* __restrict__ s, const float* __restrict__ a,
    const float* __restrict__ en_b, const float* __restrict__ oa_b,
    const float* __restrict__ goal_b, const float* __restrict__ aval_b,
    const float* __restrict__ merge_b, const float* __restrict__ senc_b,
    const float* __restrict__ cval_b, const float* __restrict__ cb1,
    const float* __restrict__ cb2, const unsigned char* __restrict__ wsc,
    float* __restrict__ out)
{
  __shared__ __align__(16) unsigned char SM[SM_TOTAL];
  unsigned char* sm = SM;
  const int t = threadIdx.x;
  const int lane = t & 63;
  const int wave = t >> 6;
  const int col = wave * 16 + (lane & 15);
  const int gb0 = blockIdx.x * TB;
  const float* stats = (const float*)(wsc + WSB_STATS);
  const unsigned short* wsu = (const unsigned short*)(wsc + WSB_W);
  const f32x4 Z = binit(0.f);

  if (t < 96){
    int n = t >> 5, row = t & 31;
    size_t gb = (size_t)gb0 + row;
    const float* st = stats + n * 40;
    const float* srow = s + ((size_t)n * BATCH + gb) * SD;
    const float* arow = a + ((size_t)n * BATCH + gb) * 2;
    #pragma unroll
    for (int c = 0; c < 32; ++c){
      float v = 0.f;
      if (c < 18) v = (srow[c] - st[c*2]) * st[c*2+1];
      else if (c < 20) v = (arow[c-18] - st[c*2]) * st[c*2+1];
      unsigned short hi = f2bf(v);
      int off = XN_O + n * 4096 + row * 64 + ((c * 2) ^ ((row & 3) << 4));
      *(unsigned short*)(sm + off) = hi;
      *(unsigned short*)(sm + off + 2048) = f2bf(v - bf2f(hi));
    }
  }
  __syncthreads();

  #pragma unroll 1
  for (int n = 0; n < NAG; ++n){
    const unsigned short* swh = wsu + OFF_SW(n);
    const unsigned short* swl = swh + 28672;
    {
      f32x4 v0 = binit(en_b[n*HD + col]), v1 = v0;
      gemmS(v0, v1, sm, XN_O + n*4096, swh, swl, 0 + col, lane);
      stTile(sm, EN_O, 0, lane, col, lrelu4(v0));
      stTile(sm, EN_O, 1, lane, col, lrelu4(v1));
    }
    __syncthreads();
    f32x4 sk0a = Z, sk0b = Z, sk1a = Z, sk1b = Z;
    gemmA(sk0a, sk0b, sm, EN_O, wsu + OFF_FT0, wsu + OFF_FT0 + 16384, 128, col, 0, lane);
    gemmA(sk1a, sk1b, sm, EN_O, wsu + OFF_FT1, wsu + OFF_FT1 + 16384, 128, col, 0, lane);

    f32x4 ov0a = Z, ov0b = Z;
    #pragma unroll 1
    for (int j = 0; j < 2; ++j){
      __syncthreads();
      f32x4 v0 = binit(oa_b[n*HD + col]), v1 = v0;
      gemmS(v0, v1, sm, XN_O + n*4096, swh, swl, 128*(1+j) + col, lane);
      stTile(sm, SLICE_O, 0, lane, col, lrelu4(v0));
      stTile(sm, SLICE_O, 1, lane, col, lrelu4(v1));
      __syncthreads();
      dotTile(sm, SLICE_O, sk0a, sk0b, lane, wave, col, PART_O);
      __syncthreads();
      if (t < TB){
        const float* part = (const float*)(sm + PART_O);
        float tot = 0.f;
        #pragma unroll
        for (int w2 = 0; w2 < 8; ++w2) tot += part[w2*32 + t];
        float e = __expf(tot * SCALE);
        ((float*)(sm + EP_O))[t] = e;
        float* es = (float*)(sm + ESUM_O);
        es[t] = (j == 0) ? e : es[t] + e;
      }
      __syncthreads();
      f32x4 w0 = binit(aval_b[col]), w1 = w0;
      gemmA(w0, w1, sm, SLICE_O, wsu + OFF_AV0, wsu + OFF_AV0 + 16384, 128, col, 0, lane);
      const float* eP = (const float*)(sm + EP_O);
      #pragma unroll
      for (int r = 0; r < 4; ++r){
        int row0 = ((lane >> 4) << 2) + r;
        ov0a[r] += eP[row0]      * lrelu(w0[r]);
        ov0b[r] += eP[row0 + 16] * lrelu(w1[r]);
      }
    }
    {
      const float* es = (const float*)(sm + ESUM_O);
      f32x4 o0, o1;
      #pragma unroll
      for (int r = 0; r < 4; ++r){
        int row0 = ((lane >> 4) << 2) + r;
        o0[r] = ov0a[r] / es[row0];
        o1[r] = ov0b[r] / es[row0 + 16];
      }
      stTile(sm, OV0_O, 0, lane, col, o0);
      stTile(sm, OV0_O, 1, lane, col, o1);
    }

    f32x4 ov1a = Z, ov1b = Z;
    #pragma unroll 1
    for (int j = 0; j < 3; ++j){
      __syncthreads();
      f32x4 v0 = binit(goal_b[n*HD + col]), v1 = v0;
      gemmS(v0, v1, sm, XN_O + n*4096, swh, swl, 128*(3+j) + col, lane);
      stTile(sm, SLICE_O, 0, lane, col, lrelu4(v0));
      stTile(sm, SLICE_O, 1, lane, col, lrelu4(v1));
      __syncthreads();
      dotTile(sm, SLICE_O, sk1a, sk1b, lane, wave, col, PART_O);
      __syncthreads();
      if (t < TB){
        const float* part = (const float*)(sm + PART_O);
        float tot = 0.f;
        #pragma unroll
        for (int w2 = 0; w2 < 8; ++w2) tot += part[w2*32 + t];
        float e = __expf(tot * SCALE);
        ((float*)(sm + EP_O))[t] = e;
        float* es = (float*)(sm + ESUM_O);
        es[t] = (j == 0) ? e : es[t] + e;
      }
      __syncthreads();
      f32x4 w0 = binit(aval_b[HD + col]), w1 = w0;
      gemmA(w0, w1, sm, SLICE_O, wsu + OFF_AV1, wsu + OFF_AV1 + 16384, 128, col, 0, lane);
      const float* eP = (const float*)(sm + EP_O);
      #pragma unroll
      for (int r = 0; r < 4; ++r){
        int row0 = ((lane >> 4) << 2) + r;
        ov1a[r] += eP[row0]      * lrelu(w0[r]);
        ov1b[r] += eP[row0 + 16] * lrelu(w1[r]);
      }
    }
    __syncthreads();
    {
      const float* es = (const float*)(sm + ESUM_O);
      f32x4 o0, o1;
      #pragma unroll
      for (int r = 0; r < 4; ++r){
        int row0 = ((lane >> 4) << 2) + r;
        o0[r] = ov1a[r] / es[row0];
        o1[r] = ov1b[r] / es[row0 + 16];
      }
      stTile(sm, SLICE_O, 0, lane, col, o0);
      stTile(sm, SLICE_O, 1, lane, col, o1);
    }
    __syncthreads();
    {
      const unsigned short* mhp = wsu + OFF_MG(n);
      const unsigned short* mlp = mhp + 49152;
      f32x4 m0 = binit(merge_b[n*HD + col]), m1 = m0;
      gemmA(m0, m1, sm, EN_O,    mhp, mlp, 384, col, 0,   lane);
      gemmA(m0, m1, sm, OV0_O,   mhp, mlp, 384, col, 128, lane);
      gemmA(m0, m1, sm, SLICE_O, mhp, mlp, 384, col, 256, lane);
      stTile(sm, SA_O + n*16384, 0, lane, col, lrelu4(m0));
      stTile(sm, SA_O + n*16384, 1, lane, col, lrelu4(m1));
    }
    __syncthreads();
  }

  #pragma unroll 1
  for (int i = 0; i < NAG; ++i){
    const unsigned short* swh = wsu + OFF_SW(i);
    const unsigned short* swl = swh + 28672;
    f32x4 e0 = binit(senc_b[i*HD + col]), e1 = e0;
    gemmS(e0, e1, sm, XN_O + i*4096, swh, swl, 768 + col, lane);
    stTile(sm, EN_O, 0, lane, col, lrelu4(e0));
    stTile(sm, EN_O, 1, lane, col, lrelu4(e1));
    __syncthreads();
    f32x4 sm0 = Z, sm1 = Z;
    gemmA(sm0, sm1, sm, EN_O, wsu + OFF_MT, wsu + OFF_MT + 16384, 128, col, 0, lane);
    #pragma unroll 1
    for (int j = 0; j < NAG; ++j){
      if (j == i) continue;
      dotTile(sm, SA_O + j*16384, sm0, sm1, lane, wave, col, PART_O);
      __syncthreads();
      if (t < TB){
        const float* part = (const float*)(sm + PART_O);
        float tot = 0.f;
        #pragma unroll
        for (int w2 = 0; w2 < 8; ++w2) tot += part[w2*32 + t];
        ((float*)(sm + LW_O))[(i*3 + j)*32 + t] = tot;
      }
      __syncthreads();
    }
  }
  if (t < TB){
    float* LW = (float*)(sm + LW_O);
    #pragma unroll
    for (int i = 0; i < NAG; ++i){
      int j0 = (i == 0) ? 1 : 0;
      int j1 = (i == 2) ? 1 : 2;
      float l0 = LW[(i*3 + j0)*32 + t] * SCALE;
      float l1 = LW[(i*3 + j1)*32 + t] * SCALE;
      float q0 = __expf(l0), q1 = __expf(l1);
      float inv = 1.f / (q0 + q1);
      LW[(i*3 + j0)*32 + t] = q0 * inv;
      LW[(i*3 + j1)*32 + t] = q1 * inv;
    }
  }
  __syncthreads();
  f32x4 oc00 = Z, oc01 = Z, oc10 = Z, oc11 = Z, oc20 = Z, oc21 = Z;
  {
    const float* LW = (const float*)(sm + LW_O);
    #pragma unroll 1
    for (int j = 0; j < NAG; ++j){
      f32x4 v0 = binit(cval_b[col]), v1 = v0;
      gemmA(v0, v1, sm, SA_O + j*16384, wsu + OFF_CV, wsu + OFF_CV + 16384, 128, col, 0, lane);
      v0 = lrelu4(v0); v1 = lrelu4(v1);
      #pragma unroll
      for (int i = 0; i < NAG; ++i){
        if (i == j) continue;
        f32x4& o0 = (i == 0) ? oc00 : ((i == 1) ? oc10 : oc20);
        f32x4& o1 = (i == 0) ? oc01 : ((i == 1) ? oc11 : oc21);
        #pragma unroll
        for (int r = 0; r < 4; ++r){
          int row0 = ((lane >> 4) << 2) + r;
          o0[r] += LW[(i*3 + j)*32 + row0]      * v0[r];
          o1[r] += LW[(i*3 + j)*32 + row0 + 16] * v1[r];
        }
      }
    }
  }
  __syncthreads();
  #pragma unroll 1
  for (int i = 0; i < NAG; ++i){
    const unsigned short* swh = wsu + OFF_SW(i);
    const unsigned short* swl = swh + 28672;
    f32x4 se0 = binit(senc_b[i*HD + col]), se1 = se0;
    gemmS(se0, se1, sm, XN_O + i*4096, swh, swl, 768 + col, lane);
    stTile(sm, EN_O, 0, lane, col, lrelu4(se0));
    stTile(sm, EN_O, 1, lane, col, lrelu4(se1));
    {
      f32x4 o0 = (i == 0) ? oc00 : ((i == 1) ? oc10 : oc20);
      f32x4 o1 = (i == 0) ? oc01 : ((i == 1) ? oc11 : oc21);
      stTile(sm, OV0_O, 0, lane, col, o0);
      stTile(sm, OV0_O, 1, lane, col, o1);
    }
    __syncthreads();
    const unsigned short* c1h = wsu + OFF_C1(i);
    const unsigned short* c1l = c1h + 32768;
    f32x4 h0 = binit(cb1[i*HD + col]), h1 = h0;
    gemmA(h0, h1, sm, EN_O,  c1h, c1l, 256, col, 0,   lane);
    gemmA(h0, h1, sm, OV0_O, c1h, c1l, 256, col, 128, lane);
    stTile(sm, SLICE_O, 0, lane, col, lrelu4(h0));
    stTile(sm, SLICE_O, 1, lane, col, lrelu4(h1));
    __syncthreads();
    f32x4 q0 = Z, q1 = Z;
    gemmA(q0, q1, sm, SLICE_O, wsu + OFF_C2(i), wsu + OFF_C2(i) + 2048, 128, (lane & 15), 0, lane);
    if (wave == 0 && (lane & 15) < 2){
      int c2 = lane & 15;
      float bb = cb2[i*2 + c2];
      #pragma unroll
      for (int r = 0; r < 4; ++r){
        int row = ((lane >> 4) << 2) + r;
        out[((size_t)i*BATCH + gb0 + row)*2 + c2]      = q0[r] + bb;
        out[((size_t)i*BATCH + gb0 + row + 16)*2 + c2] = q1[r] + bb;
      }
    }
    __syncthreads();
  }
}

// ------------------------------------------------------------ launch -----
extern "C" void kernel_launch(void* const* d_in, const int* in_sizes, int n_in,
                              void* d_out, int out_size, void* d_ws, size_t ws_size,
                              hipStream_t stream) {
  const float* s       = (const float*)d_in[0];
  const float* a       = (const float*)d_in[1];
  const float* en_W    = (const float*)d_in[2];
  const float* en_b    = (const float*)d_in[3];
  const float* oa_W    = (const float*)d_in[4];
  const float* oa_b    = (const float*)d_in[5];
  const float* goal_W  = (const float*)d_in[6];
  const float* goal_b  = (const float*)d_in[7];
  const float* akey_W  = (const float*)d_in[8];
  const float* asel_W  = (const float*)d_in[9];
  const float* aval_W  = (const float*)d_in[10];
  const float* aval_b  = (const float*)d_in[11];
  const float* merge_W = (const float*)d_in[12];
  const float* merge_b = (const float*)d_in[13];
  const float* senc_W  = (const float*)d_in[14];
  const float* senc_b  = (const float*)d_in[15];
  const float* ckey_W  = (const float*)d_in[16];
  const float* csel_W  = (const float*)d_in[17];
  const float* cval_W  = (const float*)d_in[18];
  const float* cval_b  = (const float*)d_in[19];
  const float* cW1     = (const float*)d_in[20];
  const float* cb1     = (const float*)d_in[21];
  const float* cW2     = (const float*)d_in[22];
  const float* cb2     = (const float*)d_in[23];
  unsigned char* wsc = (unsigned char*)d_ws;
  float* F = (float*)(wsc + WSB_F);
  unsigned short* wsu = (unsigned short*)(wsc + WSB_W);
  float* out = (float*)d_out;

  hipMemsetAsync(wsc + WSB_ACCUM, 0, 480, stream);
  stats_partial_kernel<<<48, 256, 0, stream>>>(s, a, (float*)(wsc + WSB_ACCUM));
  fuse_mats_kernel<<<dim3(HD, 4), HD, 0, stream>>>(
      asel_W, akey_W, csel_W, ckey_W, F,
      (const float*)(wsc + WSB_ACCUM), (float*)(wsc + WSB_STATS));
  prep_split_kernel<<<dim3(336, 16), 256, 0, stream>>>(
      F, aval_W, cval_W, merge_W, cW1, cW2, en_W, oa_W, goal_W, senc_W, wsu);

  if (ws_size >= (size_t)WSB_SA + SA_BYTES_P){
    unsigned short* sa_g = (unsigned short*)(wsc + WSB_SA);
    actor_kernel<<<dim3(NBLK, NAG), 768, 0, stream>>>(
        s, a, en_b, oa_b, goal_b, aval_b, merge_b,
        (const unsigned char*)wsc, sa_g);
    critic_kernel<<<dim3(NBLK, NAG), 768, 0, stream>>>(
        s, a, senc_b, cval_b, cb1, cW2, cb2,
        (const unsigned char*)wsc, (const unsigned short*)sa_g, out);
  } else {
    fused_kernel<<<BATCH / TB, 512, 0, stream>>>(
        s, a, en_b, oa_b, goal_b, aval_b, merge_b, senc_b, cval_b, cb1, cb2,
        (const unsigned char*)wsc, out);
  }
}

// Round 13
// 252.649 us; speedup vs baseline: 2.1035x; 2.1035x over previous
//
#include <hip/hip_runtime.h>

#define NAG 3
#define BATCH 32768
#define HD 128
#define SD 18
#define TB 32
#define ROWS 48
#define NBLK 683
#define PADB (NBLK * ROWS)     // 32784
#define EPSV 1e-5f
#define SCALE 0.08838834764831845f

typedef __attribute__((ext_vector_type(8))) short short8;
typedef __attribute__((ext_vector_type(4))) float f32x4;

// ---------------- ws byte layout ----------------
#define WSB_STATS 0
#define WSB_ACCUM 512
#define WSB_F     1024
#define WSB_W     197632
#define OFF_FT0 0
#define OFF_FT1 32768
#define OFF_MT  65536
#define OFF_AV0 98304
#define OFF_AV1 131072
#define OFF_CV  163840
#define OFF_MG(n) (196608 + (n)*98304)
#define OFF_C1(n) (491520 + (n)*65536)
#define OFF_C2(n) (688128 + (n)*4096)
#define OFF_SW(n) (700416 + (n)*57344)
#define WSB_SA  2097152
#define SA_BYTES_P ((size_t)NAG * PADB * HD * 2)

__device__ __forceinline__ float lrelu(float x){ return x >= 0.0f ? x : 0.01f * x; }
__device__ __forceinline__ f32x4 lrelu4(f32x4 v){
  f32x4 r; r[0]=lrelu(v[0]); r[1]=lrelu(v[1]); r[2]=lrelu(v[2]); r[3]=lrelu(v[3]); return r;
}
__device__ __forceinline__ f32x4 binit(float b){ f32x4 c; c[0]=b;c[1]=b;c[2]=b;c[3]=b; return c; }
__device__ __forceinline__ unsigned short f2bf(float f){
  unsigned int u = __float_as_uint(f);
  unsigned int r = (u + 0x7FFFu + ((u >> 16) & 1u)) >> 16;
  return (unsigned short)r;
}
__device__ __forceinline__ float bf2f(unsigned short h){
  return __uint_as_float(((unsigned int)h) << 16);
}

// ---------------- prep: batch stats ----------------
__global__ void stats_partial_kernel(const float* __restrict__ s,
                                     const float* __restrict__ a,
                                     float* __restrict__ accum){
  const int n = blockIdx.x >> 4;
  const int chunk = blockIdx.x & 15;
  const int t = threadIdx.x;
  const int rows = BATCH / 16;
  const int b0 = chunk * rows;
  float sum[20], sq[20];
  #pragma unroll
  for (int c = 0; c < 20; ++c){ sum[c] = 0.f; sq[c] = 0.f; }
  for (int b = b0 + t; b < b0 + rows; b += 256){
    const float* row = s + ((size_t)n * BATCH + b) * SD;
    #pragma unroll
    for (int c = 0; c < SD; ++c){ float v = row[c]; sum[c] += v; sq[c] += v * v; }
    const float* ra = a + ((size_t)n * BATCH + b) * 2;
    #pragma unroll
    for (int c = 0; c < 2; ++c){ float v = ra[c]; sum[SD + c] += v; sq[SD + c] += v * v; }
  }
  __shared__ float red[256];
  for (int c = 0; c < 20; ++c){
    red[t] = sum[c]; __syncthreads();
    for (int off = 128; off > 0; off >>= 1){ if (t < off) red[t] += red[t + off]; __syncthreads(); }
    if (t == 0) atomicAdd(&accum[(n * 20 + c) * 2 + 0], red[0]);
    __syncthreads();
    red[t] = sq[c]; __syncthreads();
    for (int off = 128; off > 0; off >>= 1){ if (t < off) red[t] += red[t + off]; __syncthreads(); }
    if (t == 0) atomicAdd(&accum[(n * 20 + c) * 2 + 1], red[0]);
    __syncthreads();
  }
}

// ---------------- prep: F_m = sel @ key^T + stats finalize ----------------
__global__ void fuse_mats_kernel(const float* __restrict__ asel, const float* __restrict__ akey,
                                 const float* __restrict__ csel, const float* __restrict__ ckey,
                                 float* __restrict__ F, const float* __restrict__ accum,
                                 float* __restrict__ stats){
  const int m  = blockIdx.y;
  if (m == 3){
    if (blockIdx.x == 0){
      int i = threadIdx.x;
      if (i < 60){
        float S = accum[i * 2 + 0], SQ = accum[i * 2 + 1];
        float mean = S / (float)BATCH;
        float var = SQ / (float)BATCH - mean * mean;
        stats[i * 2 + 0] = mean;
        stats[i * 2 + 1] = 1.0f / sqrtf(var + EPSV);
      }
    }
    return;
  }
  const int h1 = blockIdx.x;
  const int h2 = threadIdx.x;
  const float* A; const float* Bm;
  if (m == 0){ A = asel;            Bm = akey; }
  else if (m == 1){ A = asel + HD*HD; Bm = akey + HD*HD; }
  else { A = csel; Bm = ckey; }
  const float* arow = A + h1 * HD;
  const float* brow = Bm + h2 * HD;
  float acc = 0.f;
  #pragma unroll 4
  for (int d = 0; d < HD; ++d) acc = fmaf(arow[d], brow[d], acc);
  F[m * HD * HD + h1 * HD + h2] = acc;
}

// ---------------- prep: all weight splits + smallpack ----------------
__global__ void prep_split_kernel(const float* __restrict__ F, const float* __restrict__ aval_W,
                                  const float* __restrict__ cval_W, const float* __restrict__ merge_W,
                                  const float* __restrict__ cW1, const float* __restrict__ cW2,
                                  const float* __restrict__ en_W, const float* __restrict__ oa_W,
                                  const float* __restrict__ goal_W, const float* __restrict__ senc_W,
                                  unsigned short* __restrict__ wsu){
  const int job = blockIdx.y;
  const int idx = blockIdx.x * 256 + threadIdx.x;
  if (job == 15){
    if (idx >= 3 * 896 * 32) return;
    int k = idx & 31; int c = (idx >> 5) % 896; int n = idx / (896 * 32);
    int tt = c >> 7, cc = c & 127;
    float v = 0.f;
    if (tt == 0){
      if (k < 4) v = en_W[(size_t)(n*6 + k)*128 + cc];
      else if (k == 18 || k == 19) v = en_W[(size_t)(n*6 + 4 + (k-18))*128 + cc];
    } else if (tt <= 2){
      int j = tt - 1; int kk = k - (4 + 4*j);
      if (kk >= 0 && kk < 4) v = oa_W[(size_t)(n*4 + kk)*128 + cc];
    } else if (tt <= 5){
      int j = tt - 3; int kk = k - (12 + 2*j);
      if (kk >= 0 && kk < 2) v = goal_W[(size_t)(n*2 + kk)*128 + cc];
    } else {
      if (k < 18) v = senc_W[(size_t)(n*18 + k)*128 + cc];
    }
    unsigned short hi = f2bf(v); float lo = v - bf2f(hi);
    unsigned short* dh = wsu + OFF_SW(n);
    dh[c * 32 + k] = hi;
    dh[28672 + c * 32 + k] = f2bf(lo);
    return;
  }
  const float* src; unsigned short* dh; int K = 128, Csrc = 128, Cdst = 128, loff = 16384;
  switch (job){
    case 0: src = F;              dh = wsu + OFF_FT0; break;
    case 1: src = F + 16384;      dh = wsu + OFF_FT1; break;
    case 2: src = F + 32768;      dh = wsu + OFF_MT;  break;
    case 3: src = aval_W;         dh = wsu + OFF_AV0; break;
    case 4: src = aval_W + 16384; dh = wsu + OFF_AV1; break;
    case 5: src = cval_W;         dh = wsu + OFF_CV;  break;
    case 6: case 7: case 8: {
      int n = job - 6; src = merge_W + (size_t)n * 49152; dh = wsu + OFF_MG(n);
      K = 384; loff = 49152; } break;
    case 9: case 10: case 11: {
      int n = job - 9; src = cW1 + (size_t)n * 32768; dh = wsu + OFF_C1(n);
      K = 256; loff = 32768; } break;
    default: {
      int n = job - 12; src = cW2 + (size_t)n * 256; dh = wsu + OFF_C2(n);
      Csrc = 2; Cdst = 16; loff = 2048; } break;
  }
  if (idx >= K * Cdst) return;
  int k = idx / Cdst, c = idx - k * Cdst;
  float v = (c < Csrc) ? src[(size_t)k * Csrc + c] : 0.f;
  unsigned short hi = f2bf(v);
  dh[(size_t)c * K + k] = hi;
  dh[loff + (size_t)c * K + k] = f2bf(v - bf2f(hi));
}

// ---------------- MFMA helpers (shared) ----------------
__device__ __forceinline__ short8 ldAh(const unsigned char* sm, int base, int mi, int ks, int lane){
  int row = mi * 16 + (lane & 15);
  int bc  = ks * 64 + ((lane >> 4) << 4);
  return *(const short8*)(sm + base + row * 256 + (bc ^ ((row & 7) << 4)));
}
__device__ __forceinline__ void ldA(const unsigned char* sm, int base, int mi, int ks, int lane,
                                    short8& h, short8& l){
  int row = mi * 16 + (lane & 15);
  int bc  = ks * 64 + ((lane >> 4) << 4);
  int off = base + row * 256 + (bc ^ ((row & 7) << 4));
  h = *(const short8*)(sm + off);
  l = *(const short8*)(sm + off + 8192);
}
__device__ __forceinline__ void ldA32(const unsigned char* sm, int base, int mi, int lane,
                                      short8& h, short8& l){
  int row = mi * 16 + (lane & 15);
  int bc  = (lane >> 4) << 4;
  int off = base + row * 64 + (bc ^ ((row & 3) << 4));
  h = *(const short8*)(sm + off);
  l = *(const short8*)(sm + off + 2048);
}
__device__ __forceinline__ void ldA32_48(const unsigned char* sm, int base, int mi, int lane,
                                         short8& h, short8& l){
  int row = mi * 16 + (lane & 15);
  int bc  = (lane >> 4) << 4;
  int off = base + row * 64 + (bc ^ ((row & 3) << 4));
  h = *(const short8*)(sm + off);
  l = *(const short8*)(sm + off + 3072);
}

#define MM3(acc, ah, al, bh, bl) \
  acc = __builtin_amdgcn_mfma_f32_16x16x32_bf16(ah, bh, acc, 0, 0, 0); \
  acc = __builtin_amdgcn_mfma_f32_16x16x32_bf16(ah, bl, acc, 0, 0, 0); \
  acc = __builtin_amdgcn_mfma_f32_16x16x32_bf16(al, bh, acc, 0, 0, 0);
#define MM2(acc, ah, bh, bl) \
  acc = __builtin_amdgcn_mfma_f32_16x16x32_bf16(ah, bh, acc, 0, 0, 0); \
  acc = __builtin_amdgcn_mfma_f32_16x16x32_bf16(ah, bl, acc, 0, 0, 0);
#define MM1(acc, ah, bh) \
  acc = __builtin_amdgcn_mfma_f32_16x16x32_bf16(ah, bh, acc, 0, 0, 0);

// ---------------- TB=48 (3 m-tile) helpers ----------------
__device__ __forceinline__ void gemmS3(f32x4& c0, f32x4& c1, f32x4& c2,
                                       const unsigned char* sm, int abase,
                                       const unsigned short* wh, const unsigned short* wl,
                                       int bcol, int lane){
  const size_t bb = (size_t)bcol * 32 + ((lane >> 4) << 3);
  const short8 bh = *(const short8*)(wh + bb);
  const short8 bl = *(const short8*)(wl + bb);
  short8 ah, al;
  ldA32_48(sm, abase, 0, lane, ah, al); MM3(c0, ah, al, bh, bl);
  ldA32_48(sm, abase, 1, lane, ah, al); MM3(c1, ah, al, bh, bl);
  ldA32_48(sm, abase, 2, lane, ah, al); MM3(c2, ah, al, bh, bl);
}
__device__ __forceinline__ void gemmAW2_3(f32x4& k0, f32x4& k1, f32x4& k2,
                                          f32x4& m0, f32x4& m1, f32x4& m2,
                                          const unsigned char* sm, int abase,
                                          const unsigned short* wh0, const unsigned short* wh1,
                                          int bcol, int lane){
  const size_t bb = (size_t)bcol * 128 + ((lane >> 4) << 3);
  #pragma unroll
  for (int ks = 0; ks < 4; ++ks){
    short8 a0 = ldAh(sm, abase, 0, ks, lane);
    short8 a1 = ldAh(sm, abase, 1, ks, lane);
    short8 a2 = ldAh(sm, abase, 2, ks, lane);
    const short8 b0 = *(const short8*)(wh0 + bb + ks * 32);
    const short8 b1 = *(const short8*)(wh1 + bb + ks * 32);
    MM1(k0, a0, b0); MM1(k1, a1, b0); MM1(k2, a2, b0);
    MM1(m0, a0, b1); MM1(m1, a1, b1); MM1(m2, a2, b1);
  }
}
__device__ __forceinline__ void gemmA2s3(f32x4& c0, f32x4& c1, f32x4& c2,
                                         f32x4& d0, f32x4& d1, f32x4& d2,
                                         const unsigned char* sm, int a0b, int a1b,
                                         const unsigned short* wh, int bcol, int lane){
  const size_t bb = (size_t)bcol * 128 + ((lane >> 4) << 3);
  #pragma unroll
  for (int ks = 0; ks < 4; ++ks){
    const short8 bh = *(const short8*)(wh + bb + ks * 32);
    short8 x;
    x = ldAh(sm, a0b, 0, ks, lane); MM1(c0, x, bh);
    x = ldAh(sm, a0b, 1, ks, lane); MM1(c1, x, bh);
    x = ldAh(sm, a0b, 2, ks, lane); MM1(c2, x, bh);
    x = ldAh(sm, a1b, 0, ks, lane); MM1(d0, x, bh);
    x = ldAh(sm, a1b, 1, ks, lane); MM1(d1, x, bh);
    x = ldAh(sm, a1b, 2, ks, lane); MM1(d2, x, bh);
  }
}
__device__ __forceinline__ void gemmA3s3(f32x4& c0, f32x4& c1, f32x4& c2,
                                         f32x4& d0, f32x4& d1, f32x4& d2,
                                         f32x4& e0, f32x4& e1, f32x4& e2,
                                         const unsigned char* sm, int a0b, int a1b, int a2b,
                                         const unsigned short* wh, int bcol, int lane){
  const size_t bb = (size_t)bcol * 128 + ((lane >> 4) << 3);
  #pragma unroll
  for (int ks = 0; ks < 4; ++ks){
    const short8 bh = *(const short8*)(wh + bb + ks * 32);
    short8 x;
    x = ldAh(sm, a0b, 0, ks, lane); MM1(c0, x, bh);
    x = ldAh(sm, a0b, 1, ks, lane); MM1(c1, x, bh);
    x = ldAh(sm, a0b, 2, ks, lane); MM1(c2, x, bh);
    x = ldAh(sm, a1b, 0, ks, lane); MM1(d0, x, bh);
    x = ldAh(sm, a1b, 1, ks, lane); MM1(d1, x, bh);
    x = ldAh(sm, a1b, 2, ks, lane); MM1(d2, x, bh);
    x = ldAh(sm, a2b, 0, ks, lane); MM1(e0, x, bh);
    x = ldAh(sm, a2b, 1, ks, lane); MM1(e1, x, bh);
    x = ldAh(sm, a2b, 2, ks, lane); MM1(e2, x, bh);
  }
}
__device__ __forceinline__ void gemmAh3(f32x4& c0, f32x4& c1, f32x4& c2,
                                        const unsigned char* sm, int abase,
                                        const unsigned short* wh, const unsigned short* wl,
                                        int K, int bcol, int kBase, int lane){
  const size_t bb = (size_t)bcol * K + kBase + ((lane >> 4) << 3);
  #pragma unroll
  for (int ks = 0; ks < 4; ++ks){
    const short8 bh = *(const short8*)(wh + bb + ks * 32);
    const short8 bl = *(const short8*)(wl + bb + ks * 32);
    short8 a;
    a = ldAh(sm, abase, 0, ks, lane); MM2(c0, a, bh, bl);
    a = ldAh(sm, abase, 1, ks, lane); MM2(c1, a, bh, bl);
    a = ldAh(sm, abase, 2, ks, lane); MM2(c2, a, bh, bl);
  }
}
__device__ __forceinline__ void gemmAh_hb3(f32x4& c0, f32x4& c1, f32x4& c2,
                                           const unsigned char* sm, int abase,
                                           const unsigned short* wh, int bcol, int lane){
  const size_t bb = (size_t)bcol * 128 + ((lane >> 4) << 3);
  #pragma unroll
  for (int ks = 0; ks < 4; ++ks){
    const short8 bh = *(const short8*)(wh + bb + ks * 32);
    short8 a;
    a = ldAh(sm, abase, 0, ks, lane); MM1(c0, a, bh);
    a = ldAh(sm, abase, 1, ks, lane); MM1(c1, a, bh);
    a = ldAh(sm, abase, 2, ks, lane); MM1(c2, a, bh);
  }
}

// stores
__device__ __forceinline__ void stTile(unsigned char* sm, int base, int mi, int lane, int col, f32x4 v){
  #pragma unroll
  for (int r = 0; r < 4; ++r){
    int row = mi * 16 + ((lane >> 4) << 2) + r;
    int off = base + row * 256 + ((col * 2) ^ ((row & 7) << 4));
    unsigned short hi = f2bf(v[r]);
    *(unsigned short*)(sm + off) = hi;
    *(unsigned short*)(sm + off + 8192) = f2bf(v[r] - bf2f(hi));
  }
}
__device__ __forceinline__ void stTileC(unsigned char* sm, int base, int mi, int lane, int col, f32x4 v){
  #pragma unroll
  for (int r = 0; r < 4; ++r){
    int row = mi * 16 + ((lane >> 4) << 2) + r;
    int off = base + row * 256 + ((col * 2) ^ ((row & 7) << 4));
    unsigned short hi = f2bf(v[r]);
    *(unsigned short*)(sm + off) = hi;
    *(unsigned short*)(sm + off + 12288) = f2bf(v[r] - bf2f(hi));
  }
}
__device__ __forceinline__ void stH(unsigned char* sm, int base, int mi, int lane, int col, f32x4 v){
  #pragma unroll
  for (int r = 0; r < 4; ++r){
    int row = mi * 16 + ((lane >> 4) << 2) + r;
    int off = base + row * 256 + ((col * 2) ^ ((row & 7) << 4));
    *(unsigned short*)(sm + off) = f2bf(v[r]);
  }
}
__device__ __forceinline__ void stSK(unsigned char* sm, int base, int mi, int lane, int col, f32x4 v){
  #pragma unroll
  for (int r = 0; r < 4; ++r){
    int row = mi * 16 + ((lane >> 4) << 2) + r;
    int off = base + row * 256 + ((col * 2) ^ ((row & 7) << 5));
    *(unsigned short*)(sm + off) = f2bf(v[r]);
  }
}
__device__ __forceinline__ float dot8(short8 x, short8 y){
  float acc = 0.f;
  #pragma unroll
  for (int e = 0; e < 8; ++e)
    acc = fmaf(bf2f((unsigned short)x[e]), bf2f((unsigned short)y[e]), acc);
  return acc;
}
#define RED16(p) { p += __shfl_xor(p, 1, 16); p += __shfl_xor(p, 2, 16); \
                   p += __shfl_xor(p, 4, 16); p += __shfl_xor(p, 8, 16); }
#define RED8(p) { p += __shfl_xor(p, 1); p += __shfl_xor(p, 2); p += __shfl_xor(p, 4); }

// ======================================================================
// PATH A: actor kernel — grid (NBLK, NAG), 512 threads, ROWS=48, 78.75KB LDS
// ======================================================================
__global__ __launch_bounds__(512, 4) void actor_kernel(
    const float* __restrict__ s, const float* __restrict__ a,
    const float* __restrict__ en_b, const float* __restrict__ oa_b,
    const float* __restrict__ goal_b, const float* __restrict__ aval_b,
    const float* __restrict__ merge_b, const unsigned char* __restrict__ wsc,
    unsigned short* __restrict__ sa_g)
{
  __shared__ __align__(16) unsigned char SM[80640];
  const int AXN = 0, AEN = 6144, AOV = 18432, ASK = 30720;
  const int SLB0 = 43008, SLB1 = 55296, SLB2 = 67584, AEP = 79872;
  const int t = threadIdx.x, lane = t & 63, wave = t >> 6;
  const int col = wave * 16 + (lane & 15);
  const int n = blockIdx.y;
  const int gb0 = blockIdx.x * ROWS;
  const float* stats = (const float*)(wsc + WSB_STATS);
  const unsigned short* wsu = (const unsigned short*)(wsc + WSB_W);
  const unsigned short* swh = wsu + OFF_SW(n);
  const unsigned short* swl = swh + 28672;
  float* eP0 = (float*)(SM + AEP);
  float* eP1 = eP0 + 48;
  float* eP2 = eP0 + 96;
  float* esm = eP0 + 144;
  const f32x4 Z = binit(0.f);
  const int drow = wave * 8 + (lane >> 3);
  const int dcb  = (lane & 7) * 32;
  const int r0base = (lane >> 4) << 2;

  // init: stage normalized XN (split, K=32), clamped reads
  if (t < ROWS){
    int row = t;
    size_t gb = (size_t)gb0 + row;
    if (gb >= BATCH) gb = BATCH - 1;
    const float* st = stats + n * 40;
    const float* srow = s + ((size_t)n * BATCH + gb) * SD;
    const float* arow = a + ((size_t)n * BATCH + gb) * 2;
    #pragma unroll
    for (int c = 0; c < 32; ++c){
      float v = 0.f;
      if (c < 18) v = (srow[c] - st[c*2]) * st[c*2+1];
      else if (c < 20) v = (arow[c-18] - st[c*2]) * st[c*2+1];
      unsigned short hi = f2bf(v);
      int off = AXN + row * 64 + ((c * 2) ^ ((row & 3) << 4));
      *(unsigned short*)(SM + off) = hi;
      *(unsigned short*)(SM + off + 3072) = f2bf(v - bf2f(hi));
    }
  }
  __syncthreads();
  // R0: en_enc -> AEN ; oa slices -> SLB0, SLB1
  {
    f32x4 c0 = binit(en_b[n*HD + col]), c1 = c0, c2 = c0;
    gemmS3(c0, c1, c2, SM, AXN, swh, swl, col, lane);
    stH(SM, AEN, 0, lane, col, lrelu4(c0));
    stH(SM, AEN, 1, lane, col, lrelu4(c1));
    stH(SM, AEN, 2, lane, col, lrelu4(c2));
    const float bb = oa_b[n*HD + col];
    c0 = binit(bb); c1 = c0; c2 = c0;
    gemmS3(c0, c1, c2, SM, AXN, swh, swl, 128 + col, lane);
    stH(SM, SLB0, 0, lane, col, lrelu4(c0));
    stH(SM, SLB0, 1, lane, col, lrelu4(c1));
    stH(SM, SLB0, 2, lane, col, lrelu4(c2));
    c0 = binit(bb); c1 = c0; c2 = c0;
    gemmS3(c0, c1, c2, SM, AXN, swh, swl, 256 + col, lane);
    stH(SM, SLB1, 0, lane, col, lrelu4(c0));
    stH(SM, SLB1, 1, lane, col, lrelu4(c1));
    stH(SM, SLB1, 2, lane, col, lrelu4(c2));
  }
  __syncthreads();
  // R1: selk0 -> AOV, selk1 -> ASK (hi-B)
  {
    f32x4 k0 = Z, k1 = Z, k2 = Z, m0 = Z, m1 = Z, m2 = Z;
    gemmAW2_3(k0, k1, k2, m0, m1, m2, SM, AEN,
              wsu + OFF_FT0, wsu + OFF_FT1, col, lane);
    stSK(SM, AOV, 0, lane, col, k0); stSK(SM, AOV, 1, lane, col, k1); stSK(SM, AOV, 2, lane, col, k2);
    stSK(SM, ASK, 0, lane, col, m0); stSK(SM, ASK, 1, lane, col, m1); stSK(SM, ASK, 2, lane, col, m2);
  }
  __syncthreads();
  // R2: oa vals (both slices, shared hi-B) + logit dots + exp
  f32x4 va0, va1, va2, vb0, vb1, vb2;
  {
    const float vb = aval_b[col];
    va0 = binit(vb); va1 = va0; va2 = va0; vb0 = va0; vb1 = va0; vb2 = va0;
    gemmA2s3(va0, va1, va2, vb0, vb1, vb2, SM, SLB0, SLB1, wsu + OFF_AV0, col, lane);
    if (drow < ROWS){
      int sw5 = (drow & 7) << 5, sw4 = (drow & 7) << 4;
      const unsigned char* kb = SM + AOV + drow * 256;
      short8 kfa = *(const short8*)(kb + (dcb ^ sw5));
      short8 kfb = *(const short8*)(kb + ((dcb + 16) ^ sw5));
      const unsigned char* s0 = SM + SLB0 + drow * 256;
      short8 e0a = *(const short8*)(s0 + (dcb ^ sw4));
      short8 e0b = *(const short8*)(s0 + ((dcb + 16) ^ sw4));
      const unsigned char* s1 = SM + SLB1 + drow * 256;
      short8 e1a = *(const short8*)(s1 + (dcb ^ sw4));
      short8 e1b = *(const short8*)(s1 + ((dcb + 16) ^ sw4));
      float p0 = dot8(kfa, e0a) + dot8(kfb, e0b);
      float p1 = dot8(kfa, e1a) + dot8(kfb, e1b);
      RED8(p0) RED8(p1)
      if ((lane & 7) == 0){
        float e0 = __expf(p0 * SCALE), e1 = __expf(p1 * SCALE);
        eP0[drow] = e0; eP1[drow] = e1; esm[drow] = e0 + e1;
      }
    }
  }
  __syncthreads();
  // R3: ov0 -> AOV ; goal slices g0,g1,g2 -> SLB0,1,2
  {
    f32x4 o;
    #pragma unroll
    for (int r = 0; r < 4; ++r){
      int mr = r0base + r;
      o[r] = (eP0[mr] * lrelu(va0[r]) + eP1[mr] * lrelu(vb0[r])) / esm[mr];
    }
    stH(SM, AOV, 0, lane, col, o);
    #pragma unroll
    for (int r = 0; r < 4; ++r){
      int mr = 16 + r0base + r;
      o[r] = (eP0[mr] * lrelu(va1[r]) + eP1[mr] * lrelu(vb1[r])) / esm[mr];
    }
    stH(SM, AOV, 1, lane, col, o);
    #pragma unroll
    for (int r = 0; r < 4; ++r){
      int mr = 32 + r0base + r;
      o[r] = (eP0[mr] * lrelu(va2[r]) + eP1[mr] * lrelu(vb2[r])) / esm[mr];
    }
    stH(SM, AOV, 2, lane, col, o);
    const float bb = goal_b[n*HD + col];
    f32x4 c0 = binit(bb), c1 = c0, c2 = c0;
    gemmS3(c0, c1, c2, SM, AXN, swh, swl, 384 + col, lane);
    stH(SM, SLB0, 0, lane, col, lrelu4(c0));
    stH(SM, SLB0, 1, lane, col, lrelu4(c1));
    stH(SM, SLB0, 2, lane, col, lrelu4(c2));
    c0 = binit(bb); c1 = c0; c2 = c0;
    gemmS3(c0, c1, c2, SM, AXN, swh, swl, 512 + col, lane);
    stH(SM, SLB1, 0, lane, col, lrelu4(c0));
    stH(SM, SLB1, 1, lane, col, lrelu4(c1));
    stH(SM, SLB1, 2, lane, col, lrelu4(c2));
    c0 = binit(bb); c1 = c0; c2 = c0;
    gemmS3(c0, c1, c2, SM, AXN, swh, swl, 640 + col, lane);
    stH(SM, SLB2, 0, lane, col, lrelu4(c0));
    stH(SM, SLB2, 1, lane, col, lrelu4(c1));
    stH(SM, SLB2, 2, lane, col, lrelu4(c2));
  }
  __syncthreads();
  // R4: goal vals (3 slices x 3 mt, shared hi-B) + 3 dots + exps
  f32x4 g0m0, g0m1, g0m2, g1m0, g1m1, g1m2, g2m0, g2m1, g2m2;
  {
    const float vb = aval_b[HD + col];
    g0m0 = binit(vb); g0m1 = g0m0; g0m2 = g0m0;
    g1m0 = g0m0; g1m1 = g0m0; g1m2 = g0m0;
    g2m0 = g0m0; g2m1 = g0m0; g2m2 = g0m0;
    gemmA3s3(g0m0, g0m1, g0m2, g1m0, g1m1, g1m2, g2m0, g2m1, g2m2,
             SM, SLB0, SLB1, SLB2, wsu + OFF_AV1, col, lane);
    if (drow < ROWS){
      int sw5 = (drow & 7) << 5, sw4 = (drow & 7) << 4;
      const unsigned char* kb = SM + ASK + drow * 256;
      short8 kfa = *(const short8*)(kb + (dcb ^ sw5));
      short8 kfb = *(const short8*)(kb + ((dcb + 16) ^ sw5));
      const unsigned char* s0 = SM + SLB0 + drow * 256;
      short8 e0a = *(const short8*)(s0 + (dcb ^ sw4));
      short8 e0b = *(const short8*)(s0 + ((dcb + 16) ^ sw4));
      const unsigned char* s1 = SM + SLB1 + drow * 256;
      short8 e1a = *(const short8*)(s1 + (dcb ^ sw4));
      short8 e1b = *(const short8*)(s1 + ((dcb + 16) ^ sw4));
      const unsigned char* s2 = SM + SLB2 + drow * 256;
      short8 e2a = *(const short8*)(s2 + (dcb ^ sw4));
      short8 e2b = *(const short8*)(s2 + ((dcb + 16) ^ sw4));
      float p0 = dot8(kfa, e0a) + dot8(kfb, e0b);
      float p1 = dot8(kfa, e1a) + dot8(kfb, e1b);
      float p2 = dot8(kfa, e2a) + dot8(kfb, e2b);
      RED8(p0) RED8(p1) RED8(p2)
      if ((lane & 7) == 0){
        float e0 = __expf(p0 * SCALE), e1 = __expf(p1 * SCALE), e2 = __expf(p2 * SCALE);
        eP0[drow] = e0; eP1[drow] = e1; eP2[drow] = e2;
        esm[drow] = (e0 + e1) + e2;
      }
    }
  }
  __syncthreads();
  // R5: ov1 -> SLB0
  {
    f32x4 o;
    #pragma unroll
    for (int r = 0; r < 4; ++r){
      int mr = r0base + r;
      o[r] = ((eP0[mr] * lrelu(g0m0[r]) + eP1[mr] * lrelu(g1m0[r]))
              + eP2[mr] * lrelu(g2m0[r])) / esm[mr];
    }
    stH(SM, SLB0, 0, lane, col, o);
    #pragma unroll
    for (int r = 0; r < 4; ++r){
      int mr = 16 + r0base + r;
      o[r] = ((eP0[mr] * lrelu(g0m1[r]) + eP1[mr] * lrelu(g1m1[r]))
              + eP2[mr] * lrelu(g2m1[r])) / esm[mr];
    }
    stH(SM, SLB0, 1, lane, col, o);
    #pragma unroll
    for (int r = 0; r < 4; ++r){
      int mr = 32 + r0base + r;
      o[r] = ((eP0[mr] * lrelu(g0m2[r]) + eP1[mr] * lrelu(g1m2[r]))
              + eP2[mr] * lrelu(g2m2[r])) / esm[mr];
    }
    stH(SM, SLB0, 2, lane, col, o);
  }
  __syncthreads();
  // R6: merge (split-B) -> SLB1
  {
    const unsigned short* mh = wsu + OFF_MG(n);
    const unsigned short* ml = mh + 49152;
    f32x4 c0 = binit(merge_b[n*HD + col]), c1 = c0, c2 = c0;
    gemmAh3(c0, c1, c2, SM, AEN,  mh, ml, 384, col, 0,   lane);
    gemmAh3(c0, c1, c2, SM, AOV,  mh, ml, 384, col, 128, lane);
    gemmAh3(c0, c1, c2, SM, SLB0, mh, ml, 384, col, 256, lane);
    stH(SM, SLB1, 0, lane, col, lrelu4(c0));
    stH(SM, SLB1, 1, lane, col, lrelu4(c1));
    stH(SM, SLB1, 2, lane, col, lrelu4(c2));
  }
  __syncthreads();
  // R7: coalesced copy SLB1 -> sa_g (padded)
  for (int idx = t; idx < ROWS * 16; idx += 512){
    int row = idx >> 4, ch = idx & 15;
    short8 u = *(const short8*)(SM + SLB1 + row * 256 + ((ch * 16) ^ ((row & 7) << 4)));
    *(short8*)(sa_g + ((size_t)n * PADB + gb0 + row) * HD + ch * 8) = u;
  }
}

// ======================================================================
// PATH A: critic kernel — grid (NBLK, NAG=i), 512 threads, ROWS=48, 66.4KB LDS
// ======================================================================
__global__ __launch_bounds__(512, 4) void critic_kernel(
    const float* __restrict__ s, const float* __restrict__ a,
    const float* __restrict__ senc_b, const float* __restrict__ cval_b,
    const float* __restrict__ cb1, const float* __restrict__ cW2,
    const float* __restrict__ cb2, const unsigned char* __restrict__ wsc,
    const unsigned short* __restrict__ sa_g, float* __restrict__ out)
{
  __shared__ __align__(16) unsigned char SM[67968];
  const int CXN = 0, CEN = 6144, CSMo = 18432, CSA = 30720, COV = 55296, CH = 30720, CLW = 67584;
  const int t = threadIdx.x, lane = t & 63, wave = t >> 6;
  const int col = wave * 16 + (lane & 15);
  const int i = blockIdx.y;
  const int gb0 = blockIdx.x * ROWS;
  const int j0 = (i == 0) ? 1 : 0;
  const int j1 = (i == 2) ? 1 : 2;
  const float* stats = (const float*)(wsc + WSB_STATS);
  const unsigned short* wsu = (const unsigned short*)(wsc + WSB_W);
  const unsigned short* swh = wsu + OFF_SW(i);
  const unsigned short* swl = swh + 28672;
  const f32x4 Z = binit(0.f);
  const int drow = wave * 8 + (lane >> 3);
  const int dcb  = (lane & 7) * 32;
  const int r0base = (lane >> 4) << 2;

  // R0: stage XN_i (split, clamped) + copy sa_j0/j1 -> LDS (hi, swz)
  if (t < ROWS){
    int row = t;
    size_t gb = (size_t)gb0 + row;
    if (gb >= BATCH) gb = BATCH - 1;
    const float* st = stats + i * 40;
    const float* srow = s + ((size_t)i * BATCH + gb) * SD;
    const float* arow = a + ((size_t)i * BATCH + gb) * 2;
    #pragma unroll
    for (int c = 0; c < 32; ++c){
      float v = 0.f;
      if (c < 18) v = (srow[c] - st[c*2]) * st[c*2+1];
      else if (c < 20) v = (arow[c-18] - st[c*2]) * st[c*2+1];
      unsigned short hi = f2bf(v);
      int off = CXN + row * 64 + ((c * 2) ^ ((row & 3) << 4));
      *(unsigned short*)(SM + off) = hi;
      *(unsigned short*)(SM + off + 3072) = f2bf(v - bf2f(hi));
    }
  }
  for (int idx = t; idx < 2 * ROWS * 16; idx += 512){
    int tile = idx >= ROWS * 16;
    int k = idx - tile * ROWS * 16;
    int row = k >> 4, ch = k & 15;
    int j = tile ? j1 : j0;
    short8 u = *(const short8*)(sa_g + ((size_t)j * PADB + gb0 + row) * HD + ch * 8);
    *(short8*)(SM + CSA + tile * 12288 + row * 256 + ((ch * 16) ^ ((row & 7) << 4))) = u;
  }
  __syncthreads();
  // R1: s_enc -> CEN (hi)
  {
    f32x4 c0 = binit(senc_b[i*HD + col]), c1 = c0, c2 = c0;
    gemmS3(c0, c1, c2, SM, CXN, swh, swl, 768 + col, lane);
    stH(SM, CEN, 0, lane, col, lrelu4(c0));
    stH(SM, CEN, 1, lane, col, lrelu4(c1));
    stH(SM, CEN, 2, lane, col, lrelu4(c2));
  }
  __syncthreads();
  // R2: selsM = s_enc @ M (hi-B) -> CSM (32B-swz)
  {
    f32x4 k0 = Z, k1 = Z, k2 = Z;
    gemmAh_hb3(k0, k1, k2, SM, CEN, wsu + OFF_MT, col, lane);
    stSK(SM, CSMo, 0, lane, col, k0);
    stSK(SM, CSMo, 1, lane, col, k1);
    stSK(SM, CSMo, 2, lane, col, k2);
  }
  __syncthreads();
  // R3: vals GEMMs (2 sa-tiles x 3 mt, shared hi-B) + dots + 2-way softmax
  f32x4 v00, v01, v02, v10, v11, v12;
  {
    const float vb = cval_b[col];
    v00 = binit(vb); v01 = v00; v02 = v00; v10 = v00; v11 = v00; v12 = v00;
    gemmA2s3(v00, v01, v02, v10, v11, v12, SM, CSA, CSA + 12288,
             wsu + OFF_CV, col, lane);
    if (drow < ROWS){
      int sw5 = (drow & 7) << 5, sw4 = (drow & 7) << 4;
      const unsigned char* mb = SM + CSMo + drow * 256;
      short8 ma = *(const short8*)(mb + (dcb ^ sw5));
      short8 mbf = *(const short8*)(mb + ((dcb + 16) ^ sw5));
      const unsigned char* a0p = SM + CSA + drow * 256;
      short8 a0a = *(const short8*)(a0p + (dcb ^ sw4));
      short8 a0b = *(const short8*)(a0p + ((dcb + 16) ^ sw4));
      const unsigned char* b0p = SM + CSA + 12288 + drow * 256;
      short8 b0a = *(const short8*)(b0p + (dcb ^ sw4));
      short8 b0b = *(const short8*)(b0p + ((dcb + 16) ^ sw4));
      float p0 = dot8(ma, a0a) + dot8(mbf, a0b);
      float p1 = dot8(ma, b0a) + dot8(mbf, b0b);
      RED8(p0) RED8(p1)
      if ((lane & 7) == 0){
        float e0 = __expf(p0 * SCALE), e1 = __expf(p1 * SCALE);
        float inv = 1.f / (e0 + e1);
        ((float*)(SM + CLW))[drow]      = e0 * inv;
        ((float*)(SM + CLW))[48 + drow] = e1 * inv;
      }
    }
  }
  __syncthreads();
  // R4: ov -> COV (hi)
  {
    const float* w0 = (const float*)(SM + CLW);
    const float* w1 = w0 + 48;
    f32x4 o;
    #pragma unroll
    for (int r = 0; r < 4; ++r){
      int mr = r0base + r;
      o[r] = w0[mr] * lrelu(v00[r]) + w1[mr] * lrelu(v10[r]);
    }
    stH(SM, COV, 0, lane, col, o);
    #pragma unroll
    for (int r = 0; r < 4; ++r){
      int mr = 16 + r0base + r;
      o[r] = w0[mr] * lrelu(v01[r]) + w1[mr] * lrelu(v11[r]);
    }
    stH(SM, COV, 1, lane, col, o);
    #pragma unroll
    for (int r = 0; r < 4; ++r){
      int mr = 32 + r0base + r;
      o[r] = w0[mr] * lrelu(v02[r]) + w1[mr] * lrelu(v12[r]);
    }
    stH(SM, COV, 2, lane, col, o);
  }
  __syncthreads();
  // R5: h = lrelu([s_enc|ov] @ cW1 + b) -> CH (split; overwrites CSA)
  {
    const unsigned short* c1h = wsu + OFF_C1(i);
    const unsigned short* c1l = c1h + 32768;
    f32x4 h0 = binit(cb1[i*HD + col]), h1 = h0, h2 = h0;
    gemmAh3(h0, h1, h2, SM, CEN, c1h, c1l, 256, col, 0,   lane);
    gemmAh3(h0, h1, h2, SM, COV, c1h, c1l, 256, col, 128, lane);
    stTileC(SM, CH, 0, lane, col, lrelu4(h0));
    stTileC(SM, CH, 1, lane, col, lrelu4(h1));
    stTileC(SM, CH, 2, lane, col, lrelu4(h2));
  }
  __syncthreads();
  // R6: q = h @ cW2 + cb2 (per-row dot, split h), guarded out store
  if (drow < ROWS && gb0 + drow < BATCH){
    int sw4 = (drow & 7) << 4;
    const unsigned char* hb = SM + CH + drow * 256;
    short8 ha = *(const short8*)(hb + (dcb ^ sw4));
    short8 hbf = *(const short8*)(hb + ((dcb + 16) ^ sw4));
    short8 la = *(const short8*)(hb + 12288 + (dcb ^ sw4));
    short8 lb = *(const short8*)(hb + 12288 + ((dcb + 16) ^ sw4));
    float q0 = 0.f, q1 = 0.f;
    #pragma unroll
    for (int e = 0; e < 8; ++e){
      int d = (lane & 7) * 16 + e;
      float hv = bf2f((unsigned short)ha[e]) + bf2f((unsigned short)la[e]);
      q0 = fmaf(hv, cW2[(i * HD + d) * 2 + 0], q0);
      q1 = fmaf(hv, cW2[(i * HD + d) * 2 + 1], q1);
    }
    #pragma unroll
    for (int e = 0; e < 8; ++e){
      int d = (lane & 7) * 16 + 8 + e;
      float hv = bf2f((unsigned short)hbf[e]) + bf2f((unsigned short)lb[e]);
      q0 = fmaf(hv, cW2[(i * HD + d) * 2 + 0], q0);
      q1 = fmaf(hv, cW2[(i * HD + d) * 2 + 1], q1);
    }
    RED8(q0) RED8(q1)
    if ((lane & 7) == 0){
      out[((size_t)i * BATCH + gb0 + drow) * 2 + 0] = q0 + cb2[i * 2 + 0];
      out[((size_t)i * BATCH + gb0 + drow) * 2 + 1] = q1 + cb2[i * 2 + 1];
    }
  }
}

// ======================================================================
// PATH B fallback: TB=32 helpers + round-2 fused kernel (proven)
// ======================================================================
__device__ __forceinline__ void gemmA(f32x4& c0, f32x4& c1, const unsigned char* sm, int abase,
                                      const unsigned short* wh, const unsigned short* wl,
                                      int K, int bcol, int kBaseB, int lane){
  const size_t bb = (size_t)bcol * K + kBaseB + ((lane >> 4) << 3);
  #pragma unroll
  for (int ks = 0; ks < 4; ++ks){
    short8 ah0, al0, ah1, al1;
    ldA(sm, abase, 0, ks, lane, ah0, al0);
    ldA(sm, abase, 1, ks, lane, ah1, al1);
    const short8 bh = *(const short8*)(wh + bb + ks * 32);
    const short8 bl = *(const short8*)(wl + bb + ks * 32);
    MM3(c0, ah0, al0, bh, bl);
    MM3(c1, ah1, al1, bh, bl);
  }
}
__device__ __forceinline__ void gemmS(f32x4& c0, f32x4& c1, const unsigned char* sm, int abase,
                                      const unsigned short* wh, const unsigned short* wl,
                                      int bcol, int lane){
  const size_t bb = (size_t)bcol * 32 + ((lane >> 4) << 3);
  short8 ah0, al0, ah1, al1;
  ldA32(sm, abase, 0, lane, ah0, al0);
  ldA32(sm, abase, 1, lane, ah1, al1);
  const short8 bh = *(const short8*)(wh + bb);
  const short8 bl = *(const short8*)(wl + bb);
  MM3(c0, ah0, al0, bh, bl);
  MM3(c1, ah1, al1, bh, bl);
}
__device__ __forceinline__ void dotTile(unsigned char* sm, int tbase, const f32x4 d0, const f32x4 d1,
                                        int lane, int wave, int col, int part_o){
  float* part = (float*)(sm + part_o);
  #pragma unroll
  for (int mi = 0; mi < 2; ++mi){
    #pragma unroll
    for (int r = 0; r < 4; ++r){
      int row = mi * 16 + ((lane >> 4) << 2) + r;
      int off = tbase + row * 256 + ((col * 2) ^ ((row & 7) << 4));
      float v = bf2f(*(const unsigned short*)(sm + off)) +
                bf2f(*(const unsigned short*)(sm + off + 8192));
      float p = (mi ? d1[r] : d0[r]) * v;
      RED16(p)
      if ((lane & 15) == 0) part[wave * 32 + row] = p;
    }
  }
}

#define XN_O    0
#define EN_O    12288
#define SLICE_O 28672
#define OV0_O   45056
#define SA_O    61440
#define PART_O  110592
#define EP_O    111616
#define ESUM_O  111744
#define LW_O    111872
#define SM_TOTAL 113024

__global__ __launch_bounds__(512, 2) void fused_kernel(
    const float* __restrict__ s, const float* __restrict__ a,
    const float* __restrict__ en_b, const float* __restrict__ oa_b,
    const float* __restrict__ goal_b, const float* __restrict__ aval_b,
    const float* __restrict__ merge_b, const float* __restrict__ senc_b,
    const float* __restrict__ cval_b, const float* __restrict__ cb1,
    const float* __restrict__ cb2, const unsigned char* __restrict__ wsc,
    float* __restrict__ out)
{
  __shared__ __align__(16) unsigned char SM[SM_TOTAL];
  unsigned char* sm = SM;
  const int t = threadIdx.x;
  const int lane = t & 63;
  const int wave = t >> 6;
  const int col = wave * 16 + (lane & 15);
  const int gb0 = blockIdx.x * TB;
  const float* stats = (const float*)(wsc + WSB_STATS);
  const unsigned short* wsu = (const unsigned short*)(wsc + WSB_W);
  const f32x4 Z = binit(0.f);

  if (t < 96){
    int n = t >> 5, row = t & 31;
    size_t gb = (size_t)gb0 + row;
    const float* st = stats + n * 40;
    const float* srow = s + ((size_t)n * BATCH + gb) * SD;
    const float* arow = a + ((size_t)n * BATCH + gb) * 2;
    #pragma unroll
    for (int c = 0; c < 32; ++c){
      float v = 0.f;
      if (c < 18) v = (srow[c] - st[c*2]) * st[c*2+1];
      else if (c < 20) v = (arow[c-18] - st[c*2]) * st[c*2+1];
      unsigned short hi = f2bf(v);
      int off = XN_O + n * 4096 + row * 64 + ((c * 2) ^ ((row & 3) << 4));
      *(unsigned short*)(sm + off) = hi;
      *(unsigned short*)(sm + off + 2048) = f2bf(v - bf2f(hi));
    }
  }
  __syncthreads();

  #pragma unroll 1
  for (int n = 0; n < NAG; ++n){
    const unsigned short* swh = wsu + OFF_SW(n);
    const unsigned short* swl = swh + 28672;
    {
      f32x4 v0 = binit(en_b[n*HD + col]), v1 = v0;
      gemmS(v0, v1, sm, XN_O + n*4096, swh, swl, 0 + col, lane);
      stTile(sm, EN_O, 0, lane, col, lrelu4(v0));
      stTile(sm, EN_O, 1, lane, col, lrelu4(v1));
    }
    __syncthreads();
    f32x4 sk0a = Z, sk0b = Z, sk1a = Z, sk1b = Z;
    gemmA(sk0a, sk0b, sm, EN_O, wsu + OFF_FT0, wsu + OFF_FT0 + 16384, 128, col, 0, lane);
    gemmA(sk1a, sk1b, sm, EN_O, wsu + OFF_FT1, wsu + OFF_FT1 + 16384, 128, col, 0, lane);

    f32x4 ov0a = Z, ov0b = Z;
    #pragma unroll 1
    for (int j = 0; j < 2; ++j){
      __syncthreads();
      f32x4 v0 = binit(oa_b[n*HD + col]), v1 = v0;
      gemmS(v0, v1, sm, XN_O + n*4096, swh, swl, 128*(1+j) + col, lane);
      stTile(sm, SLICE_O, 0, lane, col, lrelu4(v0));
      stTile(sm, SLICE_O, 1, lane, col, lrelu4(v1));
      __syncthreads();
      dotTile(sm, SLICE_O, sk0a, sk0b, lane, wave, col, PART_O);
      __syncthreads();
      if (t < TB){
        const float* part = (const float*)(sm + PART_O);
        float tot = 0.f;
        #pragma unroll
        for (int w2 = 0; w2 < 8; ++w2) tot += part[w2*32 + t];
        float e = __expf(tot * SCALE);
        ((float*)(sm + EP_O))[t] = e;
        float* es = (float*)(sm + ESUM_O);
        es[t] = (j == 0) ? e : es[t] + e;
      }
      __syncthreads();
      f32x4 w0 = binit(aval_b[col]), w1 = w0;
      gemmA(w0, w1, sm, SLICE_O, wsu + OFF_AV0, wsu + OFF_AV0 + 16384, 128, col, 0, lane);
      const float* eP = (const float*)(sm + EP_O);
      #pragma unroll
      for (int r = 0; r < 4; ++r){
        int row0 = ((lane >> 4) << 2) + r;
        ov0a[r] += eP[row0]      * lrelu(w0[r]);
        ov0b[r] += eP[row0 + 16] * lrelu(w1[r]);
      }
    }
    {
      const float* es = (const float*)(sm + ESUM_O);
      f32x4 o0, o1;
      #pragma unroll
      for (int r = 0; r < 4; ++r){
        int row0 = ((lane >> 4) << 2) + r;
        o0[r] = ov0a[r] / es[row0];
        o1[r] = ov0b[r] / es[row0 + 16];
      }
      stTile(sm, OV0_O, 0, lane, col, o0);
      stTile(sm, OV0_O, 1, lane, col, o1);
    }

    f32x4 ov1a = Z, ov1b = Z;
    #pragma unroll 1
    for (int j = 0; j < 3; ++j){
      __syncthreads();
      f32x4 v0 = binit(goal_b[n*HD + col]), v1 = v0;
      gemmS(v0, v1, sm, XN_O + n*4096, swh, swl, 128*(3+j) + col, lane);
      stTile(sm, SLICE_O, 0, lane, col, lrelu4(v0));
      stTile(sm, SLICE_O, 1, lane, col, lrelu4(v1));
      __syncthreads();
      dotTile(sm, SLICE_O, sk1a, sk1b, lane, wave, col, PART_O);
      __syncthreads();
      if (t < TB){
        const float* part = (const float*)(sm + PART_O);
        float tot = 0.f;
        #pragma unroll
        for (int w2 = 0; w2 < 8; ++w2) tot += part[w2*32 + t];
        float e = __expf(tot * SCALE);
        ((float*)(sm + EP_O))[t] = e;
        float* es = (float*)(sm + ESUM_O);
        es[t] = (j == 0) ? e : es[t] + e;
      }
      __syncthreads();
      f32x4 w0 = binit(aval_b[HD + col]), w1 = w0;
      gemmA(w0, w1, sm, SLICE_O, wsu + OFF_AV1, wsu + OFF_AV1 + 16384, 128, col, 0, lane);
      const float* eP = (const float*)(sm + EP_O);
      #pragma unroll
      for (int r = 0; r < 4; ++r){
        int row0 = ((lane >> 4) << 2) + r;
        ov1a[r] += eP[row0]      * lrelu(w0[r]);
        ov1b[r] += eP[row0 + 16] * lrelu(w1[r]);
      }
    }
    __syncthreads();
    {
      const float* es = (const float*)(sm + ESUM_O);
      f32x4 o0, o1;
      #pragma unroll
      for (int r = 0; r < 4; ++r){
        int row0 = ((lane >> 4) << 2) + r;
        o0[r] = ov1a[r] / es[row0];
        o1[r] = ov1b[r] / es[row0 + 16];
      }
      stTile(sm, SLICE_O, 0, lane, col, o0);
      stTile(sm, SLICE_O, 1, lane, col, o1);
    }
    __syncthreads();
    {
      const unsigned short* mhp = wsu + OFF_MG(n);
      const unsigned short* mlp = mhp + 49152;
      f32x4 m0 = binit(merge_b[n*HD + col]), m1 = m0;
      gemmA(m0, m1, sm, EN_O,    mhp, mlp, 384, col, 0,   lane);
      gemmA(m0, m1, sm, OV0_O,   mhp, mlp, 384, col, 128, lane);
      gemmA(m0, m1, sm, SLICE_O, mhp, mlp, 384, col, 256, lane);
      stTile(sm, SA_O + n*16384, 0, lane, col, lrelu4(m0));
      stTile(sm, SA_O + n*16384, 1, lane, col, lrelu4(m1));
    }
    __syncthreads();
  }

  #pragma unroll 1
  for (int i = 0; i < NAG; ++i){
    const unsigned short* swh = wsu + OFF_SW(i);
    const unsigned short* swl = swh + 28672;
    f32x4 e0 = binit(senc_b[i*HD + col]), e1 = e0;
    gemmS(e0, e1, sm, XN_O + i*4096, swh, swl, 768 + col, lane);
    stTile(sm, EN_O, 0, lane, col, lrelu4(e0));
    stTile(sm, EN_O, 1, lane, col, lrelu4(e1));
    __syncthreads();
    f32x4 sm0 = Z, sm1 = Z;
    gemmA(sm0, sm1, sm, EN_O, wsu + OFF_MT, wsu + OFF_MT + 16384, 128, col, 0, lane);
    #pragma unroll 1
    for (int j = 0; j < NAG; ++j){
      if (j == i) continue;
      dotTile(sm, SA_O + j*16384, sm0, sm1, lane, wave, col, PART_O);
      __syncthreads();
      if (t < TB){
        const float* part = (const float*)(sm + PART_O);
        float tot = 0.f;
        #pragma unroll
        for (int w2 = 0; w2 < 8; ++w2) tot += part[w2*32 + t];
        ((float*)(sm + LW_O))[(i*3 + j)*32 + t] = tot;
      }
      __syncthreads();
    }
  }
  if (t < TB){
    float* LW = (float*)(sm + LW_O);
    #pragma unroll
    for (int i = 0; i < NAG; ++i){
      int j0 = (i == 0) ? 1 : 0;
      int j1 = (i == 2) ? 1 : 2;
      float l0 = LW[(i*3 + j0)*32 + t] * SCALE;
      float l1 = LW[(i*3 + j1)*32 + t] * SCALE;
      float q0 = __expf(l0), q1 = __expf(l1);
      float inv = 1.f / (q0 + q1);
      LW[(i*3 + j0)*32 + t] = q0 * inv;
      LW[(i*3 + j1)*32 + t] = q1 * inv;
    }
  }
  __syncthreads();
  f32x4 oc00 = Z, oc01 = Z, oc10 = Z, oc11 = Z, oc20 = Z, oc21 = Z;
  {
    const float* LW = (const float*)(sm + LW_O);
    #pragma unroll 1
    for (int j = 0; j < NAG; ++j){
      f32x4 v0 = binit(cval_b[col]), v1 = v0;
      gemmA(v0, v1, sm, SA_O + j*16384, wsu + OFF_CV, wsu + OFF_CV + 16384, 128, col, 0, lane);
      v0 = lrelu4(v0); v1 = lrelu4(v1);
      #pragma unroll
      for (int i = 0; i < NAG; ++i){
        if (i == j) continue;
        f32x4& o0 = (i == 0) ? oc00 : ((i == 1) ? oc10 : oc20);
        f32x4& o1 = (i == 0) ? oc01 : ((i == 1) ? oc11 : oc21);
        #pragma unroll
        for (int r = 0; r < 4; ++r){
          int row0 = ((lane >> 4) << 2) + r;
          o0[r] += LW[(i*3 + j)*32 + row0]      * v0[r];
          o1[r] += LW[(i*3 + j)*32 + row0 + 16] * v1[r];
        }
      }
    }
  }
  __syncthreads();
  #pragma unroll 1
  for (int i = 0; i < NAG; ++i){
    const unsigned short* swh = wsu + OFF_SW(i);
    const unsigned short* swl = swh + 28672;
    f32x4 se0 = binit(senc_b[i*HD + col]), se1 = se0;
    gemmS(se0, se1, sm, XN_O + i*4096, swh, swl, 768 + col, lane);
    stTile(sm, EN_O, 0, lane, col, lrelu4(se0));
    stTile(sm, EN_O, 1, lane, col, lrelu4(se1));
    {
      f32x4 o0 = (i == 0) ? oc00 : ((i == 1) ? oc10 : oc20);
      f32x4 o1 = (i == 0) ? oc01 : ((i == 1) ? oc11 : oc21);
      stTile(sm, OV0_O, 0, lane, col, o0);
      stTile(sm, OV0_O, 1, lane, col, o1);
    }
    __syncthreads();
    const unsigned short* c1h = wsu + OFF_C1(i);
    const unsigned short* c1l = c1h + 32768;
    f32x4 h0 = binit(cb1[i*HD + col]), h1 = h0;
    gemmA(h0, h1, sm, EN_O,  c1h, c1l, 256, col, 0,   lane);
    gemmA(h0, h1, sm, OV0_O, c1h, c1l, 256, col, 128, lane);
    stTile(sm, SLICE_O, 0, lane, col, lrelu4(h0));
    stTile(sm, SLICE_O, 1, lane, col, lrelu4(h1));
    __syncthreads();
    f32x4 q0 = Z, q1 = Z;
    gemmA(q0, q1, sm, SLICE_O, wsu + OFF_C2(i), wsu + OFF_C2(i) + 2048, 128, (lane & 15), 0, lane);
    if (wave == 0 && (lane & 15) < 2){
      int c2 = lane & 15;
      float bb = cb2[i*2 + c2];
      #pragma unroll
      for (int r = 0; r < 4; ++r){
        int row = ((lane >> 4) << 2) + r;
        out[((size_t)i*BATCH + gb0 + row)*2 + c2]      = q0[r] + bb;
        out[((size_t)i*BATCH + gb0 + row + 16)*2 + c2] = q1[r] + bb;
      }
    }
    __syncthreads();
  }
}

// ------------------------------------------------------------ launch -----
extern "C" void kernel_launch(void* const* d_in, const int* in_sizes, int n_in,
                              void* d_out, int out_size, void* d_ws, size_t ws_size,
                              hipStream_t stream) {
  const float* s       = (const float*)d_in[0];
  const float* a       = (const float*)d_in[1];
  const float* en_W    = (const float*)d_in[2];
  const float* en_b    = (const float*)d_in[3];
  const float* oa_W    = (const float*)d_in[4];
  const float* oa_b    = (const float*)d_in[5];
  const float* goal_W  = (const float*)d_in[6];
  const float* goal_b  = (const float*)d_in[7];
  const float* akey_W  = (const float*)d_in[8];
  const float* asel_W  = (const float*)d_in[9];
  const float* aval_W  = (const float*)d_in[10];
  const float* aval_b  = (const float*)d_in[11];
  const float* merge_W = (const float*)d_in[12];
  const float* merge_b = (const float*)d_in[13];
  const float* senc_W  = (const float*)d_in[14];
  const float* senc_b  = (const float*)d_in[15];
  const float* ckey_W  = (const float*)d_in[16];
  const float* csel_W  = (const float*)d_in[17];
  const float* cval_W  = (const float*)d_in[18];
  const float* cval_b  = (const float*)d_in[19];
  const float* cW1     = (const float*)d_in[20];
  const float* cb1     = (const float*)d_in[21];
  const float* cW2     = (const float*)d_in[22];
  const float* cb2     = (const float*)d_in[23];
  unsigned char* wsc = (unsigned char*)d_ws;
  float* F = (float*)(wsc + WSB_F);
  unsigned short* wsu = (unsigned short*)(wsc + WSB_W);
  float* out = (float*)d_out;

  hipMemsetAsync(wsc + WSB_ACCUM, 0, 480, stream);
  stats_partial_kernel<<<48, 256, 0, stream>>>(s, a, (float*)(wsc + WSB_ACCUM));
  fuse_mats_kernel<<<dim3(HD, 4), HD, 0, stream>>>(
      asel_W, akey_W, csel_W, ckey_W, F,
      (const float*)(wsc + WSB_ACCUM), (float*)(wsc + WSB_STATS));
  prep_split_kernel<<<dim3(336, 16), 256, 0, stream>>>(
      F, aval_W, cval_W, merge_W, cW1, cW2, en_W, oa_W, goal_W, senc_W, wsu);

  if (ws_size >= (size_t)WSB_SA + SA_BYTES_P){
    unsigned short* sa_g = (unsigned short*)(wsc + WSB_SA);
    actor_kernel<<<dim3(NBLK, NAG), 512, 0, stream>>>(
        s, a, en_b, oa_b, goal_b, aval_b, merge_b,
        (const unsigned char*)wsc, sa_g);
    critic_kernel<<<dim3(NBLK, NAG), 512, 0, stream>>>(
        s, a, senc_b, cval_b, cb1, cW2, cb2,
        (const unsigned char*)wsc, (const unsigned short*)sa_g, out);
  } else {
    fused_kernel<<<BATCH / TB, 512, 0, stream>>>(
        s, a, en_b, oa_b, goal_b, aval_b, merge_b, senc_b, cval_b, cb1, cb2,
        (const unsigned char*)wsc, out);
  }
}

// Round 14
// 214.960 us; speedup vs baseline: 2.4723x; 1.1753x over previous
//
#include <hip/hip_runtime.h>

#define NAG 3
#define BATCH 32768
#define HD 128
#define SD 18
#define TB 32
#define ROWS 48
#define NBLK 683
#define PADB (NBLK * ROWS)     // 32784
#define EPSV 1e-5f
#define SCALE 0.08838834764831845f

typedef __attribute__((ext_vector_type(8))) short short8;
typedef __attribute__((ext_vector_type(4))) float f32x4;

// ---------------- ws byte layout ----------------
#define WSB_STATS 0
#define WSB_ACCUM 512
#define WSB_F     1024
#define WSB_W     197632
#define OFF_FT0 0
#define OFF_FT1 32768
#define OFF_MT  65536
#define OFF_AV0 98304
#define OFF_AV1 131072
#define OFF_CV  163840
#define OFF_MG(n) (196608 + (n)*98304)
#define OFF_C1(n) (491520 + (n)*65536)
#define OFF_C2(n) (688128 + (n)*4096)
#define OFF_SW(n) (700416 + (n)*57344)
#define WSB_SA  2097152
#define SA_BYTES_P ((size_t)NAG * PADB * HD * 2)

__device__ __forceinline__ float lrelu(float x){ return x >= 0.0f ? x : 0.01f * x; }
__device__ __forceinline__ f32x4 lrelu4(f32x4 v){
  f32x4 r; r[0]=lrelu(v[0]); r[1]=lrelu(v[1]); r[2]=lrelu(v[2]); r[3]=lrelu(v[3]); return r;
}
__device__ __forceinline__ f32x4 binit(float b){ f32x4 c; c[0]=b;c[1]=b;c[2]=b;c[3]=b; return c; }
__device__ __forceinline__ unsigned short f2bf(float f){
  unsigned int u = __float_as_uint(f);
  unsigned int r = (u + 0x7FFFu + ((u >> 16) & 1u)) >> 16;
  return (unsigned short)r;
}
__device__ __forceinline__ float bf2f(unsigned short h){
  return __uint_as_float(((unsigned int)h) << 16);
}

// ---------------- prep: batch stats ----------------
__global__ void stats_partial_kernel(const float* __restrict__ s,
                                     const float* __restrict__ a,
                                     float* __restrict__ accum){
  const int n = blockIdx.x >> 4;
  const int chunk = blockIdx.x & 15;
  const int t = threadIdx.x;
  const int rows = BATCH / 16;
  const int b0 = chunk * rows;
  float sum[20], sq[20];
  #pragma unroll
  for (int c = 0; c < 20; ++c){ sum[c] = 0.f; sq[c] = 0.f; }
  for (int b = b0 + t; b < b0 + rows; b += 256){
    const float* row = s + ((size_t)n * BATCH + b) * SD;
    #pragma unroll
    for (int c = 0; c < SD; ++c){ float v = row[c]; sum[c] += v; sq[c] += v * v; }
    const float* ra = a + ((size_t)n * BATCH + b) * 2;
    #pragma unroll
    for (int c = 0; c < 2; ++c){ float v = ra[c]; sum[SD + c] += v; sq[SD + c] += v * v; }
  }
  __shared__ float red[256];
  for (int c = 0; c < 20; ++c){
    red[t] = sum[c]; __syncthreads();
    for (int off = 128; off > 0; off >>= 1){ if (t < off) red[t] += red[t + off]; __syncthreads(); }
    if (t == 0) atomicAdd(&accum[(n * 20 + c) * 2 + 0], red[0]);
    __syncthreads();
    red[t] = sq[c]; __syncthreads();
    for (int off = 128; off > 0; off >>= 1){ if (t < off) red[t] += red[t + off]; __syncthreads(); }
    if (t == 0) atomicAdd(&accum[(n * 20 + c) * 2 + 1], red[0]);
    __syncthreads();
  }
}

// ---------------- prep: F_m = sel @ key^T + stats finalize ----------------
__global__ void fuse_mats_kernel(const float* __restrict__ asel, const float* __restrict__ akey,
                                 const float* __restrict__ csel, const float* __restrict__ ckey,
                                 float* __restrict__ F, const float* __restrict__ accum,
                                 float* __restrict__ stats){
  const int m  = blockIdx.y;
  if (m == 3){
    if (blockIdx.x == 0){
      int i = threadIdx.x;
      if (i < 60){
        float S = accum[i * 2 + 0], SQ = accum[i * 2 + 1];
        float mean = S / (float)BATCH;
        float var = SQ / (float)BATCH - mean * mean;
        stats[i * 2 + 0] = mean;
        stats[i * 2 + 1] = 1.0f / sqrtf(var + EPSV);
      }
    }
    return;
  }
  const int h1 = blockIdx.x;
  const int h2 = threadIdx.x;
  const float* A; const float* Bm;
  if (m == 0){ A = asel;            Bm = akey; }
  else if (m == 1){ A = asel + HD*HD; Bm = akey + HD*HD; }
  else { A = csel; Bm = ckey; }
  const float* arow = A + h1 * HD;
  const float* brow = Bm + h2 * HD;
  float acc = 0.f;
  #pragma unroll 4
  for (int d = 0; d < HD; ++d) acc = fmaf(arow[d], brow[d], acc);
  F[m * HD * HD + h1 * HD + h2] = acc;
}

// ---------------- prep: all weight splits + smallpack ----------------
__global__ void prep_split_kernel(const float* __restrict__ F, const float* __restrict__ aval_W,
                                  const float* __restrict__ cval_W, const float* __restrict__ merge_W,
                                  const float* __restrict__ cW1, const float* __restrict__ cW2,
                                  const float* __restrict__ en_W, const float* __restrict__ oa_W,
                                  const float* __restrict__ goal_W, const float* __restrict__ senc_W,
                                  unsigned short* __restrict__ wsu){
  const int job = blockIdx.y;
  const int idx = blockIdx.x * 256 + threadIdx.x;
  if (job == 15){
    if (idx >= 3 * 896 * 32) return;
    int k = idx & 31; int c = (idx >> 5) % 896; int n = idx / (896 * 32);
    int tt = c >> 7, cc = c & 127;
    float v = 0.f;
    if (tt == 0){
      if (k < 4) v = en_W[(size_t)(n*6 + k)*128 + cc];
      else if (k == 18 || k == 19) v = en_W[(size_t)(n*6 + 4 + (k-18))*128 + cc];
    } else if (tt <= 2){
      int j = tt - 1; int kk = k - (4 + 4*j);
      if (kk >= 0 && kk < 4) v = oa_W[(size_t)(n*4 + kk)*128 + cc];
    } else if (tt <= 5){
      int j = tt - 3; int kk = k - (12 + 2*j);
      if (kk >= 0 && kk < 2) v = goal_W[(size_t)(n*2 + kk)*128 + cc];
    } else {
      if (k < 18) v = senc_W[(size_t)(n*18 + k)*128 + cc];
    }
    unsigned short hi = f2bf(v); float lo = v - bf2f(hi);
    unsigned short* dh = wsu + OFF_SW(n);
    dh[c * 32 + k] = hi;
    dh[28672 + c * 32 + k] = f2bf(lo);
    return;
  }
  const float* src; unsigned short* dh; int K = 128, Csrc = 128, Cdst = 128, loff = 16384;
  switch (job){
    case 0: src = F;              dh = wsu + OFF_FT0; break;
    case 1: src = F + 16384;      dh = wsu + OFF_FT1; break;
    case 2: src = F + 32768;      dh = wsu + OFF_MT;  break;
    case 3: src = aval_W;         dh = wsu + OFF_AV0; break;
    case 4: src = aval_W + 16384; dh = wsu + OFF_AV1; break;
    case 5: src = cval_W;         dh = wsu + OFF_CV;  break;
    case 6: case 7: case 8: {
      int n = job - 6; src = merge_W + (size_t)n * 49152; dh = wsu + OFF_MG(n);
      K = 384; loff = 49152; } break;
    case 9: case 10: case 11: {
      int n = job - 9; src = cW1 + (size_t)n * 32768; dh = wsu + OFF_C1(n);
      K = 256; loff = 32768; } break;
    default: {
      int n = job - 12; src = cW2 + (size_t)n * 256; dh = wsu + OFF_C2(n);
      Csrc = 2; Cdst = 16; loff = 2048; } break;
  }
  if (idx >= K * Cdst) return;
  int k = idx / Cdst, c = idx - k * Cdst;
  float v = (c < Csrc) ? src[(size_t)k * Csrc + c] : 0.f;
  unsigned short hi = f2bf(v);
  dh[(size_t)c * K + k] = hi;
  dh[loff + (size_t)c * K + k] = f2bf(v - bf2f(hi));
}

// ---------------- MFMA helpers (shared) ----------------
__device__ __forceinline__ short8 ldAh(const unsigned char* sm, int base, int mi, int ks, int lane){
  int row = mi * 16 + (lane & 15);
  int bc  = ks * 64 + ((lane >> 4) << 4);
  return *(const short8*)(sm + base + row * 256 + (bc ^ ((row & 7) << 4)));
}
__device__ __forceinline__ void ldA(const unsigned char* sm, int base, int mi, int ks, int lane,
                                    short8& h, short8& l){
  int row = mi * 16 + (lane & 15);
  int bc  = ks * 64 + ((lane >> 4) << 4);
  int off = base + row * 256 + (bc ^ ((row & 7) << 4));
  h = *(const short8*)(sm + off);
  l = *(const short8*)(sm + off + 8192);
}
__device__ __forceinline__ void ldA32(const unsigned char* sm, int base, int mi, int lane,
                                      short8& h, short8& l){
  int row = mi * 16 + (lane & 15);
  int bc  = (lane >> 4) << 4;
  int off = base + row * 64 + (bc ^ ((row & 3) << 4));
  h = *(const short8*)(sm + off);
  l = *(const short8*)(sm + off + 2048);
}
__device__ __forceinline__ void ldA32_48(const unsigned char* sm, int base, int mi, int lane,
                                         short8& h, short8& l){
  int row = mi * 16 + (lane & 15);
  int bc  = (lane >> 4) << 4;
  int off = base + row * 64 + (bc ^ ((row & 3) << 4));
  h = *(const short8*)(sm + off);
  l = *(const short8*)(sm + off + 3072);
}

#define MM3(acc, ah, al, bh, bl) \
  acc = __builtin_amdgcn_mfma_f32_16x16x32_bf16(ah, bh, acc, 0, 0, 0); \
  acc = __builtin_amdgcn_mfma_f32_16x16x32_bf16(ah, bl, acc, 0, 0, 0); \
  acc = __builtin_amdgcn_mfma_f32_16x16x32_bf16(al, bh, acc, 0, 0, 0);
#define MM2(acc, ah, bh, bl) \
  acc = __builtin_amdgcn_mfma_f32_16x16x32_bf16(ah, bh, acc, 0, 0, 0); \
  acc = __builtin_amdgcn_mfma_f32_16x16x32_bf16(ah, bl, acc, 0, 0, 0);
#define MM1(acc, ah, bh) \
  acc = __builtin_amdgcn_mfma_f32_16x16x32_bf16(ah, bh, acc, 0, 0, 0);

// ---------------- TB=48 (3 m-tile) helpers ----------------
// split-A, split-B (fallback-compatible)
__device__ __forceinline__ void gemmS3(f32x4& c0, f32x4& c1, f32x4& c2,
                                       const unsigned char* sm, int abase,
                                       const unsigned short* wh, const unsigned short* wl,
                                       int bcol, int lane){
  const size_t bb = (size_t)bcol * 32 + ((lane >> 4) << 3);
  const short8 bh = *(const short8*)(wh + bb);
  const short8 bl = *(const short8*)(wl + bb);
  short8 ah, al;
  ldA32_48(sm, abase, 0, lane, ah, al); MM3(c0, ah, al, bh, bl);
  ldA32_48(sm, abase, 1, lane, ah, al); MM3(c1, ah, al, bh, bl);
  ldA32_48(sm, abase, 2, lane, ah, al); MM3(c2, ah, al, bh, bl);
}
// split-A, hi-B small encoder: 2 MFMA/mt
__device__ __forceinline__ void gemmS3_hb(f32x4& c0, f32x4& c1, f32x4& c2,
                                          const unsigned char* sm, int abase,
                                          const unsigned short* wh, int bcol, int lane){
  const size_t bb = (size_t)bcol * 32 + ((lane >> 4) << 3);
  const short8 bh = *(const short8*)(wh + bb);
  short8 ah, al;
  ldA32_48(sm, abase, 0, lane, ah, al); MM1(c0, ah, bh); MM1(c0, al, bh);
  ldA32_48(sm, abase, 1, lane, ah, al); MM1(c1, ah, bh); MM1(c1, al, bh);
  ldA32_48(sm, abase, 2, lane, ah, al); MM1(c2, ah, bh); MM1(c2, al, bh);
}
__device__ __forceinline__ void gemmAW2_3(f32x4& k0, f32x4& k1, f32x4& k2,
                                          f32x4& m0, f32x4& m1, f32x4& m2,
                                          const unsigned char* sm, int abase,
                                          const unsigned short* wh0, const unsigned short* wh1,
                                          int bcol, int lane){
  const size_t bb = (size_t)bcol * 128 + ((lane >> 4) << 3);
  #pragma unroll
  for (int ks = 0; ks < 4; ++ks){
    short8 a0 = ldAh(sm, abase, 0, ks, lane);
    short8 a1 = ldAh(sm, abase, 1, ks, lane);
    short8 a2 = ldAh(sm, abase, 2, ks, lane);
    const short8 b0 = *(const short8*)(wh0 + bb + ks * 32);
    const short8 b1 = *(const short8*)(wh1 + bb + ks * 32);
    MM1(k0, a0, b0); MM1(k1, a1, b0); MM1(k2, a2, b0);
    MM1(m0, a0, b1); MM1(m1, a1, b1); MM1(m2, a2, b1);
  }
}
__device__ __forceinline__ void gemmA2s3(f32x4& c0, f32x4& c1, f32x4& c2,
                                         f32x4& d0, f32x4& d1, f32x4& d2,
                                         const unsigned char* sm, int a0b, int a1b,
                                         const unsigned short* wh, int bcol, int lane){
  const size_t bb = (size_t)bcol * 128 + ((lane >> 4) << 3);
  #pragma unroll
  for (int ks = 0; ks < 4; ++ks){
    const short8 bh = *(const short8*)(wh + bb + ks * 32);
    short8 x;
    x = ldAh(sm, a0b, 0, ks, lane); MM1(c0, x, bh);
    x = ldAh(sm, a0b, 1, ks, lane); MM1(c1, x, bh);
    x = ldAh(sm, a0b, 2, ks, lane); MM1(c2, x, bh);
    x = ldAh(sm, a1b, 0, ks, lane); MM1(d0, x, bh);
    x = ldAh(sm, a1b, 1, ks, lane); MM1(d1, x, bh);
    x = ldAh(sm, a1b, 2, ks, lane); MM1(d2, x, bh);
  }
}
__device__ __forceinline__ void gemmA3s3(f32x4& c0, f32x4& c1, f32x4& c2,
                                         f32x4& d0, f32x4& d1, f32x4& d2,
                                         f32x4& e0, f32x4& e1, f32x4& e2,
                                         const unsigned char* sm, int a0b, int a1b, int a2b,
                                         const unsigned short* wh, int bcol, int lane){
  const size_t bb = (size_t)bcol * 128 + ((lane >> 4) << 3);
  #pragma unroll
  for (int ks = 0; ks < 4; ++ks){
    const short8 bh = *(const short8*)(wh + bb + ks * 32);
    short8 x;
    x = ldAh(sm, a0b, 0, ks, lane); MM1(c0, x, bh);
    x = ldAh(sm, a0b, 1, ks, lane); MM1(c1, x, bh);
    x = ldAh(sm, a0b, 2, ks, lane); MM1(c2, x, bh);
    x = ldAh(sm, a1b, 0, ks, lane); MM1(d0, x, bh);
    x = ldAh(sm, a1b, 1, ks, lane); MM1(d1, x, bh);
    x = ldAh(sm, a1b, 2, ks, lane); MM1(d2, x, bh);
    x = ldAh(sm, a2b, 0, ks, lane); MM1(e0, x, bh);
    x = ldAh(sm, a2b, 1, ks, lane); MM1(e1, x, bh);
    x = ldAh(sm, a2b, 2, ks, lane); MM1(e2, x, bh);
  }
}
// split-B (kept for reference / fallback)
__device__ __forceinline__ void gemmAh3(f32x4& c0, f32x4& c1, f32x4& c2,
                                        const unsigned char* sm, int abase,
                                        const unsigned short* wh, const unsigned short* wl,
                                        int K, int bcol, int kBase, int lane){
  const size_t bb = (size_t)bcol * K + kBase + ((lane >> 4) << 3);
  #pragma unroll
  for (int ks = 0; ks < 4; ++ks){
    const short8 bh = *(const short8*)(wh + bb + ks * 32);
    const short8 bl = *(const short8*)(wl + bb + ks * 32);
    short8 a;
    a = ldAh(sm, abase, 0, ks, lane); MM2(c0, a, bh, bl);
    a = ldAh(sm, abase, 1, ks, lane); MM2(c1, a, bh, bl);
    a = ldAh(sm, abase, 2, ks, lane); MM2(c2, a, bh, bl);
  }
}
// hi-A, hi-B with K/kBase (merge, cW1): 12 reads, 12 MFMA
__device__ __forceinline__ void gemmAh_hb3K(f32x4& c0, f32x4& c1, f32x4& c2,
                                            const unsigned char* sm, int abase,
                                            const unsigned short* wh,
                                            int K, int bcol, int kBase, int lane){
  const size_t bb = (size_t)bcol * K + kBase + ((lane >> 4) << 3);
  #pragma unroll
  for (int ks = 0; ks < 4; ++ks){
    const short8 bh = *(const short8*)(wh + bb + ks * 32);
    short8 a;
    a = ldAh(sm, abase, 0, ks, lane); MM1(c0, a, bh);
    a = ldAh(sm, abase, 1, ks, lane); MM1(c1, a, bh);
    a = ldAh(sm, abase, 2, ks, lane); MM1(c2, a, bh);
  }
}
__device__ __forceinline__ void gemmAh_hb3(f32x4& c0, f32x4& c1, f32x4& c2,
                                           const unsigned char* sm, int abase,
                                           const unsigned short* wh, int bcol, int lane){
  const size_t bb = (size_t)bcol * 128 + ((lane >> 4) << 3);
  #pragma unroll
  for (int ks = 0; ks < 4; ++ks){
    const short8 bh = *(const short8*)(wh + bb + ks * 32);
    short8 a;
    a = ldAh(sm, abase, 0, ks, lane); MM1(c0, a, bh);
    a = ldAh(sm, abase, 1, ks, lane); MM1(c1, a, bh);
    a = ldAh(sm, abase, 2, ks, lane); MM1(c2, a, bh);
  }
}

// stores
__device__ __forceinline__ void stTile(unsigned char* sm, int base, int mi, int lane, int col, f32x4 v){
  #pragma unroll
  for (int r = 0; r < 4; ++r){
    int row = mi * 16 + ((lane >> 4) << 2) + r;
    int off = base + row * 256 + ((col * 2) ^ ((row & 7) << 4));
    unsigned short hi = f2bf(v[r]);
    *(unsigned short*)(sm + off) = hi;
    *(unsigned short*)(sm + off + 8192) = f2bf(v[r] - bf2f(hi));
  }
}
__device__ __forceinline__ void stTileC(unsigned char* sm, int base, int mi, int lane, int col, f32x4 v){
  #pragma unroll
  for (int r = 0; r < 4; ++r){
    int row = mi * 16 + ((lane >> 4) << 2) + r;
    int off = base + row * 256 + ((col * 2) ^ ((row & 7) << 4));
    unsigned short hi = f2bf(v[r]);
    *(unsigned short*)(sm + off) = hi;
    *(unsigned short*)(sm + off + 12288) = f2bf(v[r] - bf2f(hi));
  }
}
__device__ __forceinline__ void stH(unsigned char* sm, int base, int mi, int lane, int col, f32x4 v){
  #pragma unroll
  for (int r = 0; r < 4; ++r){
    int row = mi * 16 + ((lane >> 4) << 2) + r;
    int off = base + row * 256 + ((col * 2) ^ ((row & 7) << 4));
    *(unsigned short*)(sm + off) = f2bf(v[r]);
  }
}
__device__ __forceinline__ void stSK(unsigned char* sm, int base, int mi, int lane, int col, f32x4 v){
  #pragma unroll
  for (int r = 0; r < 4; ++r){
    int row = mi * 16 + ((lane >> 4) << 2) + r;
    int off = base + row * 256 + ((col * 2) ^ ((row & 7) << 5));
    *(unsigned short*)(sm + off) = f2bf(v[r]);
  }
}
__device__ __forceinline__ float dot8(short8 x, short8 y){
  float acc = 0.f;
  #pragma unroll
  for (int e = 0; e < 8; ++e)
    acc = fmaf(bf2f((unsigned short)x[e]), bf2f((unsigned short)y[e]), acc);
  return acc;
}
#define RED16(p) { p += __shfl_xor(p, 1, 16); p += __shfl_xor(p, 2, 16); \
                   p += __shfl_xor(p, 4, 16); p += __shfl_xor(p, 8, 16); }
#define RED8(p) { p += __shfl_xor(p, 1); p += __shfl_xor(p, 2); p += __shfl_xor(p, 4); }

// ======================================================================
// PATH A: actor kernel — grid (NBLK, NAG), 512 threads, ROWS=48, 78.75KB LDS
// ======================================================================
__global__ __launch_bounds__(512, 4) void actor_kernel(
    const float* __restrict__ s, const float* __restrict__ a,
    const float* __restrict__ en_b, const float* __restrict__ oa_b,
    const float* __restrict__ goal_b, const float* __restrict__ aval_b,
    const float* __restrict__ merge_b, const unsigned char* __restrict__ wsc,
    unsigned short* __restrict__ sa_g)
{
  __shared__ __align__(16) unsigned char SM[80640];
  const int AXN = 0, AEN = 6144, AOV = 18432, ASK = 30720;
  const int SLB0 = 43008, SLB1 = 55296, SLB2 = 67584, AEP = 79872;
  const int t = threadIdx.x, lane = t & 63, wave = t >> 6;
  const int col = wave * 16 + (lane & 15);
  const int n = blockIdx.y;
  const int gb0 = blockIdx.x * ROWS;
  const float* stats = (const float*)(wsc + WSB_STATS);
  const unsigned short* wsu = (const unsigned short*)(wsc + WSB_W);
  const unsigned short* swh = wsu + OFF_SW(n);
  float* eP0 = (float*)(SM + AEP);
  float* eP1 = eP0 + 48;
  float* eP2 = eP0 + 96;
  float* esm = eP0 + 144;
  const f32x4 Z = binit(0.f);
  const int drow = wave * 8 + (lane >> 3);
  const int dcb  = (lane & 7) * 32;
  const int r0base = (lane >> 4) << 2;

  // init: stage normalized XN (split, K=32), clamped reads
  if (t < ROWS){
    int row = t;
    size_t gb = (size_t)gb0 + row;
    if (gb >= BATCH) gb = BATCH - 1;
    const float* st = stats + n * 40;
    const float* srow = s + ((size_t)n * BATCH + gb) * SD;
    const float* arow = a + ((size_t)n * BATCH + gb) * 2;
    #pragma unroll
    for (int c = 0; c < 32; ++c){
      float v = 0.f;
      if (c < 18) v = (srow[c] - st[c*2]) * st[c*2+1];
      else if (c < 20) v = (arow[c-18] - st[c*2]) * st[c*2+1];
      unsigned short hi = f2bf(v);
      int off = AXN + row * 64 + ((c * 2) ^ ((row & 3) << 4));
      *(unsigned short*)(SM + off) = hi;
      *(unsigned short*)(SM + off + 3072) = f2bf(v - bf2f(hi));
    }
  }
  __syncthreads();
  // R0: en_enc -> AEN ; oa slices -> SLB0, SLB1 (hi-B)
  {
    f32x4 c0 = binit(en_b[n*HD + col]), c1 = c0, c2 = c0;
    gemmS3_hb(c0, c1, c2, SM, AXN, swh, col, lane);
    stH(SM, AEN, 0, lane, col, lrelu4(c0));
    stH(SM, AEN, 1, lane, col, lrelu4(c1));
    stH(SM, AEN, 2, lane, col, lrelu4(c2));
    const float bb = oa_b[n*HD + col];
    c0 = binit(bb); c1 = c0; c2 = c0;
    gemmS3_hb(c0, c1, c2, SM, AXN, swh, 128 + col, lane);
    stH(SM, SLB0, 0, lane, col, lrelu4(c0));
    stH(SM, SLB0, 1, lane, col, lrelu4(c1));
    stH(SM, SLB0, 2, lane, col, lrelu4(c2));
    c0 = binit(bb); c1 = c0; c2 = c0;
    gemmS3_hb(c0, c1, c2, SM, AXN, swh, 256 + col, lane);
    stH(SM, SLB1, 0, lane, col, lrelu4(c0));
    stH(SM, SLB1, 1, lane, col, lrelu4(c1));
    stH(SM, SLB1, 2, lane, col, lrelu4(c2));
  }
  __syncthreads();
  // R1: selk0 -> AOV, selk1 -> ASK (hi-B)
  {
    f32x4 k0 = Z, k1 = Z, k2 = Z, m0 = Z, m1 = Z, m2 = Z;
    gemmAW2_3(k0, k1, k2, m0, m1, m2, SM, AEN,
              wsu + OFF_FT0, wsu + OFF_FT1, col, lane);
    stSK(SM, AOV, 0, lane, col, k0); stSK(SM, AOV, 1, lane, col, k1); stSK(SM, AOV, 2, lane, col, k2);
    stSK(SM, ASK, 0, lane, col, m0); stSK(SM, ASK, 1, lane, col, m1); stSK(SM, ASK, 2, lane, col, m2);
  }
  __syncthreads();
  // R2: oa vals (both slices, shared hi-B) + logit dots + exp
  f32x4 va0, va1, va2, vb0, vb1, vb2;
  {
    const float vb = aval_b[col];
    va0 = binit(vb); va1 = va0; va2 = va0; vb0 = va0; vb1 = va0; vb2 = va0;
    gemmA2s3(va0, va1, va2, vb0, vb1, vb2, SM, SLB0, SLB1, wsu + OFF_AV0, col, lane);
    if (drow < ROWS){
      int sw5 = (drow & 7) << 5, sw4 = (drow & 7) << 4;
      const unsigned char* kb = SM + AOV + drow * 256;
      short8 kfa = *(const short8*)(kb + (dcb ^ sw5));
      short8 kfb = *(const short8*)(kb + ((dcb + 16) ^ sw5));
      const unsigned char* s0 = SM + SLB0 + drow * 256;
      short8 e0a = *(const short8*)(s0 + (dcb ^ sw4));
      short8 e0b = *(const short8*)(s0 + ((dcb + 16) ^ sw4));
      const unsigned char* s1 = SM + SLB1 + drow * 256;
      short8 e1a = *(const short8*)(s1 + (dcb ^ sw4));
      short8 e1b = *(const short8*)(s1 + ((dcb + 16) ^ sw4));
      float p0 = dot8(kfa, e0a) + dot8(kfb, e0b);
      float p1 = dot8(kfa, e1a) + dot8(kfb, e1b);
      RED8(p0) RED8(p1)
      if ((lane & 7) == 0){
        float e0 = __expf(p0 * SCALE), e1 = __expf(p1 * SCALE);
        eP0[drow] = e0; eP1[drow] = e1; esm[drow] = e0 + e1;
      }
    }
  }
  __syncthreads();
  // R3: ov0 -> AOV ; goal slices g0,g1,g2 -> SLB0,1,2 (hi-B)
  {
    f32x4 o;
    #pragma unroll
    for (int r = 0; r < 4; ++r){
      int mr = r0base + r;
      o[r] = (eP0[mr] * lrelu(va0[r]) + eP1[mr] * lrelu(vb0[r])) / esm[mr];
    }
    stH(SM, AOV, 0, lane, col, o);
    #pragma unroll
    for (int r = 0; r < 4; ++r){
      int mr = 16 + r0base + r;
      o[r] = (eP0[mr] * lrelu(va1[r]) + eP1[mr] * lrelu(vb1[r])) / esm[mr];
    }
    stH(SM, AOV, 1, lane, col, o);
    #pragma unroll
    for (int r = 0; r < 4; ++r){
      int mr = 32 + r0base + r;
      o[r] = (eP0[mr] * lrelu(va2[r]) + eP1[mr] * lrelu(vb2[r])) / esm[mr];
    }
    stH(SM, AOV, 2, lane, col, o);
    const float bb = goal_b[n*HD + col];
    f32x4 c0 = binit(bb), c1 = c0, c2 = c0;
    gemmS3_hb(c0, c1, c2, SM, AXN, swh, 384 + col, lane);
    stH(SM, SLB0, 0, lane, col, lrelu4(c0));
    stH(SM, SLB0, 1, lane, col, lrelu4(c1));
    stH(SM, SLB0, 2, lane, col, lrelu4(c2));
    c0 = binit(bb); c1 = c0; c2 = c0;
    gemmS3_hb(c0, c1, c2, SM, AXN, swh, 512 + col, lane);
    stH(SM, SLB1, 0, lane, col, lrelu4(c0));
    stH(SM, SLB1, 1, lane, col, lrelu4(c1));
    stH(SM, SLB1, 2, lane, col, lrelu4(c2));
    c0 = binit(bb); c1 = c0; c2 = c0;
    gemmS3_hb(c0, c1, c2, SM, AXN, swh, 640 + col, lane);
    stH(SM, SLB2, 0, lane, col, lrelu4(c0));
    stH(SM, SLB2, 1, lane, col, lrelu4(c1));
    stH(SM, SLB2, 2, lane, col, lrelu4(c2));
  }
  __syncthreads();
  // R4: goal vals (3 slices x 3 mt, shared hi-B) + 3 dots + exps
  f32x4 g0m0, g0m1, g0m2, g1m0, g1m1, g1m2, g2m0, g2m1, g2m2;
  {
    const float vb = aval_b[HD + col];
    g0m0 = binit(vb); g0m1 = g0m0; g0m2 = g0m0;
    g1m0 = g0m0; g1m1 = g0m0; g1m2 = g0m0;
    g2m0 = g0m0; g2m1 = g0m0; g2m2 = g0m0;
    gemmA3s3(g0m0, g0m1, g0m2, g1m0, g1m1, g1m2, g2m0, g2m1, g2m2,
             SM, SLB0, SLB1, SLB2, wsu + OFF_AV1, col, lane);
    if (drow < ROWS){
      int sw5 = (drow & 7) << 5, sw4 = (drow & 7) << 4;
      const unsigned char* kb = SM + ASK + drow * 256;
      short8 kfa = *(const short8*)(kb + (dcb ^ sw5));
      short8 kfb = *(const short8*)(kb + ((dcb + 16) ^ sw5));
      const unsigned char* s0 = SM + SLB0 + drow * 256;
      short8 e0a = *(const short8*)(s0 + (dcb ^ sw4));
      short8 e0b = *(const short8*)(s0 + ((dcb + 16) ^ sw4));
      const unsigned char* s1 = SM + SLB1 + drow * 256;
      short8 e1a = *(const short8*)(s1 + (dcb ^ sw4));
      short8 e1b = *(const short8*)(s1 + ((dcb + 16) ^ sw4));
      const unsigned char* s2 = SM + SLB2 + drow * 256;
      short8 e2a = *(const short8*)(s2 + (dcb ^ sw4));
      short8 e2b = *(const short8*)(s2 + ((dcb + 16) ^ sw4));
      float p0 = dot8(kfa, e0a) + dot8(kfb, e0b);
      float p1 = dot8(kfa, e1a) + dot8(kfb, e1b);
      float p2 = dot8(kfa, e2a) + dot8(kfb, e2b);
      RED8(p0) RED8(p1) RED8(p2)
      if ((lane & 7) == 0){
        float e0 = __expf(p0 * SCALE), e1 = __expf(p1 * SCALE), e2 = __expf(p2 * SCALE);
        eP0[drow] = e0; eP1[drow] = e1; eP2[drow] = e2;
        esm[drow] = (e0 + e1) + e2;
      }
    }
  }
  __syncthreads();
  // R5: ov1 -> SLB0
  {
    f32x4 o;
    #pragma unroll
    for (int r = 0; r < 4; ++r){
      int mr = r0base + r;
      o[r] = ((eP0[mr] * lrelu(g0m0[r]) + eP1[mr] * lrelu(g1m0[r]))
              + eP2[mr] * lrelu(g2m0[r])) / esm[mr];
    }
    stH(SM, SLB0, 0, lane, col, o);
    #pragma unroll
    for (int r = 0; r < 4; ++r){
      int mr = 16 + r0base + r;
      o[r] = ((eP0[mr] * lrelu(g0m1[r]) + eP1[mr] * lrelu(g1m1[r]))
              + eP2[mr] * lrelu(g2m1[r])) / esm[mr];
    }
    stH(SM, SLB0, 1, lane, col, o);
    #pragma unroll
    for (int r = 0; r < 4; ++r){
      int mr = 32 + r0base + r;
      o[r] = ((eP0[mr] * lrelu(g0m2[r]) + eP1[mr] * lrelu(g1m2[r]))
              + eP2[mr] * lrelu(g2m2[r])) / esm[mr];
    }
    stH(SM, SLB0, 2, lane, col, o);
  }
  __syncthreads();
  // R6: merge (hi-B) -> SLB1
  {
    const unsigned short* mh = wsu + OFF_MG(n);
    f32x4 c0 = binit(merge_b[n*HD + col]), c1 = c0, c2 = c0;
    gemmAh_hb3K(c0, c1, c2, SM, AEN,  mh, 384, col, 0,   lane);
    gemmAh_hb3K(c0, c1, c2, SM, AOV,  mh, 384, col, 128, lane);
    gemmAh_hb3K(c0, c1, c2, SM, SLB0, mh, 384, col, 256, lane);
    stH(SM, SLB1, 0, lane, col, lrelu4(c0));
    stH(SM, SLB1, 1, lane, col, lrelu4(c1));
    stH(SM, SLB1, 2, lane, col, lrelu4(c2));
  }
  __syncthreads();
  // R7: coalesced copy SLB1 -> sa_g (padded)
  for (int idx = t; idx < ROWS * 16; idx += 512){
    int row = idx >> 4, ch = idx & 15;
    short8 u = *(const short8*)(SM + SLB1 + row * 256 + ((ch * 16) ^ ((row & 7) << 4)));
    *(short8*)(sa_g + ((size_t)n * PADB + gb0 + row) * HD + ch * 8) = u;
  }
}

// ======================================================================
// PATH A: critic kernel — grid (NBLK, NAG=i), 512 threads, ROWS=48, 66.4KB LDS
// ======================================================================
__global__ __launch_bounds__(512, 4) void critic_kernel(
    const float* __restrict__ s, const float* __restrict__ a,
    const float* __restrict__ senc_b, const float* __restrict__ cval_b,
    const float* __restrict__ cb1, const float* __restrict__ cW2,
    const float* __restrict__ cb2, const unsigned char* __restrict__ wsc,
    const unsigned short* __restrict__ sa_g, float* __restrict__ out)
{
  __shared__ __align__(16) unsigned char SM[67968];
  const int CXN = 0, CEN = 6144, CSMo = 18432, CSA = 30720, COV = 55296, CH = 30720, CLW = 67584;
  const int t = threadIdx.x, lane = t & 63, wave = t >> 6;
  const int col = wave * 16 + (lane & 15);
  const int i = blockIdx.y;
  const int gb0 = blockIdx.x * ROWS;
  const int j0 = (i == 0) ? 1 : 0;
  const int j1 = (i == 2) ? 1 : 2;
  const float* stats = (const float*)(wsc + WSB_STATS);
  const unsigned short* wsu = (const unsigned short*)(wsc + WSB_W);
  const unsigned short* swh = wsu + OFF_SW(i);
  const f32x4 Z = binit(0.f);
  const int drow = wave * 8 + (lane >> 3);
  const int dcb  = (lane & 7) * 32;
  const int r0base = (lane >> 4) << 2;

  // R0: stage XN_i (split, clamped) + copy sa_j0/j1 -> LDS (hi, swz)
  if (t < ROWS){
    int row = t;
    size_t gb = (size_t)gb0 + row;
    if (gb >= BATCH) gb = BATCH - 1;
    const float* st = stats + i * 40;
    const float* srow = s + ((size_t)i * BATCH + gb) * SD;
    const float* arow = a + ((size_t)i * BATCH + gb) * 2;
    #pragma unroll
    for (int c = 0; c < 32; ++c){
      float v = 0.f;
      if (c < 18) v = (srow[c] - st[c*2]) * st[c*2+1];
      else if (c < 20) v = (arow[c-18] - st[c*2]) * st[c*2+1];
      unsigned short hi = f2bf(v);
      int off = CXN + row * 64 + ((c * 2) ^ ((row & 3) << 4));
      *(unsigned short*)(SM + off) = hi;
      *(unsigned short*)(SM + off + 3072) = f2bf(v - bf2f(hi));
    }
  }
  for (int idx = t; idx < 2 * ROWS * 16; idx += 512){
    int tile = idx >= ROWS * 16;
    int k = idx - tile * ROWS * 16;
    int row = k >> 4, ch = k & 15;
    int j = tile ? j1 : j0;
    short8 u = *(const short8*)(sa_g + ((size_t)j * PADB + gb0 + row) * HD + ch * 8);
    *(short8*)(SM + CSA + tile * 12288 + row * 256 + ((ch * 16) ^ ((row & 7) << 4))) = u;
  }
  __syncthreads();
  // R1: s_enc -> CEN (hi-B)
  {
    f32x4 c0 = binit(senc_b[i*HD + col]), c1 = c0, c2 = c0;
    gemmS3_hb(c0, c1, c2, SM, CXN, swh, 768 + col, lane);
    stH(SM, CEN, 0, lane, col, lrelu4(c0));
    stH(SM, CEN, 1, lane, col, lrelu4(c1));
    stH(SM, CEN, 2, lane, col, lrelu4(c2));
  }
  __syncthreads();
  // R2: selsM = s_enc @ M (hi-B) -> CSM (32B-swz)
  {
    f32x4 k0 = Z, k1 = Z, k2 = Z;
    gemmAh_hb3(k0, k1, k2, SM, CEN, wsu + OFF_MT, col, lane);
    stSK(SM, CSMo, 0, lane, col, k0);
    stSK(SM, CSMo, 1, lane, col, k1);
    stSK(SM, CSMo, 2, lane, col, k2);
  }
  __syncthreads();
  // R3: vals GEMMs (2 sa-tiles x 3 mt, shared hi-B) + dots + 2-way softmax
  f32x4 v00, v01, v02, v10, v11, v12;
  {
    const float vb = cval_b[col];
    v00 = binit(vb); v01 = v00; v02 = v00; v10 = v00; v11 = v00; v12 = v00;
    gemmA2s3(v00, v01, v02, v10, v11, v12, SM, CSA, CSA + 12288,
             wsu + OFF_CV, col, lane);
    if (drow < ROWS){
      int sw5 = (drow & 7) << 5, sw4 = (drow & 7) << 4;
      const unsigned char* mb = SM + CSMo + drow * 256;
      short8 ma = *(const short8*)(mb + (dcb ^ sw5));
      short8 mbf = *(const short8*)(mb + ((dcb + 16) ^ sw5));
      const unsigned char* a0p = SM + CSA + drow * 256;
      short8 a0a = *(const short8*)(a0p + (dcb ^ sw4));
      short8 a0b = *(const short8*)(a0p + ((dcb + 16) ^ sw4));
      const unsigned char* b0p = SM + CSA + 12288 + drow * 256;
      short8 b0a = *(const short8*)(b0p + (dcb ^ sw4));
      short8 b0b = *(const short8*)(b0p + ((dcb + 16) ^ sw4));
      float p0 = dot8(ma, a0a) + dot8(mbf, a0b);
      float p1 = dot8(ma, b0a) + dot8(mbf, b0b);
      RED8(p0) RED8(p1)
      if ((lane & 7) == 0){
        float e0 = __expf(p0 * SCALE), e1 = __expf(p1 * SCALE);
        float inv = 1.f / (e0 + e1);
        ((float*)(SM + CLW))[drow]      = e0 * inv;
        ((float*)(SM + CLW))[48 + drow] = e1 * inv;
      }
    }
  }
  __syncthreads();
  // R4: ov -> COV (hi)
  {
    const float* w0 = (const float*)(SM + CLW);
    const float* w1 = w0 + 48;
    f32x4 o;
    #pragma unroll
    for (int r = 0; r < 4; ++r){
      int mr = r0base + r;
      o[r] = w0[mr] * lrelu(v00[r]) + w1[mr] * lrelu(v10[r]);
    }
    stH(SM, COV, 0, lane, col, o);
    #pragma unroll
    for (int r = 0; r < 4; ++r){
      int mr = 16 + r0base + r;
      o[r] = w0[mr] * lrelu(v01[r]) + w1[mr] * lrelu(v11[r]);
    }
    stH(SM, COV, 1, lane, col, o);
    #pragma unroll
    for (int r = 0; r < 4; ++r){
      int mr = 32 + r0base + r;
      o[r] = w0[mr] * lrelu(v02[r]) + w1[mr] * lrelu(v12[r]);
    }
    stH(SM, COV, 2, lane, col, o);
  }
  __syncthreads();
  // R5: h = lrelu([s_enc|ov] @ cW1 + b) -> CH (hi-B; h stored split; overwrites CSA)
  {
    const unsigned short* c1h = wsu + OFF_C1(i);
    f32x4 h0 = binit(cb1[i*HD + col]), h1 = h0, h2 = h0;
    gemmAh_hb3K(h0, h1, h2, SM, CEN, c1h, 256, col, 0,   lane);
    gemmAh_hb3K(h0, h1, h2, SM, COV, c1h, 256, col, 128, lane);
    stTileC(SM, CH, 0, lane, col, lrelu4(h0));
    stTileC(SM, CH, 1, lane, col, lrelu4(h1));
    stTileC(SM, CH, 2, lane, col, lrelu4(h2));
  }
  __syncthreads();
  // R6: q = h @ cW2 + cb2 (per-row dot, split h), guarded out store
  if (drow < ROWS && gb0 + drow < BATCH){
    int sw4 = (drow & 7) << 4;
    const unsigned char* hb = SM + CH + drow * 256;
    short8 ha = *(const short8*)(hb + (dcb ^ sw4));
    short8 hbf = *(const short8*)(hb + ((dcb + 16) ^ sw4));
    short8 la = *(const short8*)(hb + 12288 + (dcb ^ sw4));
    short8 lb = *(const short8*)(hb + 12288 + ((dcb + 16) ^ sw4));
    float q0 = 0.f, q1 = 0.f;
    #pragma unroll
    for (int e = 0; e < 8; ++e){
      int d = (lane & 7) * 16 + e;
      float hv = bf2f((unsigned short)ha[e]) + bf2f((unsigned short)la[e]);
      q0 = fmaf(hv, cW2[(i * HD + d) * 2 + 0], q0);
      q1 = fmaf(hv, cW2[(i * HD + d) * 2 + 1], q1);
    }
    #pragma unroll
    for (int e = 0; e < 8; ++e){
      int d = (lane & 7) * 16 + 8 + e;
      float hv = bf2f((unsigned short)hbf[e]) + bf2f((unsigned short)lb[e]);
      q0 = fmaf(hv, cW2[(i * HD + d) * 2 + 0], q0);
      q1 = fmaf(hv, cW2[(i * HD + d) * 2 + 1], q1);
    }
    RED8(q0) RED8(q1)
    if ((lane & 7) == 0){
      out[((size_t)i * BATCH + gb0 + drow) * 2 + 0] = q0 + cb2[i * 2 + 0];
      out[((size_t)i * BATCH + gb0 + drow) * 2 + 1] = q1 + cb2[i * 2 + 1];
    }
  }
}

// ======================================================================
// PATH B fallback: TB=32 helpers + round-2 fused kernel (proven)
// ======================================================================
__device__ __forceinline__ void gemmA(f32x4& c0, f32x4& c1, const unsigned char* sm, int abase,
                                      const unsigned short* wh, const unsigned short* wl,
                                      int K, int bcol, int kBaseB, int lane){
  const size_t bb = (size_t)bcol * K + kBaseB + ((lane >> 4) << 3);
  #pragma unroll
  for (int ks = 0; ks < 4; ++ks){
    short8 ah0, al0, ah1, al1;
    ldA(sm, abase, 0, ks, lane, ah0, al0);
    ldA(sm, abase, 1, ks, lane, ah1, al1);
    const short8 bh = *(const short8*)(wh + bb + ks * 32);
    const short8 bl = *(const short8*)(wl + bb + ks * 32);
    MM3(c0, ah0, al0, bh, bl);
    MM3(c1, ah1, al1, bh, bl);
  }
}
__device__ __forceinline__ void gemmS(f32x4& c0, f32x4& c1, const unsigned char* sm, int abase,
                                      const unsigned short* wh, const unsigned short* wl,
                                      int bcol, int lane){
  const size_t bb = (size_t)bcol * 32 + ((lane >> 4) << 3);
  short8 ah0, al0, ah1, al1;
  ldA32(sm, abase, 0, lane, ah0, al0);
  ldA32(sm, abase, 1, lane, ah1, al1);
  const short8 bh = *(const short8*)(wh + bb);
  const short8 bl = *(const short8*)(wl + bb);
  MM3(c0, ah0, al0, bh, bl);
  MM3(c1, ah1, al1, bh, bl);
}
__device__ __forceinline__ void dotTile(unsigned char* sm, int tbase, const f32x4 d0, const f32x4 d1,
                                        int lane, int wave, int col, int part_o){
  float* part = (float*)(sm + part_o);
  #pragma unroll
  for (int mi = 0; mi < 2; ++mi){
    #pragma unroll
    for (int r = 0; r < 4; ++r){
      int row = mi * 16 + ((lane >> 4) << 2) + r;
      int off = tbase + row * 256 + ((col * 2) ^ ((row & 7) << 4));
      float v = bf2f(*(const unsigned short*)(sm + off)) +
                bf2f(*(const unsigned short*)(sm + off + 8192));
      float p = (mi ? d1[r] : d0[r]) * v;
      RED16(p)
      if ((lane & 15) == 0) part[wave * 32 + row] = p;
    }
  }
}

#define XN_O    0
#define EN_O    12288
#define SLICE_O 28672
#define OV0_O   45056
#define SA_O    61440
#define PART_O  110592
#define EP_O    111616
#define ESUM_O  111744
#define LW_O    111872
#define SM_TOTAL 113024

__global__ __launch_bounds__(512, 2) void fused_kernel(
    const float* __restrict__ s, const float* __restrict__ a,
    const float* __restrict__ en_b, const float* __restrict__ oa_b,
    const float* __restrict__ goal_b, const float* __restrict__ aval_b,
    const float* __restrict__ merge_b, const float* __restrict__ senc_b,
    const float* __restrict__ cval_b, const float* __restrict__ cb1,
    const float* __restrict__ cb2, const unsigned char* __restrict__ wsc,
    float* __restrict__ out)
{
  __shared__ __align__(16) unsigned char SM[SM_TOTAL];
  unsigned char* sm = SM;
  const int t = threadIdx.x;
  const int lane = t & 63;
  const int wave = t >> 6;
  const int col = wave * 16 + (lane & 15);
  const int gb0 = blockIdx.x * TB;
  const float* stats = (const float*)(wsc + WSB_STATS);
  const unsigned short* wsu = (const unsigned short*)(wsc + WSB_W);
  const f32x4 Z = binit(0.f);

  if (t < 96){
    int n = t >> 5, row = t & 31;
    size_t gb = (size_t)gb0 + row;
    const float* st = stats + n * 40;
    const float* srow = s + ((size_t)n * BATCH + gb) * SD;
    const float* arow = a + ((size_t)n * BATCH + gb) * 2;
    #pragma unroll
    for (int c = 0; c < 32; ++c){
      float v = 0.f;
      if (c < 18) v = (srow[c] - st[c*2]) * st[c*2+1];
      else if (c < 20) v = (arow[c-18] - st[c*2]) * st[c*2+1];
      unsigned short hi = f2bf(v);
      int off = XN_O + n * 4096 + row * 64 + ((c * 2) ^ ((row & 3) << 4));
      *(unsigned short*)(sm + off) = hi;
      *(unsigned short*)(sm + off + 2048) = f2bf(v - bf2f(hi));
    }
  }
  __syncthreads();

  #pragma unroll 1
  for (int n = 0; n < NAG; ++n){
    const unsigned short* swh = wsu + OFF_SW(n);
    const unsigned short* swl = swh + 28672;
    {
      f32x4 v0 = binit(en_b[n*HD + col]), v1 = v0;
      gemmS(v0, v1, sm, XN_O + n*4096, swh, swl, 0 + col, lane);
      stTile(sm, EN_O, 0, lane, col, lrelu4(v0));
      stTile(sm, EN_O, 1, lane, col, lrelu4(v1));
    }
    __syncthreads();
    f32x4 sk0a = Z, sk0b = Z, sk1a = Z, sk1b = Z;
    gemmA(sk0a, sk0b, sm, EN_O, wsu + OFF_FT0, wsu + OFF_FT0 + 16384, 128, col, 0, lane);
    gemmA(sk1a, sk1b, sm, EN_O, wsu + OFF_FT1, wsu + OFF_FT1 + 16384, 128, col, 0, lane);

    f32x4 ov0a = Z, ov0b = Z;
    #pragma unroll 1
    for (int j = 0; j < 2; ++j){
      __syncthreads();
      f32x4 v0 = binit(oa_b[n*HD + col]), v1 = v0;
      gemmS(v0, v1, sm, XN_O + n*4096, swh, swl, 128*(1+j) + col, lane);
      stTile(sm, SLICE_O, 0, lane, col, lrelu4(v0));
      stTile(sm, SLICE_O, 1, lane, col, lrelu4(v1));
      __syncthreads();
      dotTile(sm, SLICE_O, sk0a, sk0b, lane, wave, col, PART_O);
      __syncthreads();
      if (t < TB){
        const float* part = (const float*)(sm + PART_O);
        float tot = 0.f;
        #pragma unroll
        for (int w2 = 0; w2 < 8; ++w2) tot += part[w2*32 + t];
        float e = __expf(tot * SCALE);
        ((float*)(sm + EP_O))[t] = e;
        float* es = (float*)(sm + ESUM_O);
        es[t] = (j == 0) ? e : es[t] + e;
      }
      __syncthreads();
      f32x4 w0 = binit(aval_b[col]), w1 = w0;
      gemmA(w0, w1, sm, SLICE_O, wsu + OFF_AV0, wsu + OFF_AV0 + 16384, 128, col, 0, lane);
      const float* eP = (const float*)(sm + EP_O);
      #pragma unroll
      for (int r = 0; r < 4; ++r){
        int row0 = ((lane >> 4) << 2) + r;
        ov0a[r] += eP[row0]      * lrelu(w0[r]);
        ov0b[r] += eP[row0 + 16] * lrelu(w1[r]);
      }
    }
    {
      const float* es = (const float*)(sm + ESUM_O);
      f32x4 o0, o1;
      #pragma unroll
      for (int r = 0; r < 4; ++r){
        int row0 = ((lane >> 4) << 2) + r;
        o0[r] = ov0a[r] / es[row0];
        o1[r] = ov0b[r] / es[row0 + 16];
      }
      stTile(sm, OV0_O, 0, lane, col, o0);
      stTile(sm, OV0_O, 1, lane, col, o1);
    }

    f32x4 ov1a = Z, ov1b = Z;
    #pragma unroll 1
    for (int j = 0; j < 3; ++j){
      __syncthreads();
      f32x4 v0 = binit(goal_b[n*HD + col]), v1 = v0;
      gemmS(v0, v1, sm, XN_O + n*4096, swh, swl, 128*(3+j) + col, lane);
      stTile(sm, SLICE_O, 0, lane, col, lrelu4(v0));
      stTile(sm, SLICE_O, 1, lane, col, lrelu4(v1));
      __syncthreads();
      dotTile(sm, SLICE_O, sk1a, sk1b, lane, wave, col, PART_O);
      __syncthreads();
      if (t < TB){
        const float* part = (const float*)(sm + PART_O);
        float tot = 0.f;
        #pragma unroll
        for (int w2 = 0; w2 < 8; ++w2) tot += part[w2*32 + t];
        float e = __expf(tot * SCALE);
        ((float*)(sm + EP_O))[t] = e;
        float* es = (float*)(sm + ESUM_O);
        es[t] = (j == 0) ? e : es[t] + e;
      }
      __syncthreads();
      f32x4 w0 = binit(aval_b[HD + col]), w1 = w0;
      gemmA(w0, w1, sm, SLICE_O, wsu + OFF_AV1, wsu + OFF_AV1 + 16384, 128, col, 0, lane);
      const float* eP = (const float*)(sm + EP_O);
      #pragma unroll
      for (int r = 0; r < 4; ++r){
        int row0 = ((lane >> 4) << 2) + r;
        ov1a[r] += eP[row0]      * lrelu(w0[r]);
        ov1b[r] += eP[row0 + 16] * lrelu(w1[r]);
      }
    }
    __syncthreads();
    {
      const float* es = (const float*)(sm + ESUM_O);
      f32x4 o0, o1;
      #pragma unroll
      for (int r = 0; r < 4; ++r){
        int row0 = ((lane >> 4) << 2) + r;
        o0[r] = ov1a[r] / es[row0];
        o1[r] = ov1b[r] / es[row0 + 16];
      }
      stTile(sm, SLICE_O, 0, lane, col, o0);
      stTile(sm, SLICE_O, 1, lane, col, o1);
    }
    __syncthreads();
    {
      const unsigned short* mhp = wsu + OFF_MG(n);
      const unsigned short* mlp = mhp + 49152;
      f32x4 m0 = binit(merge_b[n*HD + col]), m1 = m0;
      gemmA(m0, m1, sm, EN_O,    mhp, mlp, 384, col, 0,   lane);
      gemmA(m0, m1, sm, OV0_O,   mhp, mlp, 384, col, 128, lane);
      gemmA(m0, m1, sm, SLICE_O, mhp, mlp, 384, col, 256, lane);
      stTile(sm, SA_O + n*16384, 0, lane, col, lrelu4(m0));
      stTile(sm, SA_O + n*16384, 1, lane, col, lrelu4(m1));
    }
    __syncthreads();
  }

  #pragma unroll 1
  for (int i = 0; i < NAG; ++i){
    const unsigned short* swh = wsu + OFF_SW(i);
    const unsigned short* swl = swh + 28672;
    f32x4 e0 = binit(senc_b[i*HD + col]), e1 = e0;
    gemmS(e0, e1, sm, XN_O + i*4096, swh, swl, 768 + col, lane);
    stTile(sm, EN_O, 0, lane, col, lrelu4(e0));
    stTile(sm, EN_O, 1, lane, col, lrelu4(e1));
    __syncthreads();
    f32x4 sm0 = Z, sm1 = Z;
    gemmA(sm0, sm1, sm, EN_O, wsu + OFF_MT, wsu + OFF_MT + 16384, 128, col, 0, lane);
    #pragma unroll 1
    for (int j = 0; j < NAG; ++j){
      if (j == i) continue;
      dotTile(sm, SA_O + j*16384, sm0, sm1, lane, wave, col, PART_O);
      __syncthreads();
      if (t < TB){
        const float* part = (const float*)(sm + PART_O);
        float tot = 0.f;
        #pragma unroll
        for (int w2 = 0; w2 < 8; ++w2) tot += part[w2*32 + t];
        ((float*)(sm + LW_O))[(i*3 + j)*32 + t] = tot;
      }
      __syncthreads();
    }
  }
  if (t < TB){
    float* LW = (float*)(sm + LW_O);
    #pragma unroll
    for (int i = 0; i < NAG; ++i){
      int j0 = (i == 0) ? 1 : 0;
      int j1 = (i == 2) ? 1 : 2;
      float l0 = LW[(i*3 + j0)*32 + t] * SCALE;
      float l1 = LW[(i*3 + j1)*32 + t] * SCALE;
      float q0 = __expf(l0), q1 = __expf(l1);
      float inv = 1.f / (q0 + q1);
      LW[(i*3 + j0)*32 + t] = q0 * inv;
      LW[(i*3 + j1)*32 + t] = q1 * inv;
    }
  }
  __syncthreads();
  f32x4 oc00 = Z, oc01 = Z, oc10 = Z, oc11 = Z, oc20 = Z, oc21 = Z;
  {
    const float* LW = (const float*)(sm + LW_O);
    #pragma unroll 1
    for (int j = 0; j < NAG; ++j){
      f32x4 v0 = binit(cval_b[col]), v1 = v0;
      gemmA(v0, v1, sm, SA_O + j*16384, wsu + OFF_CV, wsu + OFF_CV + 16384, 128, col, 0, lane);
      v0 = lrelu4(v0); v1 = lrelu4(v1);
      #pragma unroll
      for (int i = 0; i < NAG; ++i){
        if (i == j) continue;
        f32x4& o0 = (i == 0) ? oc00 : ((i == 1) ? oc10 : oc20);
        f32x4& o1 = (i == 0) ? oc01 : ((i == 1) ? oc11 : oc21);
        #pragma unroll
        for (int r = 0; r < 4; ++r){
          int row0 = ((lane >> 4) << 2) + r;
          o0[r] += LW[(i*3 + j)*32 + row0]      * v0[r];
          o1[r] += LW[(i*3 + j)*32 + row0 + 16] * v1[r];
        }
      }
    }
  }
  __syncthreads();
  #pragma unroll 1
  for (int i = 0; i < NAG; ++i){
    const unsigned short* swh = wsu + OFF_SW(i);
    const unsigned short* swl = swh + 28672;
    f32x4 se0 = binit(senc_b[i*HD + col]), se1 = se0;
    gemmS(se0, se1, sm, XN_O + i*4096, swh, swl, 768 + col, lane);
    stTile(sm, EN_O, 0, lane, col, lrelu4(se0));
    stTile(sm, EN_O, 1, lane, col, lrelu4(se1));
    {
      f32x4 o0 = (i == 0) ? oc00 : ((i == 1) ? oc10 : oc20);
      f32x4 o1 = (i == 0) ? oc01 : ((i == 1) ? oc11 : oc21);
      stTile(sm, OV0_O, 0, lane, col, o0);
      stTile(sm, OV0_O, 1, lane, col, o1);
    }
    __syncthreads();
    const unsigned short* c1h = wsu + OFF_C1(i);
    const unsigned short* c1l = c1h + 32768;
    f32x4 h0 = binit(cb1[i*HD + col]), h1 = h0;
    gemmA(h0, h1, sm, EN_O,  c1h, c1l, 256, col, 0,   lane);
    gemmA(h0, h1, sm, OV0_O, c1h, c1l, 256, col, 128, lane);
    stTile(sm, SLICE_O, 0, lane, col, lrelu4(h0));
    stTile(sm, SLICE_O, 1, lane, col, lrelu4(h1));
    __syncthreads();
    f32x4 q0 = Z, q1 = Z;
    gemmA(q0, q1, sm, SLICE_O, wsu + OFF_C2(i), wsu + OFF_C2(i) + 2048, 128, (lane & 15), 0, lane);
    if (wave == 0 && (lane & 15) < 2){
      int c2 = lane & 15;
      float bb = cb2[i*2 + c2];
      #pragma unroll
      for (int r = 0; r < 4; ++r){
        int row = ((lane >> 4) << 2) + r;
        out[((size_t)i*BATCH + gb0 + row)*2 + c2]      = q0[r] + bb;
        out[((size_t)i*BATCH + gb0 + row + 16)*2 + c2] = q1[r] + bb;
      }
    }
    __syncthreads();
  }
}

// ------------------------------------------------------------ launch -----
extern "C" void kernel_launch(void* const* d_in, const int* in_sizes, int n_in,
                              void* d_out, int out_size, void* d_ws, size_t ws_size,
                              hipStream_t stream) {
  const float* s       = (const float*)d_in[0];
  const float* a       = (const float*)d_in[1];
  const float* en_W    = (const float*)d_in[2];
  const float* en_b    = (const float*)d_in[3];
  const float* oa_W    = (const float*)d_in[4];
  const float* oa_b    = (const float*)d_in[5];
  const float* goal_W  = (const float*)d_in[6];
  const float* goal_b  = (const float*)d_in[7];
  const float* akey_W  = (const float*)d_in[8];
  const float* asel_W  = (const float*)d_in[9];
  const float* aval_W  = (const float*)d_in[10];
  const float* aval_b  = (const float*)d_in[11];
  const float* merge_W = (const float*)d_in[12];
  const float* merge_b = (const float*)d_in[13];
  const float* senc_W  = (const float*)d_in[14];
  const float* senc_b  = (const float*)d_in[15];
  const float* ckey_W  = (const float*)d_in[16];
  const float* csel_W  = (const float*)d_in[17];
  const float* cval_W  = (const float*)d_in[18];
  const float* cval_b  = (const float*)d_in[19];
  const float* cW1     = (const float*)d_in[20];
  const float* cb1     = (const float*)d_in[21];
  const float* cW2     = (const float*)d_in[22];
  const float* cb2     = (const float*)d_in[23];
  unsigned char* wsc = (unsigned char*)d_ws;
  float* F = (float*)(wsc + WSB_F);
  unsigned short* wsu = (unsigned short*)(wsc + WSB_W);
  float* out = (float*)d_out;

  hipMemsetAsync(wsc + WSB_ACCUM, 0, 480, stream);
  stats_partial_kernel<<<48, 256, 0, stream>>>(s, a, (float*)(wsc + WSB_ACCUM));
  fuse_mats_kernel<<<dim3(HD, 4), HD, 0, stream>>>(
      asel_W, akey_W, csel_W, ckey_W, F,
      (const float*)(wsc + WSB_ACCUM), (float*)(wsc + WSB_STATS));
  prep_split_kernel<<<dim3(336, 16), 256, 0, stream>>>(
      F, aval_W, cval_W, merge_W, cW1, cW2, en_W, oa_W, goal_W, senc_W, wsu);

  if (ws_size >= (size_t)WSB_SA + SA_BYTES_P){
    unsigned short* sa_g = (unsigned short*)(wsc + WSB_SA);
    actor_kernel<<<dim3(NBLK, NAG), 512, 0, stream>>>(
        s, a, en_b, oa_b, goal_b, aval_b, merge_b,
        (const unsigned char*)wsc, sa_g);
    critic_kernel<<<dim3(NBLK, NAG), 512, 0, stream>>>(
        s, a, senc_b, cval_b, cb1, cW2, cb2,
        (const unsigned char*)wsc, (const unsigned short*)sa_g, out);
  } else {
    fused_kernel<<<BATCH / TB, 512, 0, stream>>>(
        s, a, en_b, oa_b, goal_b, aval_b, merge_b, senc_b, cval_b, cb1, cb2,
        (const unsigned char*)wsc, out);
  }
}

// Round 15
// 211.470 us; speedup vs baseline: 2.5131x; 1.0165x over previous
//
#include <hip/hip_runtime.h>
#include <hip/hip_bf16.h>

#define NAG 3
#define BATCH 32768
#define HD 128
#define SD 18
#define TB 32
#define ROWS 48
#define NBLK 683
#define PADB (NBLK * ROWS)     // 32784
#define EPSV 1e-5f
#define SCALE 0.08838834764831845f

typedef __attribute__((ext_vector_type(8))) short short8;
typedef __attribute__((ext_vector_type(4))) float f32x4;

// ---------------- ws byte layout ----------------
#define WSB_STATS 0
#define WSB_ACCUM 512
#define WSB_F     1024
#define WSB_W     197632
#define OFF_FT0 0
#define OFF_FT1 32768
#define OFF_MT  65536
#define OFF_AV0 98304
#define OFF_AV1 131072
#define OFF_CV  163840
#define OFF_MG(n) (196608 + (n)*98304)
#define OFF_C1(n) (491520 + (n)*65536)
#define OFF_C2(n) (688128 + (n)*4096)
#define OFF_SW(n) (700416 + (n)*57344)
#define WSB_SA  2097152
#define SA_BYTES_P ((size_t)NAG * PADB * HD * 2)

__device__ __forceinline__ float lrelu(float x){ return x >= 0.0f ? x : 0.01f * x; }
__device__ __forceinline__ f32x4 lrelu4(f32x4 v){
  f32x4 r; r[0]=lrelu(v[0]); r[1]=lrelu(v[1]); r[2]=lrelu(v[2]); r[3]=lrelu(v[3]); return r;
}
__device__ __forceinline__ f32x4 binit(float b){ f32x4 c; c[0]=b;c[1]=b;c[2]=b;c[3]=b; return c; }
__device__ __forceinline__ unsigned short f2bf(float f){
  __hip_bfloat16 h = __float2bfloat16(f);     // HW v_cvt (RNE) — was 5-op SW round
  return *reinterpret_cast<unsigned short*>(&h);
}
__device__ __forceinline__ float bf2f(unsigned short h){
  return __uint_as_float(((unsigned int)h) << 16);
}

// ---------------- prep: batch stats ----------------
__global__ void stats_partial_kernel(const float* __restrict__ s,
                                     const float* __restrict__ a,
                                     float* __restrict__ accum){
  const int n = blockIdx.x >> 4;
  const int chunk = blockIdx.x & 15;
  const int t = threadIdx.x;
  const int rows = BATCH / 16;
  const int b0 = chunk * rows;
  float sum[20], sq[20];
  #pragma unroll
  for (int c = 0; c < 20; ++c){ sum[c] = 0.f; sq[c] = 0.f; }
  for (int b = b0 + t; b < b0 + rows; b += 256){
    const float* row = s + ((size_t)n * BATCH + b) * SD;
    #pragma unroll
    for (int c = 0; c < SD; ++c){ float v = row[c]; sum[c] += v; sq[c] += v * v; }
    const float* ra = a + ((size_t)n * BATCH + b) * 2;
    #pragma unroll
    for (int c = 0; c < 2; ++c){ float v = ra[c]; sum[SD + c] += v; sq[SD + c] += v * v; }
  }
  __shared__ float red[256];
  for (int c = 0; c < 20; ++c){
    red[t] = sum[c]; __syncthreads();
    for (int off = 128; off > 0; off >>= 1){ if (t < off) red[t] += red[t + off]; __syncthreads(); }
    if (t == 0) atomicAdd(&accum[(n * 20 + c) * 2 + 0], red[0]);
    __syncthreads();
    red[t] = sq[c]; __syncthreads();
    for (int off = 128; off > 0; off >>= 1){ if (t < off) red[t] += red[t + off]; __syncthreads(); }
    if (t == 0) atomicAdd(&accum[(n * 20 + c) * 2 + 1], red[0]);
    __syncthreads();
  }
}

// ---------------- prep: F_m = sel @ key^T + stats finalize ----------------
__global__ void fuse_mats_kernel(const float* __restrict__ asel, const float* __restrict__ akey,
                                 const float* __restrict__ csel, const float* __restrict__ ckey,
                                 float* __restrict__ F, const float* __restrict__ accum,
                                 float* __restrict__ stats){
  const int m  = blockIdx.y;
  if (m == 3){
    if (blockIdx.x == 0){
      int i = threadIdx.x;
      if (i < 60){
        float S = accum[i * 2 + 0], SQ = accum[i * 2 + 1];
        float mean = S / (float)BATCH;
        float var = SQ / (float)BATCH - mean * mean;
        stats[i * 2 + 0] = mean;
        stats[i * 2 + 1] = 1.0f / sqrtf(var + EPSV);
      }
    }
    return;
  }
  const int h1 = blockIdx.x;
  const int h2 = threadIdx.x;
  const float* A; const float* Bm;
  if (m == 0){ A = asel;            Bm = akey; }
  else if (m == 1){ A = asel + HD*HD; Bm = akey + HD*HD; }
  else { A = csel; Bm = ckey; }
  const float* arow = A + h1 * HD;
  const float* brow = Bm + h2 * HD;
  float acc = 0.f;
  #pragma unroll 4
  for (int d = 0; d < HD; ++d) acc = fmaf(arow[d], brow[d], acc);
  F[m * HD * HD + h1 * HD + h2] = acc;
}

// ---------------- prep: all weight splits + smallpack ----------------
__global__ void prep_split_kernel(const float* __restrict__ F, const float* __restrict__ aval_W,
                                  const float* __restrict__ cval_W, const float* __restrict__ merge_W,
                                  const float* __restrict__ cW1, const float* __restrict__ cW2,
                                  const float* __restrict__ en_W, const float* __restrict__ oa_W,
                                  const float* __restrict__ goal_W, const float* __restrict__ senc_W,
                                  unsigned short* __restrict__ wsu){
  const int job = blockIdx.y;
  const int idx = blockIdx.x * 256 + threadIdx.x;
  if (job == 15){
    if (idx >= 3 * 896 * 32) return;
    int k = idx & 31; int c = (idx >> 5) % 896; int n = idx / (896 * 32);
    int tt = c >> 7, cc = c & 127;
    float v = 0.f;
    if (tt == 0){
      if (k < 4) v = en_W[(size_t)(n*6 + k)*128 + cc];
      else if (k == 18 || k == 19) v = en_W[(size_t)(n*6 + 4 + (k-18))*128 + cc];
    } else if (tt <= 2){
      int j = tt - 1; int kk = k - (4 + 4*j);
      if (kk >= 0 && kk < 4) v = oa_W[(size_t)(n*4 + kk)*128 + cc];
    } else if (tt <= 5){
      int j = tt - 3; int kk = k - (12 + 2*j);
      if (kk >= 0 && kk < 2) v = goal_W[(size_t)(n*2 + kk)*128 + cc];
    } else {
      if (k < 18) v = senc_W[(size_t)(n*18 + k)*128 + cc];
    }
    unsigned short hi = f2bf(v); float lo = v - bf2f(hi);
    unsigned short* dh = wsu + OFF_SW(n);
    dh[c * 32 + k] = hi;
    dh[28672 + c * 32 + k] = f2bf(lo);
    return;
  }
  const float* src; unsigned short* dh; int K = 128, Csrc = 128, Cdst = 128, loff = 16384;
  switch (job){
    case 0: src = F;              dh = wsu + OFF_FT0; break;
    case 1: src = F + 16384;      dh = wsu + OFF_FT1; break;
    case 2: src = F + 32768;      dh = wsu + OFF_MT;  break;
    case 3: src = aval_W;         dh = wsu + OFF_AV0; break;
    case 4: src = aval_W + 16384; dh = wsu + OFF_AV1; break;
    case 5: src = cval_W;         dh = wsu + OFF_CV;  break;
    case 6: case 7: case 8: {
      int n = job - 6; src = merge_W + (size_t)n * 49152; dh = wsu + OFF_MG(n);
      K = 384; loff = 49152; } break;
    case 9: case 10: case 11: {
      int n = job - 9; src = cW1 + (size_t)n * 32768; dh = wsu + OFF_C1(n);
      K = 256; loff = 32768; } break;
    default: {
      int n = job - 12; src = cW2 + (size_t)n * 256; dh = wsu + OFF_C2(n);
      Csrc = 2; Cdst = 16; loff = 2048; } break;
  }
  if (idx >= K * Cdst) return;
  int k = idx / Cdst, c = idx - k * Cdst;
  float v = (c < Csrc) ? src[(size_t)k * Csrc + c] : 0.f;
  unsigned short hi = f2bf(v);
  dh[(size_t)c * K + k] = hi;
  dh[loff + (size_t)c * K + k] = f2bf(v - bf2f(hi));
}

// ---------------- MFMA helpers (shared) ----------------
__device__ __forceinline__ short8 ldAh(const unsigned char* sm, int base, int mi, int ks, int lane){
  int row = mi * 16 + (lane & 15);
  int bc  = ks * 64 + ((lane >> 4) << 4);
  return *(const short8*)(sm + base + row * 256 + (bc ^ ((row & 7) << 4)));
}
__device__ __forceinline__ void ldA(const unsigned char* sm, int base, int mi, int ks, int lane,
                                    short8& h, short8& l){
  int row = mi * 16 + (lane & 15);
  int bc  = ks * 64 + ((lane >> 4) << 4);
  int off = base + row * 256 + (bc ^ ((row & 7) << 4));
  h = *(const short8*)(sm + off);
  l = *(const short8*)(sm + off + 8192);
}
__device__ __forceinline__ void ldA32(const unsigned char* sm, int base, int mi, int lane,
                                      short8& h, short8& l){
  int row = mi * 16 + (lane & 15);
  int bc  = (lane >> 4) << 4;
  int off = base + row * 64 + (bc ^ ((row & 3) << 4));
  h = *(const short8*)(sm + off);
  l = *(const short8*)(sm + off + 2048);
}
__device__ __forceinline__ void ldA32_48(const unsigned char* sm, int base, int mi, int lane,
                                         short8& h, short8& l){
  int row = mi * 16 + (lane & 15);
  int bc  = (lane >> 4) << 4;
  int off = base + row * 64 + (bc ^ ((row & 3) << 4));
  h = *(const short8*)(sm + off);
  l = *(const short8*)(sm + off + 3072);
}

#define MM3(acc, ah, al, bh, bl) \
  acc = __builtin_amdgcn_mfma_f32_16x16x32_bf16(ah, bh, acc, 0, 0, 0); \
  acc = __builtin_amdgcn_mfma_f32_16x16x32_bf16(ah, bl, acc, 0, 0, 0); \
  acc = __builtin_amdgcn_mfma_f32_16x16x32_bf16(al, bh, acc, 0, 0, 0);
#define MM2(acc, ah, bh, bl) \
  acc = __builtin_amdgcn_mfma_f32_16x16x32_bf16(ah, bh, acc, 0, 0, 0); \
  acc = __builtin_amdgcn_mfma_f32_16x16x32_bf16(ah, bl, acc, 0, 0, 0);
#define MM1(acc, ah, bh) \
  acc = __builtin_amdgcn_mfma_f32_16x16x32_bf16(ah, bh, acc, 0, 0, 0);

// ---------------- TB=48 (3 m-tile) helpers ----------------
__device__ __forceinline__ void gemmS3(f32x4& c0, f32x4& c1, f32x4& c2,
                                       const unsigned char* sm, int abase,
                                       const unsigned short* wh, const unsigned short* wl,
                                       int bcol, int lane){
  const size_t bb = (size_t)bcol * 32 + ((lane >> 4) << 3);
  const short8 bh = *(const short8*)(wh + bb);
  const short8 bl = *(const short8*)(wl + bb);
  short8 ah, al;
  ldA32_48(sm, abase, 0, lane, ah, al); MM3(c0, ah, al, bh, bl);
  ldA32_48(sm, abase, 1, lane, ah, al); MM3(c1, ah, al, bh, bl);
  ldA32_48(sm, abase, 2, lane, ah, al); MM3(c2, ah, al, bh, bl);
}
// split-A, hi-B small encoder: 2 MFMA/mt
__device__ __forceinline__ void gemmS3_hb(f32x4& c0, f32x4& c1, f32x4& c2,
                                          const unsigned char* sm, int abase,
                                          const unsigned short* wh, int bcol, int lane){
  const size_t bb = (size_t)bcol * 32 + ((lane >> 4) << 3);
  const short8 bh = *(const short8*)(wh + bb);
  short8 ah, al;
  ldA32_48(sm, abase, 0, lane, ah, al); MM1(c0, ah, bh); MM1(c0, al, bh);
  ldA32_48(sm, abase, 1, lane, ah, al); MM1(c1, ah, bh); MM1(c1, al, bh);
  ldA32_48(sm, abase, 2, lane, ah, al); MM1(c2, ah, bh); MM1(c2, al, bh);
}
__device__ __forceinline__ void gemmAW2_3(f32x4& k0, f32x4& k1, f32x4& k2,
                                          f32x4& m0, f32x4& m1, f32x4& m2,
                                          const unsigned char* sm, int abase,
                                          const unsigned short* wh0, const unsigned short* wh1,
                                          int bcol, int lane){
  const size_t bb = (size_t)bcol * 128 + ((lane >> 4) << 3);
  #pragma unroll
  for (int ks = 0; ks < 4; ++ks){
    short8 a0 = ldAh(sm, abase, 0, ks, lane);
    short8 a1 = ldAh(sm, abase, 1, ks, lane);
    short8 a2 = ldAh(sm, abase, 2, ks, lane);
    const short8 b0 = *(const short8*)(wh0 + bb + ks * 32);
    const short8 b1 = *(const short8*)(wh1 + bb + ks * 32);
    MM1(k0, a0, b0); MM1(k1, a1, b0); MM1(k2, a2, b0);
    MM1(m0, a0, b1); MM1(m1, a1, b1); MM1(m2, a2, b1);
  }
}
__device__ __forceinline__ void gemmA2s3(f32x4& c0, f32x4& c1, f32x4& c2,
                                         f32x4& d0, f32x4& d1, f32x4& d2,
                                         const unsigned char* sm, int a0b, int a1b,
                                         const unsigned short* wh, int bcol, int lane){
  const size_t bb = (size_t)bcol * 128 + ((lane >> 4) << 3);
  #pragma unroll
  for (int ks = 0; ks < 4; ++ks){
    const short8 bh = *(const short8*)(wh + bb + ks * 32);
    short8 x;
    x = ldAh(sm, a0b, 0, ks, lane); MM1(c0, x, bh);
    x = ldAh(sm, a0b, 1, ks, lane); MM1(c1, x, bh);
    x = ldAh(sm, a0b, 2, ks, lane); MM1(c2, x, bh);
    x = ldAh(sm, a1b, 0, ks, lane); MM1(d0, x, bh);
    x = ldAh(sm, a1b, 1, ks, lane); MM1(d1, x, bh);
    x = ldAh(sm, a1b, 2, ks, lane); MM1(d2, x, bh);
  }
}
__device__ __forceinline__ void gemmA3s3(f32x4& c0, f32x4& c1, f32x4& c2,
                                         f32x4& d0, f32x4& d1, f32x4& d2,
                                         f32x4& e0, f32x4& e1, f32x4& e2,
                                         const unsigned char* sm, int a0b, int a1b, int a2b,
                                         const unsigned short* wh, int bcol, int lane){
  const size_t bb = (size_t)bcol * 128 + ((lane >> 4) << 3);
  #pragma unroll
  for (int ks = 0; ks < 4; ++ks){
    const short8 bh = *(const short8*)(wh + bb + ks * 32);
    short8 x;
    x = ldAh(sm, a0b, 0, ks, lane); MM1(c0, x, bh);
    x = ldAh(sm, a0b, 1, ks, lane); MM1(c1, x, bh);
    x = ldAh(sm, a0b, 2, ks, lane); MM1(c2, x, bh);
    x = ldAh(sm, a1b, 0, ks, lane); MM1(d0, x, bh);
    x = ldAh(sm, a1b, 1, ks, lane); MM1(d1, x, bh);
    x = ldAh(sm, a1b, 2, ks, lane); MM1(d2, x, bh);
    x = ldAh(sm, a2b, 0, ks, lane); MM1(e0, x, bh);
    x = ldAh(sm, a2b, 1, ks, lane); MM1(e1, x, bh);
    x = ldAh(sm, a2b, 2, ks, lane); MM1(e2, x, bh);
  }
}
// hi-A, hi-B with K/kBase (merge, cW1): 12 reads, 12 MFMA
__device__ __forceinline__ void gemmAh_hb3K(f32x4& c0, f32x4& c1, f32x4& c2,
                                            const unsigned char* sm, int abase,
                                            const unsigned short* wh,
                                            int K, int bcol, int kBase, int lane){
  const size_t bb = (size_t)bcol * K + kBase + ((lane >> 4) << 3);
  #pragma unroll
  for (int ks = 0; ks < 4; ++ks){
    const short8 bh = *(const short8*)(wh + bb + ks * 32);
    short8 a;
    a = ldAh(sm, abase, 0, ks, lane); MM1(c0, a, bh);
    a = ldAh(sm, abase, 1, ks, lane); MM1(c1, a, bh);
    a = ldAh(sm, abase, 2, ks, lane); MM1(c2, a, bh);
  }
}
__device__ __forceinline__ void gemmAh_hb3(f32x4& c0, f32x4& c1, f32x4& c2,
                                           const unsigned char* sm, int abase,
                                           const unsigned short* wh, int bcol, int lane){
  const size_t bb = (size_t)bcol * 128 + ((lane >> 4) << 3);
  #pragma unroll
  for (int ks = 0; ks < 4; ++ks){
    const short8 bh = *(const short8*)(wh + bb + ks * 32);
    short8 a;
    a = ldAh(sm, abase, 0, ks, lane); MM1(c0, a, bh);
    a = ldAh(sm, abase, 1, ks, lane); MM1(c1, a, bh);
    a = ldAh(sm, abase, 2, ks, lane); MM1(c2, a, bh);
  }
}

// stores
__device__ __forceinline__ void stTile(unsigned char* sm, int base, int mi, int lane, int col, f32x4 v){
  #pragma unroll
  for (int r = 0; r < 4; ++r){
    int row = mi * 16 + ((lane >> 4) << 2) + r;
    int off = base + row * 256 + ((col * 2) ^ ((row & 7) << 4));
    unsigned short hi = f2bf(v[r]);
    *(unsigned short*)(sm + off) = hi;
    *(unsigned short*)(sm + off + 8192) = f2bf(v[r] - bf2f(hi));
  }
}
__device__ __forceinline__ void stTileC(unsigned char* sm, int base, int mi, int lane, int col, f32x4 v){
  #pragma unroll
  for (int r = 0; r < 4; ++r){
    int row = mi * 16 + ((lane >> 4) << 2) + r;
    int off = base + row * 256 + ((col * 2) ^ ((row & 7) << 4));
    unsigned short hi = f2bf(v[r]);
    *(unsigned short*)(sm + off) = hi;
    *(unsigned short*)(sm + off + 12288) = f2bf(v[r] - bf2f(hi));
  }
}
__device__ __forceinline__ void stH(unsigned char* sm, int base, int mi, int lane, int col, f32x4 v){
  #pragma unroll
  for (int r = 0; r < 4; ++r){
    int row = mi * 16 + ((lane >> 4) << 2) + r;
    int off = base + row * 256 + ((col * 2) ^ ((row & 7) << 4));
    *(unsigned short*)(sm + off) = f2bf(v[r]);
  }
}
__device__ __forceinline__ void stSK(unsigned char* sm, int base, int mi, int lane, int col, f32x4 v){
  #pragma unroll
  for (int r = 0; r < 4; ++r){
    int row = mi * 16 + ((lane >> 4) << 2) + r;
    int off = base + row * 256 + ((col * 2) ^ ((row & 7) << 5));
    *(unsigned short*)(sm + off) = f2bf(v[r]);
  }
}
__device__ __forceinline__ float dot8(short8 x, short8 y){
  float acc = 0.f;
  #pragma unroll
  for (int e = 0; e < 8; ++e)
    acc = fmaf(bf2f((unsigned short)x[e]), bf2f((unsigned short)y[e]), acc);
  return acc;
}
#define RED16(p) { p += __shfl_xor(p, 1, 16); p += __shfl_xor(p, 2, 16); \
                   p += __shfl_xor(p, 4, 16); p += __shfl_xor(p, 8, 16); }
#define RED8(p) { p += __shfl_xor(p, 1); p += __shfl_xor(p, 2); p += __shfl_xor(p, 4); }

// ======================================================================
// PATH A: actor kernel — grid (NBLK, NAG), 512 threads, ROWS=48, 78.75KB LDS
// ======================================================================
__global__ __launch_bounds__(512, 4) void actor_kernel(
    const float* __restrict__ s, const float* __restrict__ a,
    const float* __restrict__ en_b, const float* __restrict__ oa_b,
    const float* __restrict__ goal_b, const float* __restrict__ aval_b,
    const float* __restrict__ merge_b, const unsigned char* __restrict__ wsc,
    unsigned short* __restrict__ sa_g)
{
  __shared__ __align__(16) unsigned char SM[80640];
  const int AXN = 0, AEN = 6144, AOV = 18432, ASK = 30720;
  const int SLB0 = 43008, SLB1 = 55296, SLB2 = 67584, AEP = 79872;
  const int t = threadIdx.x, lane = t & 63, wave = t >> 6;
  const int col = wave * 16 + (lane & 15);
  const int n = blockIdx.y;
  const int gb0 = blockIdx.x * ROWS;
  const float* stats = (const float*)(wsc + WSB_STATS);
  const unsigned short* wsu = (const unsigned short*)(wsc + WSB_W);
  const unsigned short* swh = wsu + OFF_SW(n);
  float* eP0 = (float*)(SM + AEP);
  float* eP1 = eP0 + 48;
  float* eP2 = eP0 + 96;
  float* esm = eP0 + 144;
  const f32x4 Z = binit(0.f);
  const int drow = wave * 8 + (lane >> 3);
  const int dcb  = (lane & 7) * 32;
  const int r0base = (lane >> 4) << 2;

  // init: stage normalized XN (split, K=32), clamped reads
  if (t < ROWS){
    int row = t;
    size_t gb = (size_t)gb0 + row;
    if (gb >= BATCH) gb = BATCH - 1;
    const float* st = stats + n * 40;
    const float* srow = s + ((size_t)n * BATCH + gb) * SD;
    const float* arow = a + ((size_t)n * BATCH + gb) * 2;
    #pragma unroll
    for (int c = 0; c < 32; ++c){
      float v = 0.f;
      if (c < 18) v = (srow[c] - st[c*2]) * st[c*2+1];
      else if (c < 20) v = (arow[c-18] - st[c*2]) * st[c*2+1];
      unsigned short hi = f2bf(v);
      int off = AXN + row * 64 + ((c * 2) ^ ((row & 3) << 4));
      *(unsigned short*)(SM + off) = hi;
      *(unsigned short*)(SM + off + 3072) = f2bf(v - bf2f(hi));
    }
  }
  __syncthreads();
  // R0: en_enc -> AEN ; oa slices -> SLB0, SLB1 (hi-B)
  {
    f32x4 c0 = binit(en_b[n*HD + col]), c1 = c0, c2 = c0;
    gemmS3_hb(c0, c1, c2, SM, AXN, swh, col, lane);
    stH(SM, AEN, 0, lane, col, lrelu4(c0));
    stH(SM, AEN, 1, lane, col, lrelu4(c1));
    stH(SM, AEN, 2, lane, col, lrelu4(c2));
    const float bb = oa_b[n*HD + col];
    c0 = binit(bb); c1 = c0; c2 = c0;
    gemmS3_hb(c0, c1, c2, SM, AXN, swh, 128 + col, lane);
    stH(SM, SLB0, 0, lane, col, lrelu4(c0));
    stH(SM, SLB0, 1, lane, col, lrelu4(c1));
    stH(SM, SLB0, 2, lane, col, lrelu4(c2));
    c0 = binit(bb); c1 = c0; c2 = c0;
    gemmS3_hb(c0, c1, c2, SM, AXN, swh, 256 + col, lane);
    stH(SM, SLB1, 0, lane, col, lrelu4(c0));
    stH(SM, SLB1, 1, lane, col, lrelu4(c1));
    stH(SM, SLB1, 2, lane, col, lrelu4(c2));
  }
  __syncthreads();
  // R1: selk0 -> AOV, selk1 -> ASK (hi-B)
  {
    f32x4 k0 = Z, k1 = Z, k2 = Z, m0 = Z, m1 = Z, m2 = Z;
    gemmAW2_3(k0, k1, k2, m0, m1, m2, SM, AEN,
              wsu + OFF_FT0, wsu + OFF_FT1, col, lane);
    stSK(SM, AOV, 0, lane, col, k0); stSK(SM, AOV, 1, lane, col, k1); stSK(SM, AOV, 2, lane, col, k2);
    stSK(SM, ASK, 0, lane, col, m0); stSK(SM, ASK, 1, lane, col, m1); stSK(SM, ASK, 2, lane, col, m2);
  }
  __syncthreads();
  // R2: oa vals (both slices, shared hi-B) + logit dots + exp
  f32x4 va0, va1, va2, vb0, vb1, vb2;
  {
    const float vb = aval_b[col];
    va0 = binit(vb); va1 = va0; va2 = va0; vb0 = va0; vb1 = va0; vb2 = va0;
    gemmA2s3(va0, va1, va2, vb0, vb1, vb2, SM, SLB0, SLB1, wsu + OFF_AV0, col, lane);
    if (drow < ROWS){
      int sw5 = (drow & 7) << 5, sw4 = (drow & 7) << 4;
      const unsigned char* kb = SM + AOV + drow * 256;
      short8 kfa = *(const short8*)(kb + (dcb ^ sw5));
      short8 kfb = *(const short8*)(kb + ((dcb + 16) ^ sw5));
      const unsigned char* s0 = SM + SLB0 + drow * 256;
      short8 e0a = *(const short8*)(s0 + (dcb ^ sw4));
      short8 e0b = *(const short8*)(s0 + ((dcb + 16) ^ sw4));
      const unsigned char* s1 = SM + SLB1 + drow * 256;
      short8 e1a = *(const short8*)(s1 + (dcb ^ sw4));
      short8 e1b = *(const short8*)(s1 + ((dcb + 16) ^ sw4));
      float p0 = dot8(kfa, e0a) + dot8(kfb, e0b);
      float p1 = dot8(kfa, e1a) + dot8(kfb, e1b);
      RED8(p0) RED8(p1)
      if ((lane & 7) == 0){
        float e0 = __expf(p0 * SCALE), e1 = __expf(p1 * SCALE);
        eP0[drow] = e0; eP1[drow] = e1; esm[drow] = e0 + e1;
      }
    }
  }
  __syncthreads();
  // R3: ov0 -> AOV ; goal slices g0,g1,g2 -> SLB0,1,2 (hi-B)
  {
    f32x4 o;
    #pragma unroll
    for (int r = 0; r < 4; ++r){
      int mr = r0base + r;
      o[r] = (eP0[mr] * lrelu(va0[r]) + eP1[mr] * lrelu(vb0[r])) / esm[mr];
    }
    stH(SM, AOV, 0, lane, col, o);
    #pragma unroll
    for (int r = 0; r < 4; ++r){
      int mr = 16 + r0base + r;
      o[r] = (eP0[mr] * lrelu(va1[r]) + eP1[mr] * lrelu(vb1[r])) / esm[mr];
    }
    stH(SM, AOV, 1, lane, col, o);
    #pragma unroll
    for (int r = 0; r < 4; ++r){
      int mr = 32 + r0base + r;
      o[r] = (eP0[mr] * lrelu(va2[r]) + eP1[mr] * lrelu(vb2[r])) / esm[mr];
    }
    stH(SM, AOV, 2, lane, col, o);
    const float bb = goal_b[n*HD + col];
    f32x4 c0 = binit(bb), c1 = c0, c2 = c0;
    gemmS3_hb(c0, c1, c2, SM, AXN, swh, 384 + col, lane);
    stH(SM, SLB0, 0, lane, col, lrelu4(c0));
    stH(SM, SLB0, 1, lane, col, lrelu4(c1));
    stH(SM, SLB0, 2, lane, col, lrelu4(c2));
    c0 = binit(bb); c1 = c0; c2 = c0;
    gemmS3_hb(c0, c1, c2, SM, AXN, swh, 512 + col, lane);
    stH(SM, SLB1, 0, lane, col, lrelu4(c0));
    stH(SM, SLB1, 1, lane, col, lrelu4(c1));
    stH(SM, SLB1, 2, lane, col, lrelu4(c2));
    c0 = binit(bb); c1 = c0; c2 = c0;
    gemmS3_hb(c0, c1, c2, SM, AXN, swh, 640 + col, lane);
    stH(SM, SLB2, 0, lane, col, lrelu4(c0));
    stH(SM, SLB2, 1, lane, col, lrelu4(c1));
    stH(SM, SLB2, 2, lane, col, lrelu4(c2));
  }
  __syncthreads();
  // R4: goal vals (3 slices x 3 mt, shared hi-B) + 3 dots + exps
  f32x4 g0m0, g0m1, g0m2, g1m0, g1m1, g1m2, g2m0, g2m1, g2m2;
  {
    const float vb = aval_b[HD + col];
    g0m0 = binit(vb); g0m1 = g0m0; g0m2 = g0m0;
    g1m0 = g0m0; g1m1 = g0m0; g1m2 = g0m0;
    g2m0 = g0m0; g2m1 = g0m0; g2m2 = g0m0;
    gemmA3s3(g0m0, g0m1, g0m2, g1m0, g1m1, g1m2, g2m0, g2m1, g2m2,
             SM, SLB0, SLB1, SLB2, wsu + OFF_AV1, col, lane);
    if (drow < ROWS){
      int sw5 = (drow & 7) << 5, sw4 = (drow & 7) << 4;
      const unsigned char* kb = SM + ASK + drow * 256;
      short8 kfa = *(const short8*)(kb + (dcb ^ sw5));
      short8 kfb = *(const short8*)(kb + ((dcb + 16) ^ sw5));
      const unsigned char* s0 = SM + SLB0 + drow * 256;
      short8 e0a = *(const short8*)(s0 + (dcb ^ sw4));
      short8 e0b = *(const short8*)(s0 + ((dcb + 16) ^ sw4));
      const unsigned char* s1 = SM + SLB1 + drow * 256;
      short8 e1a = *(const short8*)(s1 + (dcb ^ sw4));
      short8 e1b = *(const short8*)(s1 + ((dcb + 16) ^ sw4));
      const unsigned char* s2 = SM + SLB2 + drow * 256;
      short8 e2a = *(const short8*)(s2 + (dcb ^ sw4));
      short8 e2b = *(const short8*)(s2 + ((dcb + 16) ^ sw4));
      float p0 = dot8(kfa, e0a) + dot8(kfb, e0b);
      float p1 = dot8(kfa, e1a) + dot8(kfb, e1b);
      float p2 = dot8(kfa, e2a) + dot8(kfb, e2b);
      RED8(p0) RED8(p1) RED8(p2)
      if ((lane & 7) == 0){
        float e0 = __expf(p0 * SCALE), e1 = __expf(p1 * SCALE), e2 = __expf(p2 * SCALE);
        eP0[drow] = e0; eP1[drow] = e1; eP2[drow] = e2;
        esm[drow] = (e0 + e1) + e2;
      }
    }
  }
  __syncthreads();
  // R5: ov1 -> SLB0
  {
    f32x4 o;
    #pragma unroll
    for (int r = 0; r < 4; ++r){
      int mr = r0base + r;
      o[r] = ((eP0[mr] * lrelu(g0m0[r]) + eP1[mr] * lrelu(g1m0[r]))
              + eP2[mr] * lrelu(g2m0[r])) / esm[mr];
    }
    stH(SM, SLB0, 0, lane, col, o);
    #pragma unroll
    for (int r = 0; r < 4; ++r){
      int mr = 16 + r0base + r;
      o[r] = ((eP0[mr] * lrelu(g0m1[r]) + eP1[mr] * lrelu(g1m1[r]))
              + eP2[mr] * lrelu(g2m1[r])) / esm[mr];
    }
    stH(SM, SLB0, 1, lane, col, o);
    #pragma unroll
    for (int r = 0; r < 4; ++r){
      int mr = 32 + r0base + r;
      o[r] = ((eP0[mr] * lrelu(g0m2[r]) + eP1[mr] * lrelu(g1m2[r]))
              + eP2[mr] * lrelu(g2m2[r])) / esm[mr];
    }
    stH(SM, SLB0, 2, lane, col, o);
  }
  __syncthreads();
  // R6: merge (hi-B) -> SLB1
  {
    const unsigned short* mh = wsu + OFF_MG(n);
    f32x4 c0 = binit(merge_b[n*HD + col]), c1 = c0, c2 = c0;
    gemmAh_hb3K(c0, c1, c2, SM, AEN,  mh, 384, col, 0,   lane);
    gemmAh_hb3K(c0, c1, c2, SM, AOV,  mh, 384, col, 128, lane);
    gemmAh_hb3K(c0, c1, c2, SM, SLB0, mh, 384, col, 256, lane);
    stH(SM, SLB1, 0, lane, col, lrelu4(c0));
    stH(SM, SLB1, 1, lane, col, lrelu4(c1));
    stH(SM, SLB1, 2, lane, col, lrelu4(c2));
  }
  __syncthreads();
  // R7: coalesced copy SLB1 -> sa_g (padded)
  for (int idx = t; idx < ROWS * 16; idx += 512){
    int row = idx >> 4, ch = idx & 15;
    short8 u = *(const short8*)(SM + SLB1 + row * 256 + ((ch * 16) ^ ((row & 7) << 4)));
    *(short8*)(sa_g + ((size_t)n * PADB + gb0 + row) * HD + ch * 8) = u;
  }
}

// ======================================================================
// PATH A: critic kernel — grid (NBLK, NAG=i), 512 threads, ROWS=48, 66.4KB LDS
// ======================================================================
__global__ __launch_bounds__(512, 4) void critic_kernel(
    const float* __restrict__ s, const float* __restrict__ a,
    const float* __restrict__ senc_b, const float* __restrict__ cval_b,
    const float* __restrict__ cb1, const float* __restrict__ cW2,
    const float* __restrict__ cb2, const unsigned char* __restrict__ wsc,
    const unsigned short* __restrict__ sa_g, float* __restrict__ out)
{
  __shared__ __align__(16) unsigned char SM[67968];
  const int CXN = 0, CEN = 6144, CSMo = 18432, CSA = 30720, COV = 55296, CH = 30720, CLW = 67584;
  const int t = threadIdx.x, lane = t & 63, wave = t >> 6;
  const int col = wave * 16 + (lane & 15);
  const int i = blockIdx.y;
  const int gb0 = blockIdx.x * ROWS;
  const int j0 = (i == 0) ? 1 : 0;
  const int j1 = (i == 2) ? 1 : 2;
  const float* stats = (const float*)(wsc + WSB_STATS);
  const unsigned short* wsu = (const unsigned short*)(wsc + WSB_W);
  const unsigned short* swh = wsu + OFF_SW(i);
  const f32x4 Z = binit(0.f);
  const int drow = wave * 8 + (lane >> 3);
  const int dcb  = (lane & 7) * 32;
  const int r0base = (lane >> 4) << 2;

  // R0: stage XN_i (split, clamped) + copy sa_j0/j1 -> LDS (hi, swz)
  if (t < ROWS){
    int row = t;
    size_t gb = (size_t)gb0 + row;
    if (gb >= BATCH) gb = BATCH - 1;
    const float* st = stats + i * 40;
    const float* srow = s + ((size_t)i * BATCH + gb) * SD;
    const float* arow = a + ((size_t)i * BATCH + gb) * 2;
    #pragma unroll
    for (int c = 0; c < 32; ++c){
      float v = 0.f;
      if (c < 18) v = (srow[c] - st[c*2]) * st[c*2+1];
      else if (c < 20) v = (arow[c-18] - st[c*2]) * st[c*2+1];
      unsigned short hi = f2bf(v);
      int off = CXN + row * 64 + ((c * 2) ^ ((row & 3) << 4));
      *(unsigned short*)(SM + off) = hi;
      *(unsigned short*)(SM + off + 3072) = f2bf(v - bf2f(hi));
    }
  }
  for (int idx = t; idx < 2 * ROWS * 16; idx += 512){
    int tile = idx >= ROWS * 16;
    int k = idx - tile * ROWS * 16;
    int row = k >> 4, ch = k & 15;
    int j = tile ? j1 : j0;
    short8 u = *(const short8*)(sa_g + ((size_t)j * PADB + gb0 + row) * HD + ch * 8);
    *(short8*)(SM + CSA + tile * 12288 + row * 256 + ((ch * 16) ^ ((row & 7) << 4))) = u;
  }
  __syncthreads();
  // R1: s_enc -> CEN (hi-B)
  {
    f32x4 c0 = binit(senc_b[i*HD + col]), c1 = c0, c2 = c0;
    gemmS3_hb(c0, c1, c2, SM, CXN, swh, 768 + col, lane);
    stH(SM, CEN, 0, lane, col, lrelu4(c0));
    stH(SM, CEN, 1, lane, col, lrelu4(c1));
    stH(SM, CEN, 2, lane, col, lrelu4(c2));
  }
  __syncthreads();
  // R2: selsM = s_enc @ M (hi-B) -> CSM (32B-swz)
  {
    f32x4 k0 = Z, k1 = Z, k2 = Z;
    gemmAh_hb3(k0, k1, k2, SM, CEN, wsu + OFF_MT, col, lane);
    stSK(SM, CSMo, 0, lane, col, k0);
    stSK(SM, CSMo, 1, lane, col, k1);
    stSK(SM, CSMo, 2, lane, col, k2);
  }
  __syncthreads();
  // R3: vals GEMMs (2 sa-tiles x 3 mt, shared hi-B) + dots + 2-way softmax
  f32x4 v00, v01, v02, v10, v11, v12;
  {
    const float vb = cval_b[col];
    v00 = binit(vb); v01 = v00; v02 = v00; v10 = v00; v11 = v00; v12 = v00;
    gemmA2s3(v00, v01, v02, v10, v11, v12, SM, CSA, CSA + 12288,
             wsu + OFF_CV, col, lane);
    if (drow < ROWS){
      int sw5 = (drow & 7) << 5, sw4 = (drow & 7) << 4;
      const unsigned char* mb = SM + CSMo + drow * 256;
      short8 ma = *(const short8*)(mb + (dcb ^ sw5));
      short8 mbf = *(const short8*)(mb + ((dcb + 16) ^ sw5));
      const unsigned char* a0p = SM + CSA + drow * 256;
      short8 a0a = *(const short8*)(a0p + (dcb ^ sw4));
      short8 a0b = *(const short8*)(a0p + ((dcb + 16) ^ sw4));
      const unsigned char* b0p = SM + CSA + 12288 + drow * 256;
      short8 b0a = *(const short8*)(b0p + (dcb ^ sw4));
      short8 b0b = *(const short8*)(b0p + ((dcb + 16) ^ sw4));
      float p0 = dot8(ma, a0a) + dot8(mbf, a0b);
      float p1 = dot8(ma, b0a) + dot8(mbf, b0b);
      RED8(p0) RED8(p1)
      if ((lane & 7) == 0){
        float e0 = __expf(p0 * SCALE), e1 = __expf(p1 * SCALE);
        float inv = 1.f / (e0 + e1);
        ((float*)(SM + CLW))[drow]      = e0 * inv;
        ((float*)(SM + CLW))[48 + drow] = e1 * inv;
      }
    }
  }
  __syncthreads();
  // R4: ov -> COV (hi)
  {
    const float* w0 = (const float*)(SM + CLW);
    const float* w1 = w0 + 48;
    f32x4 o;
    #pragma unroll
    for (int r = 0; r < 4; ++r){
      int mr = r0base + r;
      o[r] = w0[mr] * lrelu(v00[r]) + w1[mr] * lrelu(v10[r]);
    }
    stH(SM, COV, 0, lane, col, o);
    #pragma unroll
    for (int r = 0; r < 4; ++r){
      int mr = 16 + r0base + r;
      o[r] = w0[mr] * lrelu(v01[r]) + w1[mr] * lrelu(v11[r]);
    }
    stH(SM, COV, 1, lane, col, o);
    #pragma unroll
    for (int r = 0; r < 4; ++r){
      int mr = 32 + r0base + r;
      o[r] = w0[mr] * lrelu(v02[r]) + w1[mr] * lrelu(v12[r]);
    }
    stH(SM, COV, 2, lane, col, o);
  }
  __syncthreads();
  // R5: h = lrelu([s_enc|ov] @ cW1 + b) -> CH (hi-B; h stored split; overwrites CSA)
  {
    const unsigned short* c1h = wsu + OFF_C1(i);
    f32x4 h0 = binit(cb1[i*HD + col]), h1 = h0, h2 = h0;
    gemmAh_hb3K(h0, h1, h2, SM, CEN, c1h, 256, col, 0,   lane);
    gemmAh_hb3K(h0, h1, h2, SM, COV, c1h, 256, col, 128, lane);
    stTileC(SM, CH, 0, lane, col, lrelu4(h0));
    stTileC(SM, CH, 1, lane, col, lrelu4(h1));
    stTileC(SM, CH, 2, lane, col, lrelu4(h2));
  }
  __syncthreads();
  // R6: q = h @ cW2 + cb2 (per-row dot, split h), guarded out store
  if (drow < ROWS && gb0 + drow < BATCH){
    int sw4 = (drow & 7) << 4;
    const unsigned char* hb = SM + CH + drow * 256;
    short8 ha = *(const short8*)(hb + (dcb ^ sw4));
    short8 hbf = *(const short8*)(hb + ((dcb + 16) ^ sw4));
    short8 la = *(const short8*)(hb + 12288 + (dcb ^ sw4));
    short8 lb = *(const short8*)(hb + 12288 + ((dcb + 16) ^ sw4));
    float q0 = 0.f, q1 = 0.f;
    #pragma unroll
    for (int e = 0; e < 8; ++e){
      int d = (lane & 7) * 16 + e;
      float hv = bf2f((unsigned short)ha[e]) + bf2f((unsigned short)la[e]);
      q0 = fmaf(hv, cW2[(i * HD + d) * 2 + 0], q0);
      q1 = fmaf(hv, cW2[(i * HD + d) * 2 + 1], q1);
    }
    #pragma unroll
    for (int e = 0; e < 8; ++e){
      int d = (lane & 7) * 16 + 8 + e;
      float hv = bf2f((unsigned short)hbf[e]) + bf2f((unsigned short)lb[e]);
      q0 = fmaf(hv, cW2[(i * HD + d) * 2 + 0], q0);
      q1 = fmaf(hv, cW2[(i * HD + d) * 2 + 1], q1);
    }
    RED8(q0) RED8(q1)
    if ((lane & 7) == 0){
      out[((size_t)i * BATCH + gb0 + drow) * 2 + 0] = q0 + cb2[i * 2 + 0];
      out[((size_t)i * BATCH + gb0 + drow) * 2 + 1] = q1 + cb2[i * 2 + 1];
    }
  }
}

// ======================================================================
// PATH B fallback: TB=32 helpers + round-2 fused kernel (proven)
// ======================================================================
__device__ __forceinline__ void gemmA(f32x4& c0, f32x4& c1, const unsigned char* sm, int abase,
                                      const unsigned short* wh, const unsigned short* wl,
                                      int K, int bcol, int kBaseB, int lane){
  const size_t bb = (size_t)bcol * K + kBaseB + ((lane >> 4) << 3);
  #pragma unroll
  for (int ks = 0; ks < 4; ++ks){
    short8 ah0, al0, ah1, al1;
    ldA(sm, abase, 0, ks, lane, ah0, al0);
    ldA(sm, abase, 1, ks, lane, ah1, al1);
    const short8 bh = *(const short8*)(wh + bb + ks * 32);
    const short8 bl = *(const short8*)(wl + bb + ks * 32);
    MM3(c0, ah0, al0, bh, bl);
    MM3(c1, ah1, al1, bh, bl);
  }
}
__device__ __forceinline__ void gemmS(f32x4& c0, f32x4& c1, const unsigned char* sm, int abase,
                                      const unsigned short* wh, const unsigned short* wl,
                                      int bcol, int lane){
  const size_t bb = (size_t)bcol * 32 + ((lane >> 4) << 3);
  short8 ah0, al0, ah1, al1;
  ldA32(sm, abase, 0, lane, ah0, al0);
  ldA32(sm, abase, 1, lane, ah1, al1);
  const short8 bh = *(const short8*)(wh + bb);
  const short8 bl = *(const short8*)(wl + bb);
  MM3(c0, ah0, al0, bh, bl);
  MM3(c1, ah1, al1, bh, bl);
}
__device__ __forceinline__ void dotTile(unsigned char* sm, int tbase, const f32x4 d0, const f32x4 d1,
                                        int lane, int wave, int col, int part_o){
  float* part = (float*)(sm + part_o);
  #pragma unroll
  for (int mi = 0; mi < 2; ++mi){
    #pragma unroll
    for (int r = 0; r < 4; ++r){
      int row = mi * 16 + ((lane >> 4) << 2) + r;
      int off = tbase + row * 256 + ((col * 2) ^ ((row & 7) << 4));
      float v = bf2f(*(const unsigned short*)(sm + off)) +
                bf2f(*(const unsigned short*)(sm + off + 8192));
      float p = (mi ? d1[r] : d0[r]) * v;
      RED16(p)
      if ((lane & 15) == 0) part[wave * 32 + row] = p;
    }
  }
}

#define XN_O    0
#define EN_O    12288
#define SLICE_O 28672
#define OV0_O   45056
#define SA_O    61440
#define PART_O  110592
#define EP_O    111616
#define ESUM_O  111744
#define LW_O    111872
#define SM_TOTAL 113024

__global__ __launch_bounds__(512, 2) void fused_kernel(
    const float* __restrict__ s, const float* __restrict__ a,
    const float* __restrict__ en_b, const float* __restrict__ oa_b,
    const float* __restrict__ goal_b, const float* __restrict__ aval_b,
    const float* __restrict__ merge_b, const float* __restrict__ senc_b,
    const float* __restrict__ cval_b, const float* __restrict__ cb1,
    const float* __restrict__ cb2, const unsigned char* __restrict__ wsc,
    float* __restrict__ out)
{
  __shared__ __align__(16) unsigned char SM[SM_TOTAL];
  unsigned char* sm = SM;
  const int t = threadIdx.x;
  const int lane = t & 63;
  const int wave = t >> 6;
  const int col = wave * 16 + (lane & 15);
  const int gb0 = blockIdx.x * TB;
  const float* stats = (const float*)(wsc + WSB_STATS);
  const unsigned short* wsu = (const unsigned short*)(wsc + WSB_W);
  const f32x4 Z = binit(0.f);

  if (t < 96){
    int n = t >> 5, row = t & 31;
    size_t gb = (size_t)gb0 + row;
    const float* st = stats + n * 40;
    const float* srow = s + ((size_t)n * BATCH + gb) * SD;
    const float* arow = a + ((size_t)n * BATCH + gb) * 2;
    #pragma unroll
    for (int c = 0; c < 32; ++c){
      float v = 0.f;
      if (c < 18) v = (srow[c] - st[c*2]) * st[c*2+1];
      else if (c < 20) v = (arow[c-18] - st[c*2]) * st[c*2+1];
      unsigned short hi = f2bf(v);
      int off = XN_O + n * 4096 + row * 64 + ((c * 2) ^ ((row & 3) << 4));
      *(unsigned short*)(sm + off) = hi;
      *(unsigned short*)(sm + off + 2048) = f2bf(v - bf2f(hi));
    }
  }
  __syncthreads();

  #pragma unroll 1
  for (int n = 0; n < NAG; ++n){
    const unsigned short* swh = wsu + OFF_SW(n);
    const unsigned short* swl = swh + 28672;
    {
      f32x4 v0 = binit(en_b[n*HD + col]), v1 = v0;
      gemmS(v0, v1, sm, XN_O + n*4096, swh, swl, 0 + col, lane);
      stTile(sm, EN_O, 0, lane, col, lrelu4(v0));
      stTile(sm, EN_O, 1, lane, col, lrelu4(v1));
    }
    __syncthreads();
    f32x4 sk0a = Z, sk0b = Z, sk1a = Z, sk1b = Z;
    gemmA(sk0a, sk0b, sm, EN_O, wsu + OFF_FT0, wsu + OFF_FT0 + 16384, 128, col, 0, lane);
    gemmA(sk1a, sk1b, sm, EN_O, wsu + OFF_FT1, wsu + OFF_FT1 + 16384, 128, col, 0, lane);

    f32x4 ov0a = Z, ov0b = Z;
    #pragma unroll 1
    for (int j = 0; j < 2; ++j){
      __syncthreads();
      f32x4 v0 = binit(oa_b[n*HD + col]), v1 = v0;
      gemmS(v0, v1, sm, XN_O + n*4096, swh, swl, 128*(1+j) + col, lane);
      stTile(sm, SLICE_O, 0, lane, col, lrelu4(v0));
      stTile(sm, SLICE_O, 1, lane, col, lrelu4(v1));
      __syncthreads();
      dotTile(sm, SLICE_O, sk0a, sk0b, lane, wave, col, PART_O);
      __syncthreads();
      if (t < TB){
        const float* part = (const float*)(sm + PART_O);
        float tot = 0.f;
        #pragma unroll
        for (int w2 = 0; w2 < 8; ++w2) tot += part[w2*32 + t];
        float e = __expf(tot * SCALE);
        ((float*)(sm + EP_O))[t] = e;
        float* es = (float*)(sm + ESUM_O);
        es[t] = (j == 0) ? e : es[t] + e;
      }
      __syncthreads();
      f32x4 w0 = binit(aval_b[col]), w1 = w0;
      gemmA(w0, w1, sm, SLICE_O, wsu + OFF_AV0, wsu + OFF_AV0 + 16384, 128, col, 0, lane);
      const float* eP = (const float*)(sm + EP_O);
      #pragma unroll
      for (int r = 0; r < 4; ++r){
        int row0 = ((lane >> 4) << 2) + r;
        ov0a[r] += eP[row0]      * lrelu(w0[r]);
        ov0b[r] += eP[row0 + 16] * lrelu(w1[r]);
      }
    }
    {
      const float* es = (const float*)(sm + ESUM_O);
      f32x4 o0, o1;
      #pragma unroll
      for (int r = 0; r < 4; ++r){
        int row0 = ((lane >> 4) << 2) + r;
        o0[r] = ov0a[r] / es[row0];
        o1[r] = ov0b[r] / es[row0 + 16];
      }
      stTile(sm, OV0_O, 0, lane, col, o0);
      stTile(sm, OV0_O, 1, lane, col, o1);
    }

    f32x4 ov1a = Z, ov1b = Z;
    #pragma unroll 1
    for (int j = 0; j < 3; ++j){
      __syncthreads();
      f32x4 v0 = binit(goal_b[n*HD + col]), v1 = v0;
      gemmS(v0, v1, sm, XN_O + n*4096, swh, swl, 128*(3+j) + col, lane);
      stTile(sm, SLICE_O, 0, lane, col, lrelu4(v0));
      stTile(sm, SLICE_O, 1, lane, col, lrelu4(v1));
      __syncthreads();
      dotTile(sm, SLICE_O, sk1a, sk1b, lane, wave, col, PART_O);
      __syncthreads();
      if (t < TB){
        const float* part = (const float*)(sm + PART_O);
        float tot = 0.f;
        #pragma unroll
        for (int w2 = 0; w2 < 8; ++w2) tot += part[w2*32 + t];
        float e = __expf(tot * SCALE);
        ((float*)(sm + EP_O))[t] = e;
        float* es = (float*)(sm + ESUM_O);
        es[t] = (j == 0) ? e : es[t] + e;
      }
      __syncthreads();
      f32x4 w0 = binit(aval_b[HD + col]), w1 = w0;
      gemmA(w0, w1, sm, SLICE_O, wsu + OFF_AV1, wsu + OFF_AV1 + 16384, 128, col, 0, lane);
      const float* eP = (const float*)(sm + EP_O);
      #pragma unroll
      for (int r = 0; r < 4; ++r){
        int row0 = ((lane >> 4) << 2) + r;
        ov1a[r] += eP[row0]      * lrelu(w0[r]);
        ov1b[r] += eP[row0 + 16] * lrelu(w1[r]);
      }
    }
    __syncthreads();
    {
      const float* es = (const float*)(sm + ESUM_O);
      f32x4 o0, o1;
      #pragma unroll
      for (int r = 0; r < 4; ++r){
        int row0 = ((lane >> 4) << 2) + r;
        o0[r] = ov1a[r] / es[row0];
        o1[r] = ov1b[r] / es[row0 + 16];
      }
      stTile(sm, SLICE_O, 0, lane, col, o0);
      stTile(sm, SLICE_O, 1, lane, col, o1);
    }
    __syncthreads();
    {
      const unsigned short* mhp = wsu + OFF_MG(n);
      const unsigned short* mlp = mhp + 49152;
      f32x4 m0 = binit(merge_b[n*HD + col]), m1 = m0;
      gemmA(m0, m1, sm, EN_O,    mhp, mlp, 384, col, 0,   lane);
      gemmA(m0, m1, sm, OV0_O,   mhp, mlp, 384, col, 128, lane);
      gemmA(m0, m1, sm, SLICE_O, mhp, mlp, 384, col, 256, lane);
      stTile(sm, SA_O + n*16384, 0, lane, col, lrelu4(m0));
      stTile(sm, SA_O + n*16384, 1, lane, col, lrelu4(m1));
    }
    __syncthreads();
  }

  #pragma unroll 1
  for (int i = 0; i < NAG; ++i){
    const unsigned short* swh = wsu + OFF_SW(i);
    const unsigned short* swl = swh + 28672;
    f32x4 e0 = binit(senc_b[i*HD + col]), e1 = e0;
    gemmS(e0, e1, sm, XN_O + i*4096, swh, swl, 768 + col, lane);
    stTile(sm, EN_O, 0, lane, col, lrelu4(e0));
    stTile(sm, EN_O, 1, lane, col, lrelu4(e1));
    __syncthreads();
    f32x4 sm0 = Z, sm1 = Z;
    gemmA(sm0, sm1, sm, EN_O, wsu + OFF_MT, wsu + OFF_MT + 16384, 128, col, 0, lane);
    #pragma unroll 1
    for (int j = 0; j < NAG; ++j){
      if (j == i) continue;
      dotTile(sm, SA_O + j*16384, sm0, sm1, lane, wave, col, PART_O);
      __syncthreads();
      if (t < TB){
        const float* part = (const float*)(sm + PART_O);
        float tot = 0.f;
        #pragma unroll
        for (int w2 = 0; w2 < 8; ++w2) tot += part[w2*32 + t];
        ((float*)(sm + LW_O))[(i*3 + j)*32 + t] = tot;
      }
      __syncthreads();
    }
  }
  if (t < TB){
    float* LW = (float*)(sm + LW_O);
    #pragma unroll
    for (int i = 0; i < NAG; ++i){
      int j0 = (i == 0) ? 1 : 0;
      int j1 = (i == 2) ? 1 : 2;
      float l0 = LW[(i*3 + j0)*32 + t] * SCALE;
      float l1 = LW[(i*3 + j1)*32 + t] * SCALE;
      float q0 = __expf(l0), q1 = __expf(l1);
      float inv = 1.f / (q0 + q1);
      LW[(i*3 + j0)*32 + t] = q0 * inv;
      LW[(i*3 + j1)*32 + t] = q1 * inv;
    }
  }
  __syncthreads();
  f32x4 oc00 = Z, oc01 = Z, oc10 = Z, oc11 = Z, oc20 = Z, oc21 = Z;
  {
    const float* LW = (const float*)(sm + LW_O);
    #pragma unroll 1
    for (int j = 0; j < NAG; ++j){
      f32x4 v0 = binit(cval_b[col]), v1 = v0;
      gemmA(v0, v1, sm, SA_O + j*16384, wsu + OFF_CV, wsu + OFF_CV + 16384, 128, col, 0, lane);
      v0 = lrelu4(v0); v1 = lrelu4(v1);
      #pragma unroll
      for (int i = 0; i < NAG; ++i){
        if (i == j) continue;
        f32x4& o0 = (i == 0) ? oc00 : ((i == 1) ? oc10 : oc20);
        f32x4& o1 = (i == 0) ? oc01 : ((i == 1) ? oc11 : oc21);
        #pragma unroll
        for (int r = 0; r < 4; ++r){
          int row0 = ((lane >> 4) << 2) + r;
          o0[r] += LW[(i*3 + j)*32 + row0]      * v0[r];
          o1[r] += LW[(i*3 + j)*32 + row0 + 16] * v1[r];
        }
      }
    }
  }
  __syncthreads();
  #pragma unroll 1
  for (int i = 0; i < NAG; ++i){
    const unsigned short* swh = wsu + OFF_SW(i);
    const unsigned short* swl = swh + 28672;
    f32x4 se0 = binit(senc_b[i*HD + col]), se1 = se0;
    gemmS(se0, se1, sm, XN_O + i*4096, swh, swl, 768 + col, lane);
    stTile(sm, EN_O, 0, lane, col, lrelu4(se0));
    stTile(sm, EN_O, 1, lane, col, lrelu4(se1));
    {
      f32x4 o0 = (i == 0) ? oc00 : ((i == 1) ? oc10 : oc20);
      f32x4 o1 = (i == 0) ? oc01 : ((i == 1) ? oc11 : oc21);
      stTile(sm, OV0_O, 0, lane, col, o0);
      stTile(sm, OV0_O, 1, lane, col, o1);
    }
    __syncthreads();
    const unsigned short* c1h = wsu + OFF_C1(i);
    const unsigned short* c1l = c1h + 32768;
    f32x4 h0 = binit(cb1[i*HD + col]), h1 = h0;
    gemmA(h0, h1, sm, EN_O,  c1h, c1l, 256, col, 0,   lane);
    gemmA(h0, h1, sm, OV0_O, c1h, c1l, 256, col, 128, lane);
    stTile(sm, SLICE_O, 0, lane, col, lrelu4(h0));
    stTile(sm, SLICE_O, 1, lane, col, lrelu4(h1));
    __syncthreads();
    f32x4 q0 = Z, q1 = Z;
    gemmA(q0, q1, sm, SLICE_O, wsu + OFF_C2(i), wsu + OFF_C2(i) + 2048, 128, (lane & 15), 0, lane);
    if (wave == 0 && (lane & 15) < 2){
      int c2 = lane & 15;
      float bb = cb2[i*2 + c2];
      #pragma unroll
      for (int r = 0; r < 4; ++r){
        int row = ((lane >> 4) << 2) + r;
        out[((size_t)i*BATCH + gb0 + row)*2 + c2]      = q0[r] + bb;
        out[((size_t)i*BATCH + gb0 + row + 16)*2 + c2] = q1[r] + bb;
      }
    }
    __syncthreads();
  }
}

// ------------------------------------------------------------ launch -----
extern "C" void kernel_launch(void* const* d_in, const int* in_sizes, int n_in,
                              void* d_out, int out_size, void* d_ws, size_t ws_size,
                              hipStream_t stream) {
  const float* s       = (const float*)d_in[0];
  const float* a       = (const float*)d_in[1];
  const float* en_W    = (const float*)d_in[2];
  const float* en_b    = (const float*)d_in[3];
  const float* oa_W    = (const float*)d_in[4];
  const float* oa_b    = (const float*)d_in[5];
  const float* goal_W  = (const float*)d_in[6];
  const float* goal_b  = (const float*)d_in[7];
  const float* akey_W  = (const float*)d_in[8];
  const float* asel_W  = (const float*)d_in[9];
  const float* aval_W  = (const float*)d_in[10];
  const float* aval_b  = (const float*)d_in[11];
  const float* merge_W = (const float*)d_in[12];
  const float* merge_b = (const float*)d_in[13];
  const float* senc_W  = (const float*)d_in[14];
  const float* senc_b  = (const float*)d_in[15];
  const float* ckey_W  = (const float*)d_in[16];
  const float* csel_W  = (const float*)d_in[17];
  const float* cval_W  = (const float*)d_in[18];
  const float* cval_b  = (const float*)d_in[19];
  const float* cW1     = (const float*)d_in[20];
  const float* cb1     = (const float*)d_in[21];
  const float* cW2     = (const float*)d_in[22];
  const float* cb2     = (const float*)d_in[23];
  unsigned char* wsc = (unsigned char*)d_ws;
  float* F = (float*)(wsc + WSB_F);
  unsigned short* wsu = (unsigned short*)(wsc + WSB_W);
  float* out = (float*)d_out;

  hipMemsetAsync(wsc + WSB_ACCUM, 0, 480, stream);
  stats_partial_kernel<<<48, 256, 0, stream>>>(s, a, (float*)(wsc + WSB_ACCUM));
  fuse_mats_kernel<<<dim3(HD, 4), HD, 0, stream>>>(
      asel_W, akey_W, csel_W, ckey_W, F,
      (const float*)(wsc + WSB_ACCUM), (float*)(wsc + WSB_STATS));
  prep_split_kernel<<<dim3(336, 16), 256, 0, stream>>>(
      F, aval_W, cval_W, merge_W, cW1, cW2, en_W, oa_W, goal_W, senc_W, wsu);

  if (ws_size >= (size_t)WSB_SA + SA_BYTES_P){
    unsigned short* sa_g = (unsigned short*)(wsc + WSB_SA);
    actor_kernel<<<dim3(NBLK, NAG), 512, 0, stream>>>(
        s, a, en_b, oa_b, goal_b, aval_b, merge_b,
        (const unsigned char*)wsc, sa_g);
    critic_kernel<<<dim3(NBLK, NAG), 512, 0, stream>>>(
        s, a, senc_b, cval_b, cb1, cW2, cb2,
        (const unsigned char*)wsc, (const unsigned short*)sa_g, out);
  } else {
    fused_kernel<<<BATCH / TB, 512, 0, stream>>>(
        s, a, en_b, oa_b, goal_b, aval_b, merge_b, senc_b, cval_b, cb1, cb2,
        (const unsigned char*)wsc, out);
  }
}

// Round 16
// 208.747 us; speedup vs baseline: 2.5459x; 1.0130x over previous
//
#include <hip/hip_runtime.h>
#include <hip/hip_bf16.h>

#define NAG 3
#define BATCH 32768
#define HD 128
#define SD 18
#define TB 32
#define ROWS 48
#define NBLK 683
#define PADB (NBLK * ROWS)     // 32784
#define EPSV 1e-5f
#define SCALE 0.08838834764831845f

typedef __attribute__((ext_vector_type(8))) short short8;
typedef __attribute__((ext_vector_type(4))) float f32x4;

// ---------------- ws byte layout ----------------
#define WSB_STATS 0
#define WSB_ACCUM 512
#define WSB_F     1024
#define WSB_W     197632
#define OFF_FT0 0
#define OFF_FT1 32768
#define OFF_MT  65536
#define OFF_AV0 98304
#define OFF_AV1 131072
#define OFF_CV  163840
#define OFF_MG(n) (196608 + (n)*98304)
#define OFF_C1(n) (491520 + (n)*65536)
#define OFF_C2(n) (688128 + (n)*4096)
#define OFF_SW(n) (700416 + (n)*57344)
#define WSB_SA  2097152
#define SA_BYTES_P ((size_t)NAG * PADB * HD * 2)

__device__ __forceinline__ float lrelu(float x){ return x >= 0.0f ? x : 0.01f * x; }
__device__ __forceinline__ f32x4 lrelu4(f32x4 v){
  f32x4 r; r[0]=lrelu(v[0]); r[1]=lrelu(v[1]); r[2]=lrelu(v[2]); r[3]=lrelu(v[3]); return r;
}
__device__ __forceinline__ f32x4 binit(float b){ f32x4 c; c[0]=b;c[1]=b;c[2]=b;c[3]=b; return c; }
__device__ __forceinline__ unsigned short f2bf(float f){
  __hip_bfloat16 h = __float2bfloat16(f);     // HW v_cvt (RNE)
  return *reinterpret_cast<unsigned short*>(&h);
}
__device__ __forceinline__ float bf2f(unsigned short h){
  return __uint_as_float(((unsigned int)h) << 16);
}

// ---------------- prep: batch stats ----------------
__global__ void stats_partial_kernel(const float* __restrict__ s,
                                     const float* __restrict__ a,
                                     float* __restrict__ accum){
  const int n = blockIdx.x >> 4;
  const int chunk = blockIdx.x & 15;
  const int t = threadIdx.x;
  const int rows = BATCH / 16;
  const int b0 = chunk * rows;
  float sum[20], sq[20];
  #pragma unroll
  for (int c = 0; c < 20; ++c){ sum[c] = 0.f; sq[c] = 0.f; }
  for (int b = b0 + t; b < b0 + rows; b += 256){
    const float* row = s + ((size_t)n * BATCH + b) * SD;
    #pragma unroll
    for (int c = 0; c < SD; ++c){ float v = row[c]; sum[c] += v; sq[c] += v * v; }
    const float* ra = a + ((size_t)n * BATCH + b) * 2;
    #pragma unroll
    for (int c = 0; c < 2; ++c){ float v = ra[c]; sum[SD + c] += v; sq[SD + c] += v * v; }
  }
  __shared__ float red[256];
  for (int c = 0; c < 20; ++c){
    red[t] = sum[c]; __syncthreads();
    for (int off = 128; off > 0; off >>= 1){ if (t < off) red[t] += red[t + off]; __syncthreads(); }
    if (t == 0) atomicAdd(&accum[(n * 20 + c) * 2 + 0], red[0]);
    __syncthreads();
    red[t] = sq[c]; __syncthreads();
    for (int off = 128; off > 0; off >>= 1){ if (t < off) red[t] += red[t + off]; __syncthreads(); }
    if (t == 0) atomicAdd(&accum[(n * 20 + c) * 2 + 1], red[0]);
    __syncthreads();
  }
}

// ---------------- prep: F_m = sel @ key^T + stats finalize ----------------
__global__ void fuse_mats_kernel(const float* __restrict__ asel, const float* __restrict__ akey,
                                 const float* __restrict__ csel, const float* __restrict__ ckey,
                                 float* __restrict__ F, const float* __restrict__ accum,
                                 float* __restrict__ stats){
  const int m  = blockIdx.y;
  if (m == 3){
    if (blockIdx.x == 0){
      int i = threadIdx.x;
      if (i < 60){
        float S = accum[i * 2 + 0], SQ = accum[i * 2 + 1];
        float mean = S / (float)BATCH;
        float var = SQ / (float)BATCH - mean * mean;
        stats[i * 2 + 0] = mean;
        stats[i * 2 + 1] = 1.0f / sqrtf(var + EPSV);
      }
    }
    return;
  }
  const int h1 = blockIdx.x;
  const int h2 = threadIdx.x;
  const float* A; const float* Bm;
  if (m == 0){ A = asel;            Bm = akey; }
  else if (m == 1){ A = asel + HD*HD; Bm = akey + HD*HD; }
  else { A = csel; Bm = ckey; }
  const float* arow = A + h1 * HD;
  const float* brow = Bm + h2 * HD;
  float acc = 0.f;
  #pragma unroll 4
  for (int d = 0; d < HD; ++d) acc = fmaf(arow[d], brow[d], acc);
  F[m * HD * HD + h1 * HD + h2] = acc;
}

// ---------------- prep: all weight splits + smallpack ----------------
__global__ void prep_split_kernel(const float* __restrict__ F, const float* __restrict__ aval_W,
                                  const float* __restrict__ cval_W, const float* __restrict__ merge_W,
                                  const float* __restrict__ cW1, const float* __restrict__ cW2,
                                  const float* __restrict__ en_W, const float* __restrict__ oa_W,
                                  const float* __restrict__ goal_W, const float* __restrict__ senc_W,
                                  unsigned short* __restrict__ wsu){
  const int job = blockIdx.y;
  const int idx = blockIdx.x * 256 + threadIdx.x;
  if (job == 15){
    if (idx >= 3 * 896 * 32) return;
    int k = idx & 31; int c = (idx >> 5) % 896; int n = idx / (896 * 32);
    int tt = c >> 7, cc = c & 127;
    float v = 0.f;
    if (tt == 0){
      if (k < 4) v = en_W[(size_t)(n*6 + k)*128 + cc];
      else if (k == 18 || k == 19) v = en_W[(size_t)(n*6 + 4 + (k-18))*128 + cc];
    } else if (tt <= 2){
      int j = tt - 1; int kk = k - (4 + 4*j);
      if (kk >= 0 && kk < 4) v = oa_W[(size_t)(n*4 + kk)*128 + cc];
    } else if (tt <= 5){
      int j = tt - 3; int kk = k - (12 + 2*j);
      if (kk >= 0 && kk < 2) v = goal_W[(size_t)(n*2 + kk)*128 + cc];
    } else {
      if (k < 18) v = senc_W[(size_t)(n*18 + k)*128 + cc];
    }
    unsigned short hi = f2bf(v); float lo = v - bf2f(hi);
    unsigned short* dh = wsu + OFF_SW(n);
    dh[c * 32 + k] = hi;
    dh[28672 + c * 32 + k] = f2bf(lo);
    return;
  }
  const float* src; unsigned short* dh; int K = 128, Csrc = 128, Cdst = 128, loff = 16384;
  switch (job){
    case 0: src = F;              dh = wsu + OFF_FT0; break;
    case 1: src = F + 16384;      dh = wsu + OFF_FT1; break;
    case 2: src = F + 32768;      dh = wsu + OFF_MT;  break;
    case 3: src = aval_W;         dh = wsu + OFF_AV0; break;
    case 4: src = aval_W + 16384; dh = wsu + OFF_AV1; break;
    case 5: src = cval_W;         dh = wsu + OFF_CV;  break;
    case 6: case 7: case 8: {
      int n = job - 6; src = merge_W + (size_t)n * 49152; dh = wsu + OFF_MG(n);
      K = 384; loff = 49152; } break;
    case 9: case 10: case 11: {
      int n = job - 9; src = cW1 + (size_t)n * 32768; dh = wsu + OFF_C1(n);
      K = 256; loff = 32768; } break;
    default: {
      int n = job - 12; src = cW2 + (size_t)n * 256; dh = wsu + OFF_C2(n);
      Csrc = 2; Cdst = 16; loff = 2048; } break;
  }
  if (idx >= K * Cdst) return;
  int k = idx / Cdst, c = idx - k * Cdst;
  float v = (c < Csrc) ? src[(size_t)k * Csrc + c] : 0.f;
  unsigned short hi = f2bf(v);
  dh[(size_t)c * K + k] = hi;
  dh[loff + (size_t)c * K + k] = f2bf(v - bf2f(hi));
}

// ---------------- MFMA helpers (shared) ----------------
__device__ __forceinline__ short8 ldAh(const unsigned char* sm, int base, int mi, int ks, int lane){
  int row = mi * 16 + (lane & 15);
  int bc  = ks * 64 + ((lane >> 4) << 4);
  return *(const short8*)(sm + base + row * 256 + (bc ^ ((row & 7) << 4)));
}
__device__ __forceinline__ void ldA(const unsigned char* sm, int base, int mi, int ks, int lane,
                                    short8& h, short8& l){
  int row = mi * 16 + (lane & 15);
  int bc  = ks * 64 + ((lane >> 4) << 4);
  int off = base + row * 256 + (bc ^ ((row & 7) << 4));
  h = *(const short8*)(sm + off);
  l = *(const short8*)(sm + off + 8192);
}
__device__ __forceinline__ void ldA32(const unsigned char* sm, int base, int mi, int lane,
                                      short8& h, short8& l){
  int row = mi * 16 + (lane & 15);
  int bc  = (lane >> 4) << 4;
  int off = base + row * 64 + (bc ^ ((row & 3) << 4));
  h = *(const short8*)(sm + off);
  l = *(const short8*)(sm + off + 2048);
}
__device__ __forceinline__ void ldA32_48(const unsigned char* sm, int base, int mi, int lane,
                                         short8& h, short8& l){
  int row = mi * 16 + (lane & 15);
  int bc  = (lane >> 4) << 4;
  int off = base + row * 64 + (bc ^ ((row & 3) << 4));
  h = *(const short8*)(sm + off);
  l = *(const short8*)(sm + off + 3072);
}
__device__ __forceinline__ short8 ldA32_48h(const unsigned char* sm, int base, int mi, int lane){
  int row = mi * 16 + (lane & 15);
  int bc  = (lane >> 4) << 4;
  return *(const short8*)(sm + base + row * 64 + (bc ^ ((row & 3) << 4)));
}

#define MM3(acc, ah, al, bh, bl) \
  acc = __builtin_amdgcn_mfma_f32_16x16x32_bf16(ah, bh, acc, 0, 0, 0); \
  acc = __builtin_amdgcn_mfma_f32_16x16x32_bf16(ah, bl, acc, 0, 0, 0); \
  acc = __builtin_amdgcn_mfma_f32_16x16x32_bf16(al, bh, acc, 0, 0, 0);
#define MM2(acc, ah, bh, bl) \
  acc = __builtin_amdgcn_mfma_f32_16x16x32_bf16(ah, bh, acc, 0, 0, 0); \
  acc = __builtin_amdgcn_mfma_f32_16x16x32_bf16(ah, bl, acc, 0, 0, 0);
#define MM1(acc, ah, bh) \
  acc = __builtin_amdgcn_mfma_f32_16x16x32_bf16(ah, bh, acc, 0, 0, 0);

// ---------------- TB=48 (3 m-tile) helpers ----------------
__device__ __forceinline__ void gemmS3(f32x4& c0, f32x4& c1, f32x4& c2,
                                       const unsigned char* sm, int abase,
                                       const unsigned short* wh, const unsigned short* wl,
                                       int bcol, int lane){
  const size_t bb = (size_t)bcol * 32 + ((lane >> 4) << 3);
  const short8 bh = *(const short8*)(wh + bb);
  const short8 bl = *(const short8*)(wl + bb);
  short8 ah, al;
  ldA32_48(sm, abase, 0, lane, ah, al); MM3(c0, ah, al, bh, bl);
  ldA32_48(sm, abase, 1, lane, ah, al); MM3(c1, ah, al, bh, bl);
  ldA32_48(sm, abase, 2, lane, ah, al); MM3(c2, ah, al, bh, bl);
}
// split-A, hi-B small encoder: 2 MFMA/mt (actor)
__device__ __forceinline__ void gemmS3_hb(f32x4& c0, f32x4& c1, f32x4& c2,
                                          const unsigned char* sm, int abase,
                                          const unsigned short* wh, int bcol, int lane){
  const size_t bb = (size_t)bcol * 32 + ((lane >> 4) << 3);
  const short8 bh = *(const short8*)(wh + bb);
  short8 ah, al;
  ldA32_48(sm, abase, 0, lane, ah, al); MM1(c0, ah, bh); MM1(c0, al, bh);
  ldA32_48(sm, abase, 1, lane, ah, al); MM1(c1, ah, bh); MM1(c1, al, bh);
  ldA32_48(sm, abase, 2, lane, ah, al); MM1(c2, ah, bh); MM1(c2, al, bh);
}
// hi-A, hi-B small encoder: 1 MFMA/mt (critic, XN hi-only)
__device__ __forceinline__ void gemmS3_hh(f32x4& c0, f32x4& c1, f32x4& c2,
                                          const unsigned char* sm, int abase,
                                          const unsigned short* wh, int bcol, int lane){
  const size_t bb = (size_t)bcol * 32 + ((lane >> 4) << 3);
  const short8 bh = *(const short8*)(wh + bb);
  MM1(c0, ldA32_48h(sm, abase, 0, lane), bh);
  MM1(c1, ldA32_48h(sm, abase, 1, lane), bh);
  MM1(c2, ldA32_48h(sm, abase, 2, lane), bh);
}
__device__ __forceinline__ void gemmAW2_3(f32x4& k0, f32x4& k1, f32x4& k2,
                                          f32x4& m0, f32x4& m1, f32x4& m2,
                                          const unsigned char* sm, int abase,
                                          const unsigned short* wh0, const unsigned short* wh1,
                                          int bcol, int lane){
  const size_t bb = (size_t)bcol * 128 + ((lane >> 4) << 3);
  #pragma unroll
  for (int ks = 0; ks < 4; ++ks){
    short8 a0 = ldAh(sm, abase, 0, ks, lane);
    short8 a1 = ldAh(sm, abase, 1, ks, lane);
    short8 a2 = ldAh(sm, abase, 2, ks, lane);
    const short8 b0 = *(const short8*)(wh0 + bb + ks * 32);
    const short8 b1 = *(const short8*)(wh1 + bb + ks * 32);
    MM1(k0, a0, b0); MM1(k1, a1, b0); MM1(k2, a2, b0);
    MM1(m0, a0, b1); MM1(m1, a1, b1); MM1(m2, a2, b1);
  }
}
__device__ __forceinline__ void gemmA2s3(f32x4& c0, f32x4& c1, f32x4& c2,
                                         f32x4& d0, f32x4& d1, f32x4& d2,
                                         const unsigned char* sm, int a0b, int a1b,
                                         const unsigned short* wh, int bcol, int lane){
  const size_t bb = (size_t)bcol * 128 + ((lane >> 4) << 3);
  #pragma unroll
  for (int ks = 0; ks < 4; ++ks){
    const short8 bh = *(const short8*)(wh + bb + ks * 32);
    short8 x;
    x = ldAh(sm, a0b, 0, ks, lane); MM1(c0, x, bh);
    x = ldAh(sm, a0b, 1, ks, lane); MM1(c1, x, bh);
    x = ldAh(sm, a0b, 2, ks, lane); MM1(c2, x, bh);
    x = ldAh(sm, a1b, 0, ks, lane); MM1(d0, x, bh);
    x = ldAh(sm, a1b, 1, ks, lane); MM1(d1, x, bh);
    x = ldAh(sm, a1b, 2, ks, lane); MM1(d2, x, bh);
  }
}
__device__ __forceinline__ void gemmA3s3(f32x4& c0, f32x4& c1, f32x4& c2,
                                         f32x4& d0, f32x4& d1, f32x4& d2,
                                         f32x4& e0, f32x4& e1, f32x4& e2,
                                         const unsigned char* sm, int a0b, int a1b, int a2b,
                                         const unsigned short* wh, int bcol, int lane){
  const size_t bb = (size_t)bcol * 128 + ((lane >> 4) << 3);
  #pragma unroll
  for (int ks = 0; ks < 4; ++ks){
    const short8 bh = *(const short8*)(wh + bb + ks * 32);
    short8 x;
    x = ldAh(sm, a0b, 0, ks, lane); MM1(c0, x, bh);
    x = ldAh(sm, a0b, 1, ks, lane); MM1(c1, x, bh);
    x = ldAh(sm, a0b, 2, ks, lane); MM1(c2, x, bh);
    x = ldAh(sm, a1b, 0, ks, lane); MM1(d0, x, bh);
    x = ldAh(sm, a1b, 1, ks, lane); MM1(d1, x, bh);
    x = ldAh(sm, a1b, 2, ks, lane); MM1(d2, x, bh);
    x = ldAh(sm, a2b, 0, ks, lane); MM1(e0, x, bh);
    x = ldAh(sm, a2b, 1, ks, lane); MM1(e1, x, bh);
    x = ldAh(sm, a2b, 2, ks, lane); MM1(e2, x, bh);
  }
}
// hi-A, hi-B with K/kBase (merge, cW1): 12 reads, 12 MFMA
__device__ __forceinline__ void gemmAh_hb3K(f32x4& c0, f32x4& c1, f32x4& c2,
                                            const unsigned char* sm, int abase,
                                            const unsigned short* wh,
                                            int K, int bcol, int kBase, int lane){
  const size_t bb = (size_t)bcol * K + kBase + ((lane >> 4) << 3);
  #pragma unroll
  for (int ks = 0; ks < 4; ++ks){
    const short8 bh = *(const short8*)(wh + bb + ks * 32);
    short8 a;
    a = ldAh(sm, abase, 0, ks, lane); MM1(c0, a, bh);
    a = ldAh(sm, abase, 1, ks, lane); MM1(c1, a, bh);
    a = ldAh(sm, abase, 2, ks, lane); MM1(c2, a, bh);
  }
}
__device__ __forceinline__ void gemmAh_hb3(f32x4& c0, f32x4& c1, f32x4& c2,
                                           const unsigned char* sm, int abase,
                                           const unsigned short* wh, int bcol, int lane){
  const size_t bb = (size_t)bcol * 128 + ((lane >> 4) << 3);
  #pragma unroll
  for (int ks = 0; ks < 4; ++ks){
    const short8 bh = *(const short8*)(wh + bb + ks * 32);
    short8 a;
    a = ldAh(sm, abase, 0, ks, lane); MM1(c0, a, bh);
    a = ldAh(sm, abase, 1, ks, lane); MM1(c1, a, bh);
    a = ldAh(sm, abase, 2, ks, lane); MM1(c2, a, bh);
  }
}

// stores
__device__ __forceinline__ void stTile(unsigned char* sm, int base, int mi, int lane, int col, f32x4 v){
  #pragma unroll
  for (int r = 0; r < 4; ++r){
    int row = mi * 16 + ((lane >> 4) << 2) + r;
    int off = base + row * 256 + ((col * 2) ^ ((row & 7) << 4));
    unsigned short hi = f2bf(v[r]);
    *(unsigned short*)(sm + off) = hi;
    *(unsigned short*)(sm + off + 8192) = f2bf(v[r] - bf2f(hi));
  }
}
__device__ __forceinline__ void stH(unsigned char* sm, int base, int mi, int lane, int col, f32x4 v){
  #pragma unroll
  for (int r = 0; r < 4; ++r){
    int row = mi * 16 + ((lane >> 4) << 2) + r;
    int off = base + row * 256 + ((col * 2) ^ ((row & 7) << 4));
    *(unsigned short*)(sm + off) = f2bf(v[r]);
  }
}
__device__ __forceinline__ void stSK(unsigned char* sm, int base, int mi, int lane, int col, f32x4 v){
  #pragma unroll
  for (int r = 0; r < 4; ++r){
    int row = mi * 16 + ((lane >> 4) << 2) + r;
    int off = base + row * 256 + ((col * 2) ^ ((row & 7) << 5));
    *(unsigned short*)(sm + off) = f2bf(v[r]);
  }
}
__device__ __forceinline__ float dot8(short8 x, short8 y){
  float acc = 0.f;
  #pragma unroll
  for (int e = 0; e < 8; ++e)
    acc = fmaf(bf2f((unsigned short)x[e]), bf2f((unsigned short)y[e]), acc);
  return acc;
}
#define RED16(p) { p += __shfl_xor(p, 1, 16); p += __shfl_xor(p, 2, 16); \
                   p += __shfl_xor(p, 4, 16); p += __shfl_xor(p, 8, 16); }
#define RED8(p) { p += __shfl_xor(p, 1); p += __shfl_xor(p, 2); p += __shfl_xor(p, 4); }

// ======================================================================
// PATH A: actor kernel — grid (NBLK, NAG), 512 threads, ROWS=48 (unchanged)
// ======================================================================
__global__ __launch_bounds__(512, 4) void actor_kernel(
    const float* __restrict__ s, const float* __restrict__ a,
    const float* __restrict__ en_b, const float* __restrict__ oa_b,
    const float* __restrict__ goal_b, const float* __restrict__ aval_b,
    const float* __restrict__ merge_b, const unsigned char* __restrict__ wsc,
    unsigned short* __restrict__ sa_g)
{
  __shared__ __align__(16) unsigned char SM[80640];
  const int AXN = 0, AEN = 6144, AOV = 18432, ASK = 30720;
  const int SLB0 = 43008, SLB1 = 55296, SLB2 = 67584, AEP = 79872;
  const int t = threadIdx.x, lane = t & 63, wave = t >> 6;
  const int col = wave * 16 + (lane & 15);
  const int n = blockIdx.y;
  const int gb0 = blockIdx.x * ROWS;
  const float* stats = (const float*)(wsc + WSB_STATS);
  const unsigned short* wsu = (const unsigned short*)(wsc + WSB_W);
  const unsigned short* swh = wsu + OFF_SW(n);
  float* eP0 = (float*)(SM + AEP);
  float* eP1 = eP0 + 48;
  float* eP2 = eP0 + 96;
  float* esm = eP0 + 144;
  const f32x4 Z = binit(0.f);
  const int drow = wave * 8 + (lane >> 3);
  const int dcb  = (lane & 7) * 32;
  const int r0base = (lane >> 4) << 2;

  if (t < ROWS){
    int row = t;
    size_t gb = (size_t)gb0 + row;
    if (gb >= BATCH) gb = BATCH - 1;
    const float* st = stats + n * 40;
    const float* srow = s + ((size_t)n * BATCH + gb) * SD;
    const float* arow = a + ((size_t)n * BATCH + gb) * 2;
    #pragma unroll
    for (int c = 0; c < 32; ++c){
      float v = 0.f;
      if (c < 18) v = (srow[c] - st[c*2]) * st[c*2+1];
      else if (c < 20) v = (arow[c-18] - st[c*2]) * st[c*2+1];
      unsigned short hi = f2bf(v);
      int off = AXN + row * 64 + ((c * 2) ^ ((row & 3) << 4));
      *(unsigned short*)(SM + off) = hi;
      *(unsigned short*)(SM + off + 3072) = f2bf(v - bf2f(hi));
    }
  }
  __syncthreads();
  // R0: en_enc -> AEN ; oa slices -> SLB0, SLB1 (hi-B)
  {
    f32x4 c0 = binit(en_b[n*HD + col]), c1 = c0, c2 = c0;
    gemmS3_hb(c0, c1, c2, SM, AXN, swh, col, lane);
    stH(SM, AEN, 0, lane, col, lrelu4(c0));
    stH(SM, AEN, 1, lane, col, lrelu4(c1));
    stH(SM, AEN, 2, lane, col, lrelu4(c2));
    const float bb = oa_b[n*HD + col];
    c0 = binit(bb); c1 = c0; c2 = c0;
    gemmS3_hb(c0, c1, c2, SM, AXN, swh, 128 + col, lane);
    stH(SM, SLB0, 0, lane, col, lrelu4(c0));
    stH(SM, SLB0, 1, lane, col, lrelu4(c1));
    stH(SM, SLB0, 2, lane, col, lrelu4(c2));
    c0 = binit(bb); c1 = c0; c2 = c0;
    gemmS3_hb(c0, c1, c2, SM, AXN, swh, 256 + col, lane);
    stH(SM, SLB1, 0, lane, col, lrelu4(c0));
    stH(SM, SLB1, 1, lane, col, lrelu4(c1));
    stH(SM, SLB1, 2, lane, col, lrelu4(c2));
  }
  __syncthreads();
  // R1: selk0 -> AOV, selk1 -> ASK (hi-B)
  {
    f32x4 k0 = Z, k1 = Z, k2 = Z, m0 = Z, m1 = Z, m2 = Z;
    gemmAW2_3(k0, k1, k2, m0, m1, m2, SM, AEN,
              wsu + OFF_FT0, wsu + OFF_FT1, col, lane);
    stSK(SM, AOV, 0, lane, col, k0); stSK(SM, AOV, 1, lane, col, k1); stSK(SM, AOV, 2, lane, col, k2);
    stSK(SM, ASK, 0, lane, col, m0); stSK(SM, ASK, 1, lane, col, m1); stSK(SM, ASK, 2, lane, col, m2);
  }
  __syncthreads();
  // R2: oa vals + logit dots + exp
  f32x4 va0, va1, va2, vb0, vb1, vb2;
  {
    const float vb = aval_b[col];
    va0 = binit(vb); va1 = va0; va2 = va0; vb0 = va0; vb1 = va0; vb2 = va0;
    gemmA2s3(va0, va1, va2, vb0, vb1, vb2, SM, SLB0, SLB1, wsu + OFF_AV0, col, lane);
    if (drow < ROWS){
      int sw5 = (drow & 7) << 5, sw4 = (drow & 7) << 4;
      const unsigned char* kb = SM + AOV + drow * 256;
      short8 kfa = *(const short8*)(kb + (dcb ^ sw5));
      short8 kfb = *(const short8*)(kb + ((dcb + 16) ^ sw5));
      const unsigned char* s0 = SM + SLB0 + drow * 256;
      short8 e0a = *(const short8*)(s0 + (dcb ^ sw4));
      short8 e0b = *(const short8*)(s0 + ((dcb + 16) ^ sw4));
      const unsigned char* s1 = SM + SLB1 + drow * 256;
      short8 e1a = *(const short8*)(s1 + (dcb ^ sw4));
      short8 e1b = *(const short8*)(s1 + ((dcb + 16) ^ sw4));
      float p0 = dot8(kfa, e0a) + dot8(kfb, e0b);
      float p1 = dot8(kfa, e1a) + dot8(kfb, e1b);
      RED8(p0) RED8(p1)
      if ((lane & 7) == 0){
        float e0 = __expf(p0 * SCALE), e1 = __expf(p1 * SCALE);
        eP0[drow] = e0; eP1[drow] = e1; esm[drow] = e0 + e1;
      }
    }
  }
  __syncthreads();
  // R3: ov0 -> AOV ; goal slices g0,g1,g2 -> SLB0,1,2 (hi-B)
  {
    f32x4 o;
    #pragma unroll
    for (int r = 0; r < 4; ++r){
      int mr = r0base + r;
      o[r] = (eP0[mr] * lrelu(va0[r]) + eP1[mr] * lrelu(vb0[r])) / esm[mr];
    }
    stH(SM, AOV, 0, lane, col, o);
    #pragma unroll
    for (int r = 0; r < 4; ++r){
      int mr = 16 + r0base + r;
      o[r] = (eP0[mr] * lrelu(va1[r]) + eP1[mr] * lrelu(vb1[r])) / esm[mr];
    }
    stH(SM, AOV, 1, lane, col, o);
    #pragma unroll
    for (int r = 0; r < 4; ++r){
      int mr = 32 + r0base + r;
      o[r] = (eP0[mr] * lrelu(va2[r]) + eP1[mr] * lrelu(vb2[r])) / esm[mr];
    }
    stH(SM, AOV, 2, lane, col, o);
    const float bb = goal_b[n*HD + col];
    f32x4 c0 = binit(bb), c1 = c0, c2 = c0;
    gemmS3_hb(c0, c1, c2, SM, AXN, swh, 384 + col, lane);
    stH(SM, SLB0, 0, lane, col, lrelu4(c0));
    stH(SM, SLB0, 1, lane, col, lrelu4(c1));
    stH(SM, SLB0, 2, lane, col, lrelu4(c2));
    c0 = binit(bb); c1 = c0; c2 = c0;
    gemmS3_hb(c0, c1, c2, SM, AXN, swh, 512 + col, lane);
    stH(SM, SLB1, 0, lane, col, lrelu4(c0));
    stH(SM, SLB1, 1, lane, col, lrelu4(c1));
    stH(SM, SLB1, 2, lane, col, lrelu4(c2));
    c0 = binit(bb); c1 = c0; c2 = c0;
    gemmS3_hb(c0, c1, c2, SM, AXN, swh, 640 + col, lane);
    stH(SM, SLB2, 0, lane, col, lrelu4(c0));
    stH(SM, SLB2, 1, lane, col, lrelu4(c1));
    stH(SM, SLB2, 2, lane, col, lrelu4(c2));
  }
  __syncthreads();
  // R4: goal vals + 3 dots + exps
  f32x4 g0m0, g0m1, g0m2, g1m0, g1m1, g1m2, g2m0, g2m1, g2m2;
  {
    const float vb = aval_b[HD + col];
    g0m0 = binit(vb); g0m1 = g0m0; g0m2 = g0m0;
    g1m0 = g0m0; g1m1 = g0m0; g1m2 = g0m0;
    g2m0 = g0m0; g2m1 = g0m0; g2m2 = g0m0;
    gemmA3s3(g0m0, g0m1, g0m2, g1m0, g1m1, g1m2, g2m0, g2m1, g2m2,
             SM, SLB0, SLB1, SLB2, wsu + OFF_AV1, col, lane);
    if (drow < ROWS){
      int sw5 = (drow & 7) << 5, sw4 = (drow & 7) << 4;
      const unsigned char* kb = SM + ASK + drow * 256;
      short8 kfa = *(const short8*)(kb + (dcb ^ sw5));
      short8 kfb = *(const short8*)(kb + ((dcb + 16) ^ sw5));
      const unsigned char* s0 = SM + SLB0 + drow * 256;
      short8 e0a = *(const short8*)(s0 + (dcb ^ sw4));
      short8 e0b = *(const short8*)(s0 + ((dcb + 16) ^ sw4));
      const unsigned char* s1 = SM + SLB1 + drow * 256;
      short8 e1a = *(const short8*)(s1 + (dcb ^ sw4));
      short8 e1b = *(const short8*)(s1 + ((dcb + 16) ^ sw4));
      const unsigned char* s2 = SM + SLB2 + drow * 256;
      short8 e2a = *(const short8*)(s2 + (dcb ^ sw4));
      short8 e2b = *(const short8*)(s2 + ((dcb + 16) ^ sw4));
      float p0 = dot8(kfa, e0a) + dot8(kfb, e0b);
      float p1 = dot8(kfa, e1a) + dot8(kfb, e1b);
      float p2 = dot8(kfa, e2a) + dot8(kfb, e2b);
      RED8(p0) RED8(p1) RED8(p2)
      if ((lane & 7) == 0){
        float e0 = __expf(p0 * SCALE), e1 = __expf(p1 * SCALE), e2 = __expf(p2 * SCALE);
        eP0[drow] = e0; eP1[drow] = e1; eP2[drow] = e2;
        esm[drow] = (e0 + e1) + e2;
      }
    }
  }
  __syncthreads();
  // R5: ov1 -> SLB0
  {
    f32x4 o;
    #pragma unroll
    for (int r = 0; r < 4; ++r){
      int mr = r0base + r;
      o[r] = ((eP0[mr] * lrelu(g0m0[r]) + eP1[mr] * lrelu(g1m0[r]))
              + eP2[mr] * lrelu(g2m0[r])) / esm[mr];
    }
    stH(SM, SLB0, 0, lane, col, o);
    #pragma unroll
    for (int r = 0; r < 4; ++r){
      int mr = 16 + r0base + r;
      o[r] = ((eP0[mr] * lrelu(g0m1[r]) + eP1[mr] * lrelu(g1m1[r]))
              + eP2[mr] * lrelu(g2m1[r])) / esm[mr];
    }
    stH(SM, SLB0, 1, lane, col, o);
    #pragma unroll
    for (int r = 0; r < 4; ++r){
      int mr = 32 + r0base + r;
      o[r] = ((eP0[mr] * lrelu(g0m2[r]) + eP1[mr] * lrelu(g1m2[r]))
              + eP2[mr] * lrelu(g2m2[r])) / esm[mr];
    }
    stH(SM, SLB0, 2, lane, col, o);
  }
  __syncthreads();
  // R6: merge (hi-B) -> SLB1
  {
    const unsigned short* mh = wsu + OFF_MG(n);
    f32x4 c0 = binit(merge_b[n*HD + col]), c1 = c0, c2 = c0;
    gemmAh_hb3K(c0, c1, c2, SM, AEN,  mh, 384, col, 0,   lane);
    gemmAh_hb3K(c0, c1, c2, SM, AOV,  mh, 384, col, 128, lane);
    gemmAh_hb3K(c0, c1, c2, SM, SLB0, mh, 384, col, 256, lane);
    stH(SM, SLB1, 0, lane, col, lrelu4(c0));
    stH(SM, SLB1, 1, lane, col, lrelu4(c1));
    stH(SM, SLB1, 2, lane, col, lrelu4(c2));
  }
  __syncthreads();
  // R7: coalesced copy SLB1 -> sa_g (padded)
  for (int idx = t; idx < ROWS * 16; idx += 512){
    int row = idx >> 4, ch = idx & 15;
    short8 u = *(const short8*)(SM + SLB1 + row * 256 + ((ch * 16) ^ ((row & 7) << 4)));
    *(short8*)(sa_g + ((size_t)n * PADB + gb0 + row) * HD + ch * 8) = u;
  }
}

// ======================================================================
// PATH A: critic kernel — grid (NBLK, NAG=i), 512 threads, ROWS=48, 52.6KB LDS
// (XN hi-only; COV time-shares CSM; h-tile hi-only — targets 3 blocks/CU)
// ======================================================================
__global__ __launch_bounds__(512, 4) void critic_kernel(
    const float* __restrict__ s, const float* __restrict__ a,
    const float* __restrict__ senc_b, const float* __restrict__ cval_b,
    const float* __restrict__ cb1, const float* __restrict__ cW2,
    const float* __restrict__ cb2, const unsigned char* __restrict__ wsc,
    const unsigned short* __restrict__ sa_g, float* __restrict__ out)
{
  __shared__ __align__(16) unsigned char SM[52608];
  const int CXN = 0, CEN = 3072, CSMo = 15360, CSA = 27648;
  const int COV = 15360 /* = CSM, time-shared */, CH = 27648 /* = CSA, hi-only */, CLW = 52224;
  const int t = threadIdx.x, lane = t & 63, wave = t >> 6;
  const int col = wave * 16 + (lane & 15);
  const int i = blockIdx.y;
  const int gb0 = blockIdx.x * ROWS;
  const int j0 = (i == 0) ? 1 : 0;
  const int j1 = (i == 2) ? 1 : 2;
  const float* stats = (const float*)(wsc + WSB_STATS);
  const unsigned short* wsu = (const unsigned short*)(wsc + WSB_W);
  const unsigned short* swh = wsu + OFF_SW(i);
  const f32x4 Z = binit(0.f);
  const int drow = wave * 8 + (lane >> 3);
  const int dcb  = (lane & 7) * 32;
  const int r0base = (lane >> 4) << 2;

  // R0: stage XN_i (hi-only, clamped) + copy sa_j0/j1 -> LDS (hi, swz)
  if (t < ROWS){
    int row = t;
    size_t gb = (size_t)gb0 + row;
    if (gb >= BATCH) gb = BATCH - 1;
    const float* st = stats + i * 40;
    const float* srow = s + ((size_t)i * BATCH + gb) * SD;
    const float* arow = a + ((size_t)i * BATCH + gb) * 2;
    #pragma unroll
    for (int c = 0; c < 32; ++c){
      float v = 0.f;
      if (c < 18) v = (srow[c] - st[c*2]) * st[c*2+1];
      else if (c < 20) v = (arow[c-18] - st[c*2]) * st[c*2+1];
      int off = CXN + row * 64 + ((c * 2) ^ ((row & 3) << 4));
      *(unsigned short*)(SM + off) = f2bf(v);
    }
  }
  for (int idx = t; idx < 2 * ROWS * 16; idx += 512){
    int tile = idx >= ROWS * 16;
    int k = idx - tile * ROWS * 16;
    int row = k >> 4, ch = k & 15;
    int j = tile ? j1 : j0;
    short8 u = *(const short8*)(sa_g + ((size_t)j * PADB + gb0 + row) * HD + ch * 8);
    *(short8*)(SM + CSA + tile * 12288 + row * 256 + ((ch * 16) ^ ((row & 7) << 4))) = u;
  }
  __syncthreads();
  // R1: s_enc -> CEN (hi-A hi-B)
  {
    f32x4 c0 = binit(senc_b[i*HD + col]), c1 = c0, c2 = c0;
    gemmS3_hh(c0, c1, c2, SM, CXN, swh, 768 + col, lane);
    stH(SM, CEN, 0, lane, col, lrelu4(c0));
    stH(SM, CEN, 1, lane, col, lrelu4(c1));
    stH(SM, CEN, 2, lane, col, lrelu4(c2));
  }
  __syncthreads();
  // R2: selsM = s_enc @ M (hi-B) -> CSM (32B-swz)
  {
    f32x4 k0 = Z, k1 = Z, k2 = Z;
    gemmAh_hb3(k0, k1, k2, SM, CEN, wsu + OFF_MT, col, lane);
    stSK(SM, CSMo, 0, lane, col, k0);
    stSK(SM, CSMo, 1, lane, col, k1);
    stSK(SM, CSMo, 2, lane, col, k2);
  }
  __syncthreads();
  // R3: vals GEMMs + dots + 2-way softmax
  f32x4 v00, v01, v02, v10, v11, v12;
  {
    const float vb = cval_b[col];
    v00 = binit(vb); v01 = v00; v02 = v00; v10 = v00; v11 = v00; v12 = v00;
    gemmA2s3(v00, v01, v02, v10, v11, v12, SM, CSA, CSA + 12288,
             wsu + OFF_CV, col, lane);
    if (drow < ROWS){
      int sw5 = (drow & 7) << 5, sw4 = (drow & 7) << 4;
      const unsigned char* mb = SM + CSMo + drow * 256;
      short8 ma = *(const short8*)(mb + (dcb ^ sw5));
      short8 mbf = *(const short8*)(mb + ((dcb + 16) ^ sw5));
      const unsigned char* a0p = SM + CSA + drow * 256;
      short8 a0a = *(const short8*)(a0p + (dcb ^ sw4));
      short8 a0b = *(const short8*)(a0p + ((dcb + 16) ^ sw4));
      const unsigned char* b0p = SM + CSA + 12288 + drow * 256;
      short8 b0a = *(const short8*)(b0p + (dcb ^ sw4));
      short8 b0b = *(const short8*)(b0p + ((dcb + 16) ^ sw4));
      float p0 = dot8(ma, a0a) + dot8(mbf, a0b);
      float p1 = dot8(ma, b0a) + dot8(mbf, b0b);
      RED8(p0) RED8(p1)
      if ((lane & 7) == 0){
        float e0 = __expf(p0 * SCALE), e1 = __expf(p1 * SCALE);
        float inv = 1.f / (e0 + e1);
        ((float*)(SM + CLW))[drow]      = e0 * inv;
        ((float*)(SM + CLW))[48 + drow] = e1 * inv;
      }
    }
  }
  __syncthreads();
  // R4: ov -> COV (hi; overwrites CSM)
  {
    const float* w0 = (const float*)(SM + CLW);
    const float* w1 = w0 + 48;
    f32x4 o;
    #pragma unroll
    for (int r = 0; r < 4; ++r){
      int mr = r0base + r;
      o[r] = w0[mr] * lrelu(v00[r]) + w1[mr] * lrelu(v10[r]);
    }
    stH(SM, COV, 0, lane, col, o);
    #pragma unroll
    for (int r = 0; r < 4; ++r){
      int mr = 16 + r0base + r;
      o[r] = w0[mr] * lrelu(v01[r]) + w1[mr] * lrelu(v11[r]);
    }
    stH(SM, COV, 1, lane, col, o);
    #pragma unroll
    for (int r = 0; r < 4; ++r){
      int mr = 32 + r0base + r;
      o[r] = w0[mr] * lrelu(v02[r]) + w1[mr] * lrelu(v12[r]);
    }
    stH(SM, COV, 2, lane, col, o);
  }
  __syncthreads();
  // R5: h = lrelu([s_enc|ov] @ cW1 + b) -> CH (hi-only; overwrites CSA)
  {
    const unsigned short* c1h = wsu + OFF_C1(i);
    f32x4 h0 = binit(cb1[i*HD + col]), h1 = h0, h2 = h0;
    gemmAh_hb3K(h0, h1, h2, SM, CEN, c1h, 256, col, 0,   lane);
    gemmAh_hb3K(h0, h1, h2, SM, COV, c1h, 256, col, 128, lane);
    stH(SM, CH, 0, lane, col, lrelu4(h0));
    stH(SM, CH, 1, lane, col, lrelu4(h1));
    stH(SM, CH, 2, lane, col, lrelu4(h2));
  }
  __syncthreads();
  // R6: q = h @ cW2 + cb2 (per-row dot, hi-only h), guarded out store
  if (drow < ROWS && gb0 + drow < BATCH){
    int sw4 = (drow & 7) << 4;
    const unsigned char* hb = SM + CH + drow * 256;
    short8 ha = *(const short8*)(hb + (dcb ^ sw4));
    short8 hbf = *(const short8*)(hb + ((dcb + 16) ^ sw4));
    float q0 = 0.f, q1 = 0.f;
    #pragma unroll
    for (int e = 0; e < 8; ++e){
      int d = (lane & 7) * 16 + e;
      float hv = bf2f((unsigned short)ha[e]);
      q0 = fmaf(hv, cW2[(i * HD + d) * 2 + 0], q0);
      q1 = fmaf(hv, cW2[(i * HD + d) * 2 + 1], q1);
    }
    #pragma unroll
    for (int e = 0; e < 8; ++e){
      int d = (lane & 7) * 16 + 8 + e;
      float hv = bf2f((unsigned short)hbf[e]);
      q0 = fmaf(hv, cW2[(i * HD + d) * 2 + 0], q0);
      q1 = fmaf(hv, cW2[(i * HD + d) * 2 + 1], q1);
    }
    RED8(q0) RED8(q1)
    if ((lane & 7) == 0){
      out[((size_t)i * BATCH + gb0 + drow) * 2 + 0] = q0 + cb2[i * 2 + 0];
      out[((size_t)i * BATCH + gb0 + drow) * 2 + 1] = q1 + cb2[i * 2 + 1];
    }
  }
}

// ------------------------------------------------------------ launch -----
extern "C" void kernel_launch(void* const* d_in, const int* in_sizes, int n_in,
                              void* d_out, int out_size, void* d_ws, size_t ws_size,
                              hipStream_t stream) {
  const float* s       = (const float*)d_in[0];
  const float* a       = (const float*)d_in[1];
  const float* en_W    = (const float*)d_in[2];
  const float* en_b    = (const float*)d_in[3];
  const float* oa_W    = (const float*)d_in[4];
  const float* oa_b    = (const float*)d_in[5];
  const float* goal_W  = (const float*)d_in[6];
  const float* goal_b  = (const float*)d_in[7];
  const float* akey_W  = (const float*)d_in[8];
  const float* asel_W  = (const float*)d_in[9];
  const float* aval_W  = (const float*)d_in[10];
  const float* aval_b  = (const float*)d_in[11];
  const float* merge_W = (const float*)d_in[12];
  const float* merge_b = (const float*)d_in[13];
  const float* senc_W  = (const float*)d_in[14];
  const float* senc_b  = (const float*)d_in[15];
  const float* ckey_W  = (const float*)d_in[16];
  const float* csel_W  = (const float*)d_in[17];
  const float* cval_W  = (const float*)d_in[18];
  const float* cval_b  = (const float*)d_in[19];
  const float* cW1     = (const float*)d_in[20];
  const float* cb1     = (const float*)d_in[21];
  const float* cW2     = (const float*)d_in[22];
  const float* cb2     = (const float*)d_in[23];
  unsigned char* wsc = (unsigned char*)d_ws;
  float* F = (float*)(wsc + WSB_F);
  unsigned short* wsu = (unsigned short*)(wsc + WSB_W);
  float* out = (float*)d_out;

  hipMemsetAsync(wsc + WSB_ACCUM, 0, 480, stream);
  stats_partial_kernel<<<48, 256, 0, stream>>>(s, a, (float*)(wsc + WSB_ACCUM));
  fuse_mats_kernel<<<dim3(HD, 4), HD, 0, stream>>>(
      asel_W, akey_W, csel_W, ckey_W, F,
      (const float*)(wsc + WSB_ACCUM), (float*)(wsc + WSB_STATS));
  prep_split_kernel<<<dim3(336, 16), 256, 0, stream>>>(
      F, aval_W, cval_W, merge_W, cW1, cW2, en_W, oa_W, goal_W, senc_W, wsu);

  unsigned short* sa_g = (unsigned short*)(wsc + WSB_SA);
  actor_kernel<<<dim3(NBLK, NAG), 512, 0, stream>>>(
      s, a, en_b, oa_b, goal_b, aval_b, merge_b,
      (const unsigned char*)wsc, sa_g);
  critic_kernel<<<dim3(NBLK, NAG), 512, 0, stream>>>(
      s, a, senc_b, cval_b, cb1, cW2, cb2,
      (const unsigned char*)wsc, (const unsigned short*)sa_g, out);
}